// Round 5
// baseline (375.784 us; speedup 1.0000x reference)
//
#include <hip/hip_runtime.h>
#include <cstddef>

#define NRELS 8
#define EMB 128
#define HID 128
#define OUTD 256
#define HEADS 4
#define RANK 8
#define D2 512            // HEADS*HID, conv2 input dim
#define KCAT 192          // EMB + 64, concatenated K for residual+lora2 GEMM
#define NEG_SLOPE 0.2f
#define LN_EPS 1e-5f

typedef short bf16x8 __attribute__((ext_vector_type(8)));   // 8 bf16 in 4 VGPRs
typedef float f32x4 __attribute__((ext_vector_type(4)));

__device__ __forceinline__ unsigned short f2bf(float f) {   // RNE
  union { float f; unsigned u; } v; v.f = f;
  unsigned u = v.u;
  return (unsigned short)((u + 0x7fffu + ((u >> 16) & 1u)) >> 16);
}
__device__ __forceinline__ float bf2f(unsigned short u) {
  union { unsigned u; float f; } v; v.u = (unsigned)u << 16; return v.f;
}

// async global->LDS, 16B per lane; LDS dest = wave-uniform base + lane*16
#define GLOAD16(ldsp, gp) \
  __builtin_amdgcn_global_load_lds((const __attribute__((address_space(1))) unsigned int*)(gp), \
      (__attribute__((address_space(3))) unsigned int*)(ldsp), 16, 0, 0)

// ---------------- Unified big-tile bf16 MFMA GEMM (128x128 tile, BK=64) ----------------
// global_load_lds staging, linear LDS [128][64] with 8-chunk XOR involution:
//  phys_chunk = logical_chunk ^ (row&7), applied on pre-swizzled global source AND frag read.
// ATT: 0 none; 1 fused att-dots per-head (col-block == head, store al[row*4+by]);
//      2 fused att-dots single-head, per-col-block partials al[by*M + row].
// BIAS: add bias[col] (+ b1p[col] if F32OUT) before store.
// F32OUT: write fp32 to Cf instead of bf16 to C.
// PB: last blockIdx.y slice computes a fused 128x64 P-tile (Cp = A @ Bp^T), sharing A staging.
// lda: A row stride (elements); aoffc: per-col-block A column offset (lora1 head slices).
template<int ATT, int BIAS, int F32OUT, int PB>
__global__ __launch_bounds__(256) void gemm_tile(const unsigned short* __restrict__ A,
    const unsigned short* __restrict__ B, unsigned short* __restrict__ C,
    float* __restrict__ Cf, const unsigned short* __restrict__ Bp,
    float* __restrict__ Cp, int M, int N, int K, int lda, int aoffc,
    const float* __restrict__ bias, const float* __restrict__ b1p,
    const float* __restrict__ attL, const float* __restrict__ attR,
    float* __restrict__ al, float* __restrict__ ar) {
  __shared__ unsigned short As[128 * 64];
  __shared__ unsigned short Bs[128 * 64];
  __shared__ float pL[2][128];
  __shared__ float pR[2][128];
  const int tid = threadIdx.x;
  const int wave = tid >> 6;
  const int lane = tid & 63;
  const int wm = wave & 1;
  const int wn = wave >> 1;
  const int r16 = lane & 15;
  const int quad = lane >> 4;
  const int bm = blockIdx.x * 128;
  const int srow = lane >> 3;                    // 0..7 within one 8-row gload
  const int gcol = ((lane & 7) ^ srow) * 8;      // swizzled source col chunk (elems)

  if (PB && blockIdx.y == (int)gridDim.y - 1) {
    // ---- fused P-tile: 128 rows x 64 cols, Bp is [64][K] ----
    const unsigned short* Ag[4];
#pragma unroll
    for (int g = 0; g < 4; ++g) {
      int r = bm + wave * 32 + g * 8 + srow; if (r >= M) r = M - 1;
      Ag[g] = A + (size_t)r * lda + gcol;
    }
    const unsigned short* Bg[2];
#pragma unroll
    for (int g = 0; g < 2; ++g)
      Bg[g] = Bp + (size_t)(wave * 16 + g * 8 + srow) * K + gcol;
    f32x4 accp[4][2] = {};
    for (int k0 = 0; k0 < K; k0 += 64) {
      __syncthreads();
#pragma unroll
      for (int g = 0; g < 4; ++g) GLOAD16(As + (wave * 32 + g * 8) * 64, Ag[g] + k0);
#pragma unroll
      for (int g = 0; g < 2; ++g) GLOAD16(Bs + (wave * 16 + g * 8) * 64, Bg[g] + k0);
      __syncthreads();
#pragma unroll
      for (int s = 0; s < 2; ++s) {
        const int rs = ((s * 4 + quad) ^ (r16 & 7)) * 8;
        bf16x8 af[4], bfr[2];
#pragma unroll
        for (int mi = 0; mi < 4; ++mi)
          af[mi] = *(const bf16x8*)(As + (wm * 64 + mi * 16 + r16) * 64 + rs);
#pragma unroll
        for (int ni = 0; ni < 2; ++ni)
          bfr[ni] = *(const bf16x8*)(Bs + (wn * 32 + ni * 16 + r16) * 64 + rs);
#pragma unroll
        for (int mi = 0; mi < 4; ++mi)
#pragma unroll
          for (int ni = 0; ni < 2; ++ni)
            accp[mi][ni] = __builtin_amdgcn_mfma_f32_16x16x32_bf16(af[mi], bfr[ni], accp[mi][ni], 0, 0, 0);
      }
    }
#pragma unroll
    for (int mi = 0; mi < 4; ++mi)
#pragma unroll
      for (int ni = 0; ni < 2; ++ni)
#pragma unroll
        for (int r = 0; r < 4; ++r) {
          int row = bm + wm * 64 + mi * 16 + quad * 4 + r;
          if (row < M)
            Cp[(size_t)row * 64 + wn * 32 + ni * 16 + r16] = accp[mi][ni][r];
        }
    return;
  }

  const int bn = blockIdx.y * 128;
  const unsigned short* Abase = A + (size_t)blockIdx.y * aoffc;
  const unsigned short* Ag[4];
  const unsigned short* Bg[4];
#pragma unroll
  for (int g = 0; g < 4; ++g) {
    int r = bm + wave * 32 + g * 8 + srow; if (r >= M) r = M - 1;
    Ag[g] = Abase + (size_t)r * lda + gcol;
    Bg[g] = B + (size_t)(bn + wave * 32 + g * 8 + srow) * K + gcol;
  }
  f32x4 acc[4][4] = {};
  for (int k0 = 0; k0 < K; k0 += 64) {
    __syncthreads();
#pragma unroll
    for (int g = 0; g < 4; ++g) GLOAD16(As + (wave * 32 + g * 8) * 64, Ag[g] + k0);
#pragma unroll
    for (int g = 0; g < 4; ++g) GLOAD16(Bs + (wave * 32 + g * 8) * 64, Bg[g] + k0);
    __syncthreads();
#pragma unroll
    for (int s = 0; s < 2; ++s) {
      const int rs = ((s * 4 + quad) ^ (r16 & 7)) * 8;
      bf16x8 af[4], bfr[4];
#pragma unroll
      for (int mi = 0; mi < 4; ++mi)
        af[mi] = *(const bf16x8*)(As + (wm * 64 + mi * 16 + r16) * 64 + rs);
#pragma unroll
      for (int ni = 0; ni < 4; ++ni)
        bfr[ni] = *(const bf16x8*)(Bs + (wn * 64 + ni * 16 + r16) * 64 + rs);
#pragma unroll
      for (int mi = 0; mi < 4; ++mi)
#pragma unroll
        for (int ni = 0; ni < 4; ++ni)
          acc[mi][ni] = __builtin_amdgcn_mfma_f32_16x16x32_bf16(af[mi], bfr[ni], acc[mi][ni], 0, 0, 0);
    }
  }
  float bcol[4];
  if (BIAS) {
#pragma unroll
    for (int ni = 0; ni < 4; ++ni) {
      int cn = bn + wn * 64 + ni * 16 + r16;
      bcol[ni] = bias[cn];
      if (F32OUT) bcol[ni] += b1p[cn];
    }
  }
#pragma unroll
  for (int mi = 0; mi < 4; ++mi)
#pragma unroll
    for (int ni = 0; ni < 4; ++ni)
#pragma unroll
      for (int r = 0; r < 4; ++r) {
        int row = bm + wm * 64 + mi * 16 + quad * 4 + r;
        if (row < M) {
          float v = acc[mi][ni][r];
          if (BIAS) v += bcol[ni];
          size_t idx = (size_t)row * N + bn + wn * 64 + ni * 16 + r16;
          if (F32OUT) Cf[idx] = v;
          else        C[idx] = f2bf(v);
        }
      }
  if (ATT) {
    float La[4], Ra[4];
#pragma unroll
    for (int ni = 0; ni < 4; ++ni) {
      int cn = bn + wn * 64 + ni * 16 + r16;
      La[ni] = attL[cn]; Ra[ni] = attR[cn];
    }
#pragma unroll
    for (int mi = 0; mi < 4; ++mi)
#pragma unroll
      for (int r = 0; r < 4; ++r) {
        float sl = 0.f, sr = 0.f;
#pragma unroll
        for (int ni = 0; ni < 4; ++ni) {
          sl = fmaf(acc[mi][ni][r], La[ni], sl);
          sr = fmaf(acc[mi][ni][r], Ra[ni], sr);
        }
#pragma unroll
        for (int o = 1; o < 16; o <<= 1) {
          sl += __shfl_xor(sl, o, 64);
          sr += __shfl_xor(sr, o, 64);
        }
        if (r16 == 0) {
          int rl = wm * 64 + mi * 16 + quad * 4 + r;
          pL[wn][rl] = sl; pR[wn][rl] = sr;
        }
      }
    __syncthreads();
    if (tid < 128) {
      int row = bm + tid;
      if (row < M) {
        float sl = pL[0][tid] + pL[1][tid];
        float sr = pR[0][tid] + pR[1][tid];
        if (ATT == 1) {
          al[(size_t)row * 4 + blockIdx.y] = sl;
          ar[(size_t)row * 4 + blockIdx.y] = sr;
        } else {
          al[(size_t)blockIdx.y * M + row] = sl;   // per-col-block partial
          ar[(size_t)blockIdx.y * M + row] = sr;
        }
      }
    }
  }
}

// ---------------- fp32 tiled GEMM, both tiny M1/M2 precomputes in one dispatch ----------------
__global__ __launch_bounds__(256) void gemm_abt2(const float* __restrict__ Amat1,
    const float* __restrict__ W1, float* __restrict__ M1o,
    const float* __restrict__ Amat2, const float* __restrict__ W2, float* __restrict__ M2o) {
  const float* A; const float* B; float* C; int N, K, bn;
  if (blockIdx.x < D2 / 64) { A = Amat1; B = W1; C = M1o; N = D2; K = EMB; bn = blockIdx.x * 64; }
  else { A = Amat2; B = W2; C = M2o; N = OUTD; K = D2; bn = (blockIdx.x - D2 / 64) * 64; }
  __shared__ float As[32][64];
  __shared__ float Bs[32][64];
  const int tid = threadIdx.x;
  const int tx = tid & 15;
  const int ty = tid >> 4;
  const int lr = tid & 63;
  const int lq = tid >> 6;
  float acc[4][4] = {};
  for (int k0 = 0; k0 < K; k0 += 32) {
#pragma unroll
    for (int s = 0; s < 2; ++s) {
      const int q = lq + s * 4;
      float4 va = *(const float4*)(A + (size_t)lr * K + k0 + q * 4);
      As[q * 4 + 0][lr] = va.x; As[q * 4 + 1][lr] = va.y;
      As[q * 4 + 2][lr] = va.z; As[q * 4 + 3][lr] = va.w;
      float4 vb = *(const float4*)(B + (size_t)(bn + lr) * K + k0 + q * 4);
      Bs[q * 4 + 0][lr] = vb.x; Bs[q * 4 + 1][lr] = vb.y;
      Bs[q * 4 + 2][lr] = vb.z; Bs[q * 4 + 3][lr] = vb.w;
    }
    __syncthreads();
#pragma unroll
    for (int kk = 0; kk < 32; ++kk) {
      float a[4], b[4];
#pragma unroll
      for (int i2 = 0; i2 < 4; ++i2) { a[i2] = As[kk][ty * 4 + i2]; b[i2] = Bs[kk][tx * 4 + i2]; }
#pragma unroll
      for (int i2 = 0; i2 < 4; ++i2)
#pragma unroll
        for (int j2 = 0; j2 < 4; ++j2)
          acc[i2][j2] = fmaf(a[i2], b[j2], acc[i2][j2]);
    }
    __syncthreads();
  }
#pragma unroll
  for (int i2 = 0; i2 < 4; ++i2)
#pragma unroll
    for (int j2 = 0; j2 < 4; ++j2)
      C[(size_t)(ty * 4 + i2) * N + bn + tx * 4 + j2] = acc[i2][j2];
}

// ---------------- Fused prep: CSR hist + bf16 conversions + LoRA re-layouts + concat ----------------
__global__ void prep_all(const float* __restrict__ x0, const float* __restrict__ W1,
    const float* __restrict__ W2, const float* __restrict__ res_W,
    const float* __restrict__ A1, const float* __restrict__ A2,
    const float* __restrict__ B1, const float* __restrict__ B2,
    unsigned short* __restrict__ x0b, unsigned short* __restrict__ Acat,
    unsigned short* __restrict__ W1b, unsigned short* __restrict__ W2b,
    unsigned short* __restrict__ RWcat,
    float* __restrict__ Amat1, float* __restrict__ Amat2,
    unsigned short* __restrict__ Bmat1b, unsigned short* __restrict__ Bmat2b,
    const int* __restrict__ ii, int* __restrict__ ideg, int* __restrict__ prepos,
    int E, int nx0) {
  int idx = blockIdx.x * 256 + threadIdx.x;
  if (idx < E) { prepos[idx] = atomicAdd(&ideg[ii[idx]], 1); return; } idx -= E;
  if (idx < nx0) { unsigned short b = f2bf(x0[idx]); x0b[idx] = b;
    Acat[(size_t)(idx >> 7) * KCAT + (idx & 127)] = b; return; } idx -= nx0;
  if (idx < D2 * EMB) { W1b[idx] = f2bf(W1[idx]); return; } idx -= D2 * EMB;
  if (idx < OUTD * D2) { W2b[idx] = f2bf(W2[idx]); return; } idx -= OUTD * D2;
  if (idx < OUTD * EMB) { RWcat[(size_t)(idx >> 7) * KCAT + (idx & 127)] = f2bf(res_W[idx]); return; } idx -= OUTD * EMB;
  if (idx < 64 * EMB) { int d = idx % EMB, rk = idx / EMB, k = rk & 7, r = rk >> 3;
    Amat1[idx] = A1[(size_t)r * EMB * RANK + (size_t)d * RANK + k]; return; } idx -= 64 * EMB;
  if (idx < 64 * D2) { int d = idx % D2, rk = idx / D2, k = rk & 7, r = rk >> 3;
    Amat2[idx] = A2[(size_t)r * D2 * RANK + (size_t)d * RANK + k]; return; } idx -= 64 * D2;
  if (idx < 64 * EMB) { int d = idx % EMB, rk = idx / EMB, k = rk & 7, r = rk >> 3;
    Bmat1b[idx] = f2bf(B1[(size_t)r * EMB * RANK + (size_t)d * RANK + k]); return; } idx -= 64 * EMB;
  if (idx < 64 * D2) { int d = idx % D2, rk = idx / D2, k = rk & 7, r = rk >> 3;
    Bmat2b[idx] = f2bf(B2[(size_t)r * D2 * RANK + (size_t)d * RANK + k]); }
}

// ---------------- Fold Matt + build M1T2 (plain transpose) + RWcat LoRA cols ----------------
__global__ void fold_build(const float* __restrict__ M1, const float* __restrict__ M2,
                           const float* __restrict__ attR1, const float* __restrict__ attR2,
                           unsigned short* __restrict__ M1T2, unsigned short* __restrict__ RWcat,
                           float* __restrict__ Matt1, float* __restrict__ Matt2) {
  int idx = blockIdx.x * 256 + threadIdx.x;
  if (idx < 512 * 64) { int c = idx >> 6, rk = idx & 63;
    M1T2[idx] = f2bf(M1[(size_t)rk * D2 + c]); return; } idx -= 512 * 64;
  if (idx < 256 * 64) { int c = idx >> 6, rk = idx & 63;
    RWcat[(size_t)c * KCAT + 128 + rk] = f2bf(M2[(size_t)rk * OUTD + c]); return; } idx -= 256 * 64;
  if (idx < 256) { int h = idx & 3, rk = idx >> 2;
    float s = 0.f;
    for (int c = 0; c < HID; ++c)
      s = fmaf(M1[(size_t)rk * D2 + h * HID + c], attR1[h * HID + c], s);
    Matt1[rk * 4 + h] = s; return; } idx -= 256;
  if (idx < 64) {
    float s = 0.f;
    for (int c = 0; c < OUTD; ++c) s = fmaf(M2[(size_t)idx * OUTD + c], attR2[c], s);
    Matt2[idx] = s; }
}

__global__ __launch_bounds__(1024) void exscan_kernel(const int* __restrict__ deg,
                                                      int* __restrict__ rowstart, int n) {
  __shared__ int wsum[16];
  int t = threadIdx.x;
  int lane = t & 63, wid = t >> 6;
  int carry = 0;
  for (int base = 0; base < n; base += 4096) {
    int i0 = base + t * 4;
    int v0 = 0, v1 = 0, v2 = 0, v3 = 0;
    if (i0 + 3 < n) {
      int4 vv = *(const int4*)(deg + i0);
      v0 = vv.x; v1 = vv.y; v2 = vv.z; v3 = vv.w;
    } else {
      if (i0 < n) v0 = deg[i0];
      if (i0 + 1 < n) v1 = deg[i0 + 1];
      if (i0 + 2 < n) v2 = deg[i0 + 2];
      if (i0 + 3 < n) v3 = deg[i0 + 3];
    }
    int tot = v0 + v1 + v2 + v3;
    int x = tot;
#pragma unroll
    for (int o = 1; o < 64; o <<= 1) {
      int y = __shfl_up(x, o, 64);
      if (lane >= o) x += y;
    }
    if (lane == 63) wsum[wid] = x;
    __syncthreads();
    if (t == 0) {
      int s = carry;
      for (int w2 = 0; w2 < 16; ++w2) { int tmp = wsum[w2]; wsum[w2] = s; s += tmp; }
      carry = s;
    }
    __syncthreads();
    int ex0 = x - tot + wsum[wid];
    if (i0 + 3 < n) {
      int4 ov; ov.x = ex0; ov.y = ex0 + v0; ov.z = ex0 + v0 + v1; ov.w = ex0 + v0 + v1 + v2;
      *(int4*)(rowstart + i0) = ov;
    } else {
      if (i0 < n) rowstart[i0] = ex0;
      if (i0 + 1 < n) rowstart[i0 + 1] = ex0 + v0;
      if (i0 + 2 < n) rowstart[i0 + 2] = ex0 + v0 + v1;
      if (i0 + 3 < n) rowstart[i0 + 3] = ex0 + v0 + v1 + v2;
    }
    __syncthreads();
  }
  if (t == 0) rowstart[n] = carry;
}

// ---------------- Layer-1 edge logits -> packed records at CSR slots ----------------
// rec1 (16 floats): [j, ex0, ex1, ex2 | ex3, rt, low0, low1 | low2..low5 | low6, low7, 0, 0]
__global__ void edge_alpha1(const int* __restrict__ ji, const int* __restrict__ ii,
                            const int* __restrict__ et, const int* __restrict__ rowstart,
                            const int* __restrict__ prepos,
                            const float* __restrict__ P1,
                            const float* __restrict__ al1, const float* __restrict__ ar1,
                            const float* __restrict__ relb1, const float* __restrict__ Matt1,
                            float4* __restrict__ recs1, int E) {
  int e = blockIdx.x * blockDim.x + threadIdx.x;
  if (e >= E) return;
  int j = ji[e], i = ii[e], rt = et[e];
  float4 lo0 = *(const float4*)(P1 + (size_t)j * 64 + rt * 8);
  float4 lo1 = *(const float4*)(P1 + (size_t)j * 64 + rt * 8 + 4);
  float low[RANK] = {lo0.x, lo0.y, lo0.z, lo0.w, lo1.x, lo1.y, lo1.z, lo1.w};
  float4 ali = *(const float4*)(al1 + (size_t)i * 4);
  float4 arj = *(const float4*)(ar1 + (size_t)j * 4);
  float4 rb  = *(const float4*)(relb1 + rt * 4);
  float a0 = ali.x + arj.x + rb.x;
  float a1 = ali.y + arj.y + rb.y;
  float a2 = ali.z + arj.z + rb.z;
  float a3 = ali.w + arj.w + rb.w;
#pragma unroll
  for (int k = 0; k < RANK; ++k) {
    float4 mk = *(const float4*)(Matt1 + ((rt * 8 + k) << 2));
    a0 = fmaf(low[k], mk.x, a0); a1 = fmaf(low[k], mk.y, a1);
    a2 = fmaf(low[k], mk.z, a2); a3 = fmaf(low[k], mk.w, a3);
  }
  a0 = (a0 > 0.f) ? a0 : NEG_SLOPE * a0;
  a1 = (a1 > 0.f) ? a1 : NEG_SLOPE * a1;
  a2 = (a2 > 0.f) ? a2 : NEG_SLOPE * a2;
  a3 = (a3 > 0.f) ? a3 : NEG_SLOPE * a3;
  float e0 = expf(a0), e1 = expf(a1), e2 = expf(a2), e3 = expf(a3);
  float4* rp = recs1 + (size_t)(rowstart[i] + prepos[e]) * 4;
  rp[0] = make_float4(__int_as_float(j), e0, e1, e2);
  rp[1] = make_float4(e3, __int_as_float(rt), low[0], low[1]);
  rp[2] = make_float4(low[2], low[3], low[4], low[5]);
  rp[3] = make_float4(low[6], low[7], 0.f, 0.f);
}

// ---------------- Layer-1 Q/den: writes normalized Q (bf16) + rden1[Nn][32] ----------------
__global__ __launch_bounds__(256) void qden1(const float4* __restrict__ recs1,
    const int* __restrict__ rowstart, unsigned short* __restrict__ Q1b,
    float* __restrict__ rden1, int Nn) {
  const int wid = threadIdx.x >> 6, lane = threadIdx.x & 63;
  const int i = blockIdx.x * 4 + wid;
  if (i >= Nn) return;
  const int rt_mine = lane >> 3, k = lane & 7;
  const int s0 = rowstart[i], deg = rowstart[i + 1] - s0;
  const float* rf = (const float*)recs1;
  float q0 = 0.f, q1 = 0.f, q2 = 0.f, q3 = 0.f;
  float d0 = 0.f, d1 = 0.f, d2 = 0.f, d3 = 0.f;
  float4 a0 = {}, a1 = {};
  float lw = 0.f;
  if (deg > 0) {
    a0 = recs1[(size_t)s0 * 4]; a1 = recs1[(size_t)s0 * 4 + 1];
    lw = rf[(size_t)s0 * 16 + 6 + k];
  }
  for (int p = 0; p < deg; ++p) {
    float4 b0 = a0, b1 = a1; float lwn = lw;
    if (p + 1 < deg) {
      b0 = recs1[(size_t)(s0 + p + 1) * 4]; b1 = recs1[(size_t)(s0 + p + 1) * 4 + 1];
      lwn = rf[(size_t)(s0 + p + 1) * 16 + 6 + k];
    }
    int rt = __float_as_int(a1.y);
    if (rt == rt_mine) {
      q0 = fmaf(a0.y, lw, q0); q1 = fmaf(a0.z, lw, q1);
      q2 = fmaf(a0.w, lw, q2); q3 = fmaf(a1.x, lw, q3);
      d0 += a0.y; d1 += a0.z; d2 += a0.w; d3 += a1.x;
    }
    a0 = b0; a1 = b1; lw = lwn;
  }
  float r0 = (d0 > 0.f) ? 1.f / d0 : 0.f;
  float r1 = (d1 > 0.f) ? 1.f / d1 : 0.f;
  float r2 = (d2 > 0.f) ? 1.f / d2 : 0.f;
  float r3 = (d3 > 0.f) ? 1.f / d3 : 0.f;
  size_t qb = (size_t)i * 256;
  Q1b[qb + lane]       = f2bf(q0 * r0);
  Q1b[qb + 64 + lane]  = f2bf(q1 * r1);
  Q1b[qb + 128 + lane] = f2bf(q2 * r2);
  Q1b[qb + 192 + lane] = f2bf(q3 * r3);
  if (k == 0) {
    size_t db = (size_t)i * 32;
    rden1[db + rt_mine]      = r0;
    rden1[db + 8 + rt_mine]  = r1;
    rden1[db + 16 + rt_mine] = r2;
    rden1[db + 24 + rt_mine] = r3;
  }
}

// ---------------- Layer-1 gather: wave per node, 8 ch/lane, w = ex * rden[h][rt] ----------------
__global__ __launch_bounds__(256) void node_agg1_lite(const float4* __restrict__ recs1,
    const int* __restrict__ rowstart, const unsigned short* __restrict__ z1b,
    const unsigned short* __restrict__ L1b, const float* __restrict__ rden1,
    unsigned short* __restrict__ h1out, int Nn) {
  const int wid = threadIdx.x >> 6;
  const int lane = threadIdx.x & 63;
  const int i = blockIdx.x * 4 + wid;
  if (i >= Nn) return;
  __shared__ float denS[4][32];
  if (lane < 32) denS[wid][lane] = rden1[(size_t)i * 32 + lane];
  // wave-synchronous LDS (each wave writes+reads its own row), no barrier
  const int s0 = rowstart[i];
  const int deg = rowstart[i + 1] - s0;
  const int c0 = lane * 8;                 // head = lane>>4
  const float* rf = (const float*)recs1;
  const int hb = (lane >> 4) << 3;         // head*8 base into denS
  float acc[8] = {};
  float4 r0 = {}, r1 = {}, r2 = {};
  float2 g0 = {}, g1 = {}, g2 = {};        // (ex3, rt)
  uint4 za = {}, zb = {};
  if (deg > 0) { r0 = recs1[(size_t)s0 * 4]; g0 = *(const float2*)(rf + (size_t)s0 * 16 + 4);
    za = *(const uint4*)(z1b + (size_t)__float_as_int(r0.x) * D2 + c0); }
  if (deg > 1) { r1 = recs1[(size_t)(s0 + 1) * 4]; g1 = *(const float2*)(rf + (size_t)(s0 + 1) * 16 + 4);
    zb = *(const uint4*)(z1b + (size_t)__float_as_int(r1.x) * D2 + c0); }
  if (deg > 2) { r2 = recs1[(size_t)(s0 + 2) * 4]; g2 = *(const float2*)(rf + (size_t)(s0 + 2) * 16 + 4); }
  for (int p = 0; p < deg; ++p) {
    float4 r3 = r2; float2 g3 = g2; uint4 zn = zb;
    if (p + 3 < deg) { r3 = recs1[(size_t)(s0 + p + 3) * 4];
                       g3 = *(const float2*)(rf + (size_t)(s0 + p + 3) * 16 + 4); }
    if (p + 2 < deg) zn = *(const uint4*)(z1b + (size_t)__float_as_int(r2.x) * D2 + c0);
    int rt = __float_as_int(g0.y);
    float wlo = (lane & 16) ? r0.z : r0.y;
    float whi = (lane & 16) ? g0.x : r0.w;
    float wt = ((lane & 32) ? whi : wlo) * denS[wid][hb + rt];
    acc[0] = fmaf(wt, bf2f((unsigned short)(za.x & 0xffff)), acc[0]);
    acc[1] = fmaf(wt, bf2f((unsigned short)(za.x >> 16)), acc[1]);
    acc[2] = fmaf(wt, bf2f((unsigned short)(za.y & 0xffff)), acc[2]);
    acc[3] = fmaf(wt, bf2f((unsigned short)(za.y >> 16)), acc[3]);
    acc[4] = fmaf(wt, bf2f((unsigned short)(za.z & 0xffff)), acc[4]);
    acc[5] = fmaf(wt, bf2f((unsigned short)(za.z >> 16)), acc[5]);
    acc[6] = fmaf(wt, bf2f((unsigned short)(za.w & 0xffff)), acc[6]);
    acc[7] = fmaf(wt, bf2f((unsigned short)(za.w >> 16)), acc[7]);
    r0 = r1; g0 = g1; r1 = r2; g1 = g2; r2 = r3; g2 = g3; za = zb; zb = zn;
  }
  uint4 lv = *(const uint4*)(L1b + (size_t)i * D2 + c0);  // lora + bias1 (pre-folded)
  unsigned lw[4] = {lv.x, lv.y, lv.z, lv.w};
  unsigned ov[4];
#pragma unroll
  for (int q = 0; q < 4; ++q) {
    float e0 = acc[2 * q]     + bf2f((unsigned short)(lw[q] & 0xffff));
    float e1 = acc[2 * q + 1] + bf2f((unsigned short)(lw[q] >> 16));
    e0 = e0 > 0.f ? e0 : expm1f(e0);
    e1 = e1 > 0.f ? e1 : expm1f(e1);
    ov[q] = (unsigned)f2bf(e0) | ((unsigned)f2bf(e1) << 16);
  }
  *(uint4*)(h1out + (size_t)i * D2 + c0) = make_uint4(ov[0], ov[1], ov[2], ov[3]);
}

// ---------------- Layer-2 edge logits -> packed records ----------------
// rec2 (12 floats): [j, rt, ex, low0 | low1..low4 | low5, low6, low7, 0]
__global__ void edge_alpha2(const int* __restrict__ ji, const int* __restrict__ ii,
                            const int* __restrict__ et, const int* __restrict__ rowstart,
                            const int* __restrict__ prepos,
                            const float* __restrict__ P2,
                            const float* __restrict__ al2, const float* __restrict__ ar2,
                            const float* __restrict__ relb2, const float* __restrict__ Matt2,
                            float4* __restrict__ recs2, int E, int Nn) {
  int e = blockIdx.x * blockDim.x + threadIdx.x;
  if (e >= E) return;
  int j = ji[e], i = ii[e], rt = et[e];
  float4 lo0 = *(const float4*)(P2 + (size_t)j * 64 + rt * 8);
  float4 lo1 = *(const float4*)(P2 + (size_t)j * 64 + rt * 8 + 4);
  float low[RANK] = {lo0.x, lo0.y, lo0.z, lo0.w, lo1.x, lo1.y, lo1.z, lo1.w};
  float a = al2[i] + al2[(size_t)Nn + i] + ar2[j] + ar2[(size_t)Nn + j] + relb2[rt];
#pragma unroll
  for (int k = 0; k < RANK; ++k) a = fmaf(low[k], Matt2[rt * RANK + k], a);
  a = (a > 0.f) ? a : NEG_SLOPE * a;
  float ex = expf(a);
  float4* rp = recs2 + (size_t)(rowstart[i] + prepos[e]) * 3;
  rp[0] = make_float4(__int_as_float(j), __int_as_float(rt), ex, low[0]);
  rp[1] = make_float4(low[1], low[2], low[3], low[4]);
  rp[2] = make_float4(low[5], low[6], low[7], 0.f);
}

// ---------------- Layer-2 Q/den: Q -> Acat cols 128..191, rden2[Nn][8] ----------------
__global__ __launch_bounds__(256) void qden2(const float4* __restrict__ recs2,
    const int* __restrict__ rowstart, unsigned short* __restrict__ Acat,
    float* __restrict__ rden2, int Nn) {
  const int wid = threadIdx.x >> 6, lane = threadIdx.x & 63;
  const int i = blockIdx.x * 4 + wid;
  if (i >= Nn) return;
  const int rt_mine = lane >> 3, k = lane & 7;
  const int s0 = rowstart[i], deg = rowstart[i + 1] - s0;
  const float* rf = (const float*)recs2;
  float q = 0.f, d = 0.f;
  float4 a0 = {}; float lw = 0.f;
  if (deg > 0) { a0 = recs2[(size_t)s0 * 3]; lw = rf[(size_t)s0 * 12 + 3 + k]; }
  for (int p = 0; p < deg; ++p) {
    float4 b0 = a0; float lwn = lw;
    if (p + 1 < deg) {
      b0 = recs2[(size_t)(s0 + p + 1) * 3];
      lwn = rf[(size_t)(s0 + p + 1) * 12 + 3 + k];
    }
    int rt = __float_as_int(a0.y);
    if (rt == rt_mine) { q = fmaf(a0.z, lw, q); d += a0.z; }
    a0 = b0; lw = lwn;
  }
  float rd = (d > 0.f) ? 1.f / d : 0.f;
  Acat[(size_t)i * KCAT + 128 + lane] = f2bf(q * rd);
  if (k == 0) rden2[(size_t)i * 8 + rt_mine] = rd;
}

// ---------------- Layer-2 gather + residual/lora/bias (o2) + LN -> out ----------------
__global__ __launch_bounds__(256) void node_agg2_lite(const float4* __restrict__ recs2,
    const int* __restrict__ rowstart, const unsigned short* __restrict__ z2b,
    const float* __restrict__ rden2, const float* __restrict__ o2,
    const float* __restrict__ ln_g, const float* __restrict__ ln_b,
    float* __restrict__ y, int Nn) {
  const int wid = threadIdx.x >> 6;
  const int lane = threadIdx.x & 63;
  const int i = blockIdx.x * 4 + wid;
  if (i >= Nn) return;
  __shared__ float denS[4][NRELS];
  if (lane < NRELS) denS[wid][lane] = rden2[(size_t)i * 8 + lane];
  // wave-synchronous LDS, no barrier
  const int s0 = rowstart[i];
  const int deg = rowstart[i + 1] - s0;
  const int c0 = lane * 4;
  float acc[4] = {};
  float4 r0 = {}, r1 = {}, r2 = {};
  uint2 za = make_uint2(0u, 0u), zb = make_uint2(0u, 0u);
  if (deg > 0) { r0 = recs2[(size_t)s0 * 3];
    za = *(const uint2*)(z2b + (size_t)__float_as_int(r0.x) * OUTD + c0); }
  if (deg > 1) { r1 = recs2[(size_t)(s0 + 1) * 3];
    zb = *(const uint2*)(z2b + (size_t)__float_as_int(r1.x) * OUTD + c0); }
  if (deg > 2) r2 = recs2[(size_t)(s0 + 2) * 3];
  for (int p = 0; p < deg; ++p) {
    float4 r3 = r2;
    uint2 zn = zb;
    if (p + 3 < deg) r3 = recs2[(size_t)(s0 + p + 3) * 3];
    if (p + 2 < deg)
      zn = *(const uint2*)(z2b + (size_t)__float_as_int(r2.x) * OUTD + c0);
    int rt = __float_as_int(r0.y);
    float wt = r0.z * denS[wid][rt];
    acc[0] = fmaf(wt, bf2f((unsigned short)(za.x & 0xffff)), acc[0]);
    acc[1] = fmaf(wt, bf2f((unsigned short)(za.x >> 16)), acc[1]);
    acc[2] = fmaf(wt, bf2f((unsigned short)(za.y & 0xffff)), acc[2]);
    acc[3] = fmaf(wt, bf2f((unsigned short)(za.y >> 16)), acc[3]);
    r0 = r1; r1 = r2; r2 = r3; za = zb; zb = zn;
  }
  float4 rsv = *(const float4*)(o2 + (size_t)i * OUTD + c0);   // residual+lora2+bias2+res_b
  float vv[4];
  vv[0] = acc[0] + rsv.x;
  vv[1] = acc[1] + rsv.y;
  vv[2] = acc[2] + rsv.z;
  vv[3] = acc[3] + rsv.w;
  float s = vv[0] + vv[1] + vv[2] + vv[3];
  for (int o = 32; o > 0; o >>= 1) s += __shfl_xor(s, o, 64);
  float mu = s * (1.f / OUTD);
  float q = 0.f;
#pragma unroll
  for (int k = 0; k < 4; ++k) { float d = vv[k] - mu; q += d * d; }
  for (int o = 32; o > 0; o >>= 1) q += __shfl_xor(q, o, 64);
  float rstd = rsqrtf(q * (1.f / OUTD) + LN_EPS);
  float4 g = *(const float4*)(ln_g + c0);
  float4 bb = *(const float4*)(ln_b + c0);
  float4 ov;
  ov.x = (vv[0] - mu) * rstd * g.x + bb.x;
  ov.y = (vv[1] - mu) * rstd * g.y + bb.y;
  ov.z = (vv[2] - mu) * rstd * g.z + bb.z;
  ov.w = (vv[3] - mu) * rstd * g.w + bb.w;
  *(float4*)(y + (size_t)i * OUTD + c0) = ov;
}

extern "C" void kernel_launch(void* const* d_in, const int* in_sizes, int n_in,
                              void* d_out, int out_size, void* d_ws, size_t ws_size,
                              hipStream_t stream) {
  const float* x0     = (const float*)d_in[0];
  const float* A1     = (const float*)d_in[1];
  const float* B1     = (const float*)d_in[2];
  const float* W1     = (const float*)d_in[3];
  const float* attL1  = (const float*)d_in[4];
  const float* attR1  = (const float*)d_in[5];
  const float* relb1  = (const float*)d_in[6];
  const float* bias1  = (const float*)d_in[7];
  const float* A2     = (const float*)d_in[8];
  const float* B2     = (const float*)d_in[9];
  const float* W2     = (const float*)d_in[10];
  const float* attL2  = (const float*)d_in[11];
  const float* attR2  = (const float*)d_in[12];
  const float* relb2  = (const float*)d_in[13];
  const float* bias2  = (const float*)d_in[14];
  const float* res_W  = (const float*)d_in[15];
  const float* res_b  = (const float*)d_in[16];
  const float* ln_g   = (const float*)d_in[17];
  const float* ln_b   = (const float*)d_in[18];
  const int*   eidx   = (const int*)d_in[19];
  const int*   etype  = (const int*)d_in[20];
  float* out = (float*)d_out;

  const int Nn = in_sizes[0] / EMB;     // 30000
  const int E  = in_sizes[20];          // 150000
  const int* ji = eidx;
  const int* ii = eidx + E;

  // ---- workspace carve-up (float units; all offsets stay 16B-aligned) ----
  float* w = (float*)d_ws;
  size_t off = 0;
  float* o2    = w + off; off += (size_t)Nn * OUTD;   // ALSO aliased as L1b (bf16 [Nn][512])
  float* P1    = w + off; off += (size_t)Nn * 64;     // ALSO aliased (with P2) as Q1b (bf16 [Nn][256])
  float* P2    = w + off; off += (size_t)Nn * 64;
  float* M1    = w + off; off += 64 * D2;
  float* M2    = w + off; off += 64 * OUTD;
  float* Amat1 = w + off; off += 64 * EMB;
  float* Amat2 = w + off; off += 64 * D2;
  float* Matt1 = w + off; off += 64 * 4;
  float* Matt2 = w + off; off += 64;
  float* al1   = w + off; off += (size_t)Nn * 4;
  float* ar1   = w + off; off += (size_t)Nn * 4;
  float* al2   = w + off; off += (size_t)Nn * 2;      // [2][Nn] col-block partials
  float* ar2   = w + off; off += (size_t)Nn * 2;
  float* rden1 = w + off; off += (size_t)Nn * 32;
  float* rden2 = w + off; off += (size_t)Nn * 8;
  float4* recs1 = (float4*)(w + off); off += (size_t)E * 16;
  float4* recs2 = (float4*)(w + off); off += (size_t)E * 12;
  unsigned short* z1b    = (unsigned short*)(w + off); off += (size_t)Nn * D2 / 2;
  unsigned short* z2b    = (unsigned short*)(w + off); off += (size_t)Nn * OUTD / 2;
  unsigned short* x0b    = (unsigned short*)(w + off); off += (size_t)Nn * EMB / 2;
  unsigned short* h1b    = (unsigned short*)(w + off); off += (size_t)Nn * D2 / 2;
  unsigned short* W1b    = (unsigned short*)(w + off); off += (size_t)D2 * EMB / 2;
  unsigned short* W2b    = (unsigned short*)(w + off); off += (size_t)OUTD * D2 / 2;
  unsigned short* Bmat1b = (unsigned short*)(w + off); off += (size_t)64 * EMB / 2;
  unsigned short* Bmat2b = (unsigned short*)(w + off); off += (size_t)64 * D2 / 2;
  unsigned short* Acat   = (unsigned short*)(w + off); off += (size_t)Nn * KCAT / 2;
  unsigned short* RWcat  = (unsigned short*)(w + off); off += (size_t)OUTD * KCAT / 2;
  unsigned short* M1T2   = (unsigned short*)(w + off); off += (size_t)512 * 64 / 2;
  int* ideg     = (int*)(w + off); off += (size_t)Nn;
  int* prepos   = (int*)(w + off); off += (size_t)E;
  int* rowstart = (int*)(w + off); off += (size_t)Nn + 1;
  (void)ws_size; (void)n_in; (void)out_size;

  // Aliases (lifetimes verified):
  //  Q1b over P1+P2: P1 dead after edge_alpha1; P2 written (z2 P-branch) after lora1 consumed Q1b.
  //  L1b over o2:    o2 written in layer 2 (after node_agg1_lite consumed L1b).
  unsigned short* Q1b = (unsigned short*)P1;   // [Nn][256] bf16
  unsigned short* L1b = (unsigned short*)o2;   // [Nn][512] bf16

  const int MT128 = (Nn + 127) / 128;
  const int NB4 = (Nn + 3) / 4;

  // 0) CSR hist fused into prep; conversions + LoRA re-layouts + concat copies
  (void)hipMemsetAsync(ideg, 0, (size_t)Nn * sizeof(int), stream);
  {
    int nx0 = Nn * EMB;
    int total = E + nx0 + D2 * EMB + OUTD * D2 + OUTD * EMB
              + 64 * EMB + 64 * D2 + 64 * EMB + 64 * D2;
    prep_all<<<(total + 255) / 256, 256, 0, stream>>>(x0, W1, W2, res_W, A1, A2, B1, B2,
        x0b, Acat, W1b, W2b, RWcat, Amat1, Amat2, Bmat1b, Bmat2b, ii, ideg, prepos, E, nx0);
  }
  exscan_kernel<<<1, 1024, 0, stream>>>(ideg, rowstart, Nn);

  // 1) M1/M2 (one dispatch) + folds/builds (one dispatch)
  gemm_abt2<<<dim3(D2 / 64 + OUTD / 64, 1), 256, 0, stream>>>(Amat1, W1, M1, Amat2, W2, M2);
  fold_build<<<(512 * 64 + 256 * 64 + 256 + 64 + 255) / 256, 256, 0, stream>>>(
      M1, M2, attR1, attR2, M1T2, RWcat, Matt1, Matt2);

  // 2) Layer-1: z1 GEMM (+fused att-dots, +fused P1 tile)
  gemm_tile<1, 0, 0, 1><<<dim3(MT128, D2 / 128 + 1), 256, 0, stream>>>(x0b, W1b, z1b, nullptr,
      Bmat1b, P1, Nn, D2, EMB, EMB, 0, nullptr, nullptr, attL1, attR1, al1, ar1);

  // 3) Layer-1 edge logits; Q/den; LoRA GEMM (K=64 per-head, +bias1); gather
  edge_alpha1<<<(E + 255) / 256, 256, 0, stream>>>(ji, ii, etype, rowstart, prepos, P1,
                                                   al1, ar1, relb1, Matt1, recs1, E);
  qden1<<<NB4, 256, 0, stream>>>(recs1, rowstart, Q1b, rden1, Nn);
  gemm_tile<0, 1, 0, 0><<<dim3(MT128, D2 / 128), 256, 0, stream>>>(Q1b, M1T2, L1b, nullptr,
      nullptr, nullptr, Nn, D2, 64, 256, 64, bias1, nullptr, nullptr, nullptr, nullptr, nullptr);
  node_agg1_lite<<<NB4, 256, 0, stream>>>(recs1, rowstart, z1b, L1b, rden1, h1b, Nn);

  // 4) Layer-2: z2 GEMM (+fused att-dot partials, +fused P2 tile)
  gemm_tile<2, 0, 0, 1><<<dim3(MT128, OUTD / 128 + 1), 256, 0, stream>>>(h1b, W2b, z2b, nullptr,
      Bmat2b, P2, Nn, OUTD, D2, D2, 0, nullptr, nullptr, attL2, attR2, al2, ar2);

  // 5) Layer-2 edge logits; Q/den (fills Acat); fused residual+lora+bias GEMM; gather + LN
  edge_alpha2<<<(E + 255) / 256, 256, 0, stream>>>(ji, ii, etype, rowstart, prepos, P2,
                                                   al2, ar2, relb2, Matt2, recs2, E, Nn);
  qden2<<<NB4, 256, 0, stream>>>(recs2, rowstart, Acat, rden2, Nn);
  gemm_tile<0, 1, 1, 0><<<dim3(MT128, OUTD / 128), 256, 0, stream>>>(Acat, RWcat, nullptr, o2,
      nullptr, nullptr, Nn, OUTD, KCAT, KCAT, 0, bias2, res_b, nullptr, nullptr, nullptr, nullptr);
  node_agg2_lite<<<NB4, 256, 0, stream>>>(recs2, rowstart, z2b, rden2, o2, ln_g, ln_b, out, Nn);
}

// Round 6
// 367.467 us; speedup vs baseline: 1.0226x; 1.0226x over previous
//
#include <hip/hip_runtime.h>
#include <cstddef>

#define NRELS 8
#define EMB 128
#define HID 128
#define OUTD 256
#define HEADS 4
#define RANK 8
#define D2 512            // HEADS*HID, conv2 input dim
#define KCAT 192          // EMB + 64, concatenated K for residual+lora2 GEMM
#define NEG_SLOPE 0.2f
#define LN_EPS 1e-5f

typedef short bf16x8 __attribute__((ext_vector_type(8)));   // 8 bf16 in 4 VGPRs
typedef float f32x4 __attribute__((ext_vector_type(4)));

__device__ __forceinline__ unsigned short f2bf(float f) {   // RNE
  union { float f; unsigned u; } v; v.f = f;
  unsigned u = v.u;
  return (unsigned short)((u + 0x7fffu + ((u >> 16) & 1u)) >> 16);
}
__device__ __forceinline__ float bf2f(unsigned short u) {
  union { unsigned u; float f; } v; v.u = (unsigned)u << 16; return v.f;
}

// async global->LDS, 16B per lane; LDS dest = wave-uniform base + lane*16
#define GLOAD16(ldsp, gp) \
  __builtin_amdgcn_global_load_lds((const __attribute__((address_space(1))) unsigned int*)(gp), \
      (__attribute__((address_space(3))) unsigned int*)(ldsp), 16, 0, 0)

// ---------------- Unified big-tile bf16 MFMA GEMM (128x128 tile, BK=32, LDS dbuf) ----------------
// Double-buffered global_load_lds staging: prefetch tile t+1 BEFORE computing tile t;
// single __syncthreads() per K-step (its implicit vmcnt(0) waits the prefetch).
// Linear LDS [128][32] per buffer, chunk-XOR involution (2-way bank aliasing = free):
//   source col chunk  = (lane&3) ^ ((lane>>3)&3)
//   frag read chunk   = quad ^ ((r16>>1)&3)
// ATT: 0 none; 1 fused att-dots per-head (col-block == head, store al[row*4+by]);
//      2 fused att-dots single-head, per-col-block partials al[by*M + row].
// BIAS: add bias[col] (+ b1p[col] if F32OUT) before store.
// F32OUT: write fp32 to Cf instead of bf16 to C.
// PB: last blockIdx.y slice computes a fused 128x64 P-tile (Cp = A @ Bp^T), sharing A staging.
// lda: A row stride (elements); aoffc: per-col-block A column offset (lora1 head slices).
template<int ATT, int BIAS, int F32OUT, int PB>
__global__ __launch_bounds__(256) void gemm_tile(const unsigned short* __restrict__ A,
    const unsigned short* __restrict__ B, unsigned short* __restrict__ C,
    float* __restrict__ Cf, const unsigned short* __restrict__ Bp,
    float* __restrict__ Cp, int M, int N, int K, int lda, int aoffc,
    const float* __restrict__ bias, const float* __restrict__ b1p,
    const float* __restrict__ attL, const float* __restrict__ attR,
    float* __restrict__ al, float* __restrict__ ar) {
  __shared__ unsigned short As[2][128 * 32];
  __shared__ unsigned short Bs[2][128 * 32];
  __shared__ float pL[2][128];
  __shared__ float pR[2][128];
  const int tid = threadIdx.x;
  const int wave = tid >> 6;
  const int lane = tid & 63;
  const int wm = wave & 1;
  const int wn = wave >> 1;
  const int r16 = lane & 15;
  const int quad = lane >> 4;
  const int bm = blockIdx.x * 128;
  const int lr = lane >> 2;                                  // 0..15
  const int lc = ((lane & 3) ^ ((lane >> 3) & 3)) * 8;       // swizzled source col chunk
  const int rsw = (quad ^ ((r16 >> 1) & 3)) * 8;             // fragment read swizzle
  int ar0 = bm + wave * 32 + lr;      if (ar0 >= M) ar0 = M - 1;
  int ar1 = bm + wave * 32 + 16 + lr; if (ar1 >= M) ar1 = M - 1;

  if (PB && blockIdx.y == (int)gridDim.y - 1) {
    // ---- fused P-tile: 128 rows x 64 cols, Bp is [64][K] ----
    const unsigned short* Ag0 = A + (size_t)ar0 * lda + lc;
    const unsigned short* Ag1 = A + (size_t)ar1 * lda + lc;
    const unsigned short* Bg = Bp + (size_t)(wave * 16 + lr) * K + lc;
    f32x4 accp[4][2] = {};
    GLOAD16(As[0] + wave * 1024, Ag0);
    GLOAD16(As[0] + wave * 1024 + 512, Ag1);
    GLOAD16(Bs[0] + wave * 512, Bg);
    __syncthreads();
    int cur = 0;
    for (int k0 = 0; k0 < K; k0 += 32) {
      if (k0 + 32 < K) {
        GLOAD16(As[cur ^ 1] + wave * 1024, Ag0 + k0 + 32);
        GLOAD16(As[cur ^ 1] + wave * 1024 + 512, Ag1 + k0 + 32);
        GLOAD16(Bs[cur ^ 1] + wave * 512, Bg + k0 + 32);
      }
      bf16x8 af[4], bfr[2];
#pragma unroll
      for (int mi = 0; mi < 4; ++mi)
        af[mi] = *(const bf16x8*)(As[cur] + (wm * 64 + mi * 16 + r16) * 32 + rsw);
#pragma unroll
      for (int ni = 0; ni < 2; ++ni)
        bfr[ni] = *(const bf16x8*)(Bs[cur] + (wn * 32 + ni * 16 + r16) * 32 + rsw);
#pragma unroll
      for (int mi = 0; mi < 4; ++mi)
#pragma unroll
        for (int ni = 0; ni < 2; ++ni)
          accp[mi][ni] = __builtin_amdgcn_mfma_f32_16x16x32_bf16(af[mi], bfr[ni], accp[mi][ni], 0, 0, 0);
      __syncthreads();
      cur ^= 1;
    }
#pragma unroll
    for (int mi = 0; mi < 4; ++mi)
#pragma unroll
      for (int ni = 0; ni < 2; ++ni)
#pragma unroll
        for (int r = 0; r < 4; ++r) {
          int row = bm + wm * 64 + mi * 16 + quad * 4 + r;
          if (row < M)
            Cp[(size_t)row * 64 + wn * 32 + ni * 16 + r16] = accp[mi][ni][r];
        }
    return;
  }

  const int bn = blockIdx.y * 128;
  const unsigned short* Abase = A + (size_t)blockIdx.y * aoffc;
  const unsigned short* Ag0 = Abase + (size_t)ar0 * lda + lc;
  const unsigned short* Ag1 = Abase + (size_t)ar1 * lda + lc;
  const unsigned short* Bg0 = B + (size_t)(bn + wave * 32 + lr) * K + lc;
  const unsigned short* Bg1 = B + (size_t)(bn + wave * 32 + 16 + lr) * K + lc;
  f32x4 acc[4][4] = {};
  GLOAD16(As[0] + wave * 1024, Ag0);
  GLOAD16(As[0] + wave * 1024 + 512, Ag1);
  GLOAD16(Bs[0] + wave * 1024, Bg0);
  GLOAD16(Bs[0] + wave * 1024 + 512, Bg1);
  __syncthreads();
  int cur = 0;
  for (int k0 = 0; k0 < K; k0 += 32) {
    if (k0 + 32 < K) {
      GLOAD16(As[cur ^ 1] + wave * 1024, Ag0 + k0 + 32);
      GLOAD16(As[cur ^ 1] + wave * 1024 + 512, Ag1 + k0 + 32);
      GLOAD16(Bs[cur ^ 1] + wave * 1024, Bg0 + k0 + 32);
      GLOAD16(Bs[cur ^ 1] + wave * 1024 + 512, Bg1 + k0 + 32);
    }
    bf16x8 af[4], bfr[4];
#pragma unroll
    for (int mi = 0; mi < 4; ++mi)
      af[mi] = *(const bf16x8*)(As[cur] + (wm * 64 + mi * 16 + r16) * 32 + rsw);
#pragma unroll
    for (int ni = 0; ni < 4; ++ni)
      bfr[ni] = *(const bf16x8*)(Bs[cur] + (wn * 64 + ni * 16 + r16) * 32 + rsw);
#pragma unroll
    for (int mi = 0; mi < 4; ++mi)
#pragma unroll
      for (int ni = 0; ni < 4; ++ni)
        acc[mi][ni] = __builtin_amdgcn_mfma_f32_16x16x32_bf16(af[mi], bfr[ni], acc[mi][ni], 0, 0, 0);
    __syncthreads();
    cur ^= 1;
  }
  float bcol[4];
  if (BIAS) {
#pragma unroll
    for (int ni = 0; ni < 4; ++ni) {
      int cn = bn + wn * 64 + ni * 16 + r16;
      bcol[ni] = bias[cn];
      if (F32OUT) bcol[ni] += b1p[cn];
    }
  }
#pragma unroll
  for (int mi = 0; mi < 4; ++mi)
#pragma unroll
    for (int ni = 0; ni < 4; ++ni)
#pragma unroll
      for (int r = 0; r < 4; ++r) {
        int row = bm + wm * 64 + mi * 16 + quad * 4 + r;
        if (row < M) {
          float v = acc[mi][ni][r];
          if (BIAS) v += bcol[ni];
          size_t idx = (size_t)row * N + bn + wn * 64 + ni * 16 + r16;
          if (F32OUT) Cf[idx] = v;
          else        C[idx] = f2bf(v);
        }
      }
  if (ATT) {
    float La[4], Ra[4];
#pragma unroll
    for (int ni = 0; ni < 4; ++ni) {
      int cn = bn + wn * 64 + ni * 16 + r16;
      La[ni] = attL[cn]; Ra[ni] = attR[cn];
    }
#pragma unroll
    for (int mi = 0; mi < 4; ++mi)
#pragma unroll
      for (int r = 0; r < 4; ++r) {
        float sl = 0.f, sr = 0.f;
#pragma unroll
        for (int ni = 0; ni < 4; ++ni) {
          sl = fmaf(acc[mi][ni][r], La[ni], sl);
          sr = fmaf(acc[mi][ni][r], Ra[ni], sr);
        }
#pragma unroll
        for (int o = 1; o < 16; o <<= 1) {
          sl += __shfl_xor(sl, o, 64);
          sr += __shfl_xor(sr, o, 64);
        }
        if (r16 == 0) {
          int rl = wm * 64 + mi * 16 + quad * 4 + r;
          pL[wn][rl] = sl; pR[wn][rl] = sr;
        }
      }
    __syncthreads();
    if (tid < 128) {
      int row = bm + tid;
      if (row < M) {
        float sl = pL[0][tid] + pL[1][tid];
        float sr = pR[0][tid] + pR[1][tid];
        if (ATT == 1) {
          al[(size_t)row * 4 + blockIdx.y] = sl;
          ar[(size_t)row * 4 + blockIdx.y] = sr;
        } else {
          al[(size_t)blockIdx.y * M + row] = sl;   // per-col-block partial
          ar[(size_t)blockIdx.y * M + row] = sr;
        }
      }
    }
  }
}

// ---------------- fp32 tiled GEMM, both tiny M1/M2 precomputes in one dispatch ----------------
__global__ __launch_bounds__(256) void gemm_abt2(const float* __restrict__ Amat1,
    const float* __restrict__ W1, float* __restrict__ M1o,
    const float* __restrict__ Amat2, const float* __restrict__ W2, float* __restrict__ M2o) {
  const float* A; const float* B; float* C; int N, K, bn;
  if (blockIdx.x < D2 / 64) { A = Amat1; B = W1; C = M1o; N = D2; K = EMB; bn = blockIdx.x * 64; }
  else { A = Amat2; B = W2; C = M2o; N = OUTD; K = D2; bn = (blockIdx.x - D2 / 64) * 64; }
  __shared__ float As[32][64];
  __shared__ float Bs[32][64];
  const int tid = threadIdx.x;
  const int tx = tid & 15;
  const int ty = tid >> 4;
  const int lr = tid & 63;
  const int lq = tid >> 6;
  float acc[4][4] = {};
  for (int k0 = 0; k0 < K; k0 += 32) {
#pragma unroll
    for (int s = 0; s < 2; ++s) {
      const int q = lq + s * 4;
      float4 va = *(const float4*)(A + (size_t)lr * K + k0 + q * 4);
      As[q * 4 + 0][lr] = va.x; As[q * 4 + 1][lr] = va.y;
      As[q * 4 + 2][lr] = va.z; As[q * 4 + 3][lr] = va.w;
      float4 vb = *(const float4*)(B + (size_t)(bn + lr) * K + k0 + q * 4);
      Bs[q * 4 + 0][lr] = vb.x; Bs[q * 4 + 1][lr] = vb.y;
      Bs[q * 4 + 2][lr] = vb.z; Bs[q * 4 + 3][lr] = vb.w;
    }
    __syncthreads();
#pragma unroll
    for (int kk = 0; kk < 32; ++kk) {
      float a[4], b[4];
#pragma unroll
      for (int i2 = 0; i2 < 4; ++i2) { a[i2] = As[kk][ty * 4 + i2]; b[i2] = Bs[kk][tx * 4 + i2]; }
#pragma unroll
      for (int i2 = 0; i2 < 4; ++i2)
#pragma unroll
        for (int j2 = 0; j2 < 4; ++j2)
          acc[i2][j2] = fmaf(a[i2], b[j2], acc[i2][j2]);
    }
    __syncthreads();
  }
#pragma unroll
  for (int i2 = 0; i2 < 4; ++i2)
#pragma unroll
    for (int j2 = 0; j2 < 4; ++j2)
      C[(size_t)(ty * 4 + i2) * N + bn + tx * 4 + j2] = acc[i2][j2];
}

// ---------------- Fused prep: CSR hist + bf16 conversions + LoRA re-layouts + concat ----------------
__global__ void prep_all(const float* __restrict__ x0, const float* __restrict__ W1,
    const float* __restrict__ W2, const float* __restrict__ res_W,
    const float* __restrict__ A1, const float* __restrict__ A2,
    const float* __restrict__ B1, const float* __restrict__ B2,
    unsigned short* __restrict__ x0b, unsigned short* __restrict__ Acat,
    unsigned short* __restrict__ W1b, unsigned short* __restrict__ W2b,
    unsigned short* __restrict__ RWcat,
    float* __restrict__ Amat1, float* __restrict__ Amat2,
    unsigned short* __restrict__ Bmat1b, unsigned short* __restrict__ Bmat2b,
    const int* __restrict__ ii, int* __restrict__ ideg, int* __restrict__ prepos,
    int E, int nx0) {
  int idx = blockIdx.x * 256 + threadIdx.x;
  if (idx < E) { prepos[idx] = atomicAdd(&ideg[ii[idx]], 1); return; } idx -= E;
  if (idx < nx0) { unsigned short b = f2bf(x0[idx]); x0b[idx] = b;
    Acat[(size_t)(idx >> 7) * KCAT + (idx & 127)] = b; return; } idx -= nx0;
  if (idx < D2 * EMB) { W1b[idx] = f2bf(W1[idx]); return; } idx -= D2 * EMB;
  if (idx < OUTD * D2) { W2b[idx] = f2bf(W2[idx]); return; } idx -= OUTD * D2;
  if (idx < OUTD * EMB) { RWcat[(size_t)(idx >> 7) * KCAT + (idx & 127)] = f2bf(res_W[idx]); return; } idx -= OUTD * EMB;
  if (idx < 64 * EMB) { int d = idx % EMB, rk = idx / EMB, k = rk & 7, r = rk >> 3;
    Amat1[idx] = A1[(size_t)r * EMB * RANK + (size_t)d * RANK + k]; return; } idx -= 64 * EMB;
  if (idx < 64 * D2) { int d = idx % D2, rk = idx / D2, k = rk & 7, r = rk >> 3;
    Amat2[idx] = A2[(size_t)r * D2 * RANK + (size_t)d * RANK + k]; return; } idx -= 64 * D2;
  if (idx < 64 * EMB) { int d = idx % EMB, rk = idx / EMB, k = rk & 7, r = rk >> 3;
    Bmat1b[idx] = f2bf(B1[(size_t)r * EMB * RANK + (size_t)d * RANK + k]); return; } idx -= 64 * EMB;
  if (idx < 64 * D2) { int d = idx % D2, rk = idx / D2, k = rk & 7, r = rk >> 3;
    Bmat2b[idx] = f2bf(B2[(size_t)r * D2 * RANK + (size_t)d * RANK + k]); }
}

// ---------------- Fold Matt + build M1T2 (plain transpose) + RWcat LoRA cols ----------------
__global__ void fold_build(const float* __restrict__ M1, const float* __restrict__ M2,
                           const float* __restrict__ attR1, const float* __restrict__ attR2,
                           unsigned short* __restrict__ M1T2, unsigned short* __restrict__ RWcat,
                           float* __restrict__ Matt1, float* __restrict__ Matt2) {
  int idx = blockIdx.x * 256 + threadIdx.x;
  if (idx < 512 * 64) { int c = idx >> 6, rk = idx & 63;
    M1T2[idx] = f2bf(M1[(size_t)rk * D2 + c]); return; } idx -= 512 * 64;
  if (idx < 256 * 64) { int c = idx >> 6, rk = idx & 63;
    RWcat[(size_t)c * KCAT + 128 + rk] = f2bf(M2[(size_t)rk * OUTD + c]); return; } idx -= 256 * 64;
  if (idx < 256) { int h = idx & 3, rk = idx >> 2;
    float s = 0.f;
    for (int c = 0; c < HID; ++c)
      s = fmaf(M1[(size_t)rk * D2 + h * HID + c], attR1[h * HID + c], s);
    Matt1[rk * 4 + h] = s; return; } idx -= 256;
  if (idx < 64) {
    float s = 0.f;
    for (int c = 0; c < OUTD; ++c) s = fmaf(M2[(size_t)idx * OUTD + c], attR2[c], s);
    Matt2[idx] = s; }
}

__global__ __launch_bounds__(1024) void exscan_kernel(const int* __restrict__ deg,
                                                      int* __restrict__ rowstart, int n) {
  __shared__ int wsum[16];
  int t = threadIdx.x;
  int lane = t & 63, wid = t >> 6;
  int carry = 0;
  for (int base = 0; base < n; base += 4096) {
    int i0 = base + t * 4;
    int v0 = 0, v1 = 0, v2 = 0, v3 = 0;
    if (i0 + 3 < n) {
      int4 vv = *(const int4*)(deg + i0);
      v0 = vv.x; v1 = vv.y; v2 = vv.z; v3 = vv.w;
    } else {
      if (i0 < n) v0 = deg[i0];
      if (i0 + 1 < n) v1 = deg[i0 + 1];
      if (i0 + 2 < n) v2 = deg[i0 + 2];
      if (i0 + 3 < n) v3 = deg[i0 + 3];
    }
    int tot = v0 + v1 + v2 + v3;
    int x = tot;
#pragma unroll
    for (int o = 1; o < 64; o <<= 1) {
      int y = __shfl_up(x, o, 64);
      if (lane >= o) x += y;
    }
    if (lane == 63) wsum[wid] = x;
    __syncthreads();
    if (t == 0) {
      int s = carry;
      for (int w2 = 0; w2 < 16; ++w2) { int tmp = wsum[w2]; wsum[w2] = s; s += tmp; }
      carry = s;
    }
    __syncthreads();
    int ex0 = x - tot + wsum[wid];
    if (i0 + 3 < n) {
      int4 ov; ov.x = ex0; ov.y = ex0 + v0; ov.z = ex0 + v0 + v1; ov.w = ex0 + v0 + v1 + v2;
      *(int4*)(rowstart + i0) = ov;
    } else {
      if (i0 < n) rowstart[i0] = ex0;
      if (i0 + 1 < n) rowstart[i0 + 1] = ex0 + v0;
      if (i0 + 2 < n) rowstart[i0 + 2] = ex0 + v0 + v1;
      if (i0 + 3 < n) rowstart[i0 + 3] = ex0 + v0 + v1 + v2;
    }
    __syncthreads();
  }
  if (t == 0) rowstart[n] = carry;
}

// ---------------- Layer-1 edge logits -> packed records at CSR slots ----------------
// rec1 (16 floats): [j, ex0, ex1, ex2 | ex3, rt, low0, low1 | low2..low5 | low6, low7, 0, 0]
__global__ void edge_alpha1(const int* __restrict__ ji, const int* __restrict__ ii,
                            const int* __restrict__ et, const int* __restrict__ rowstart,
                            const int* __restrict__ prepos,
                            const float* __restrict__ P1,
                            const float* __restrict__ al1, const float* __restrict__ ar1,
                            const float* __restrict__ relb1, const float* __restrict__ Matt1,
                            float4* __restrict__ recs1, int E) {
  int e = blockIdx.x * blockDim.x + threadIdx.x;
  if (e >= E) return;
  int j = ji[e], i = ii[e], rt = et[e];
  float4 lo0 = *(const float4*)(P1 + (size_t)j * 64 + rt * 8);
  float4 lo1 = *(const float4*)(P1 + (size_t)j * 64 + rt * 8 + 4);
  float low[RANK] = {lo0.x, lo0.y, lo0.z, lo0.w, lo1.x, lo1.y, lo1.z, lo1.w};
  float4 ali = *(const float4*)(al1 + (size_t)i * 4);
  float4 arj = *(const float4*)(ar1 + (size_t)j * 4);
  float4 rb  = *(const float4*)(relb1 + rt * 4);
  float a0 = ali.x + arj.x + rb.x;
  float a1 = ali.y + arj.y + rb.y;
  float a2 = ali.z + arj.z + rb.z;
  float a3 = ali.w + arj.w + rb.w;
#pragma unroll
  for (int k = 0; k < RANK; ++k) {
    float4 mk = *(const float4*)(Matt1 + ((rt * 8 + k) << 2));
    a0 = fmaf(low[k], mk.x, a0); a1 = fmaf(low[k], mk.y, a1);
    a2 = fmaf(low[k], mk.z, a2); a3 = fmaf(low[k], mk.w, a3);
  }
  a0 = (a0 > 0.f) ? a0 : NEG_SLOPE * a0;
  a1 = (a1 > 0.f) ? a1 : NEG_SLOPE * a1;
  a2 = (a2 > 0.f) ? a2 : NEG_SLOPE * a2;
  a3 = (a3 > 0.f) ? a3 : NEG_SLOPE * a3;
  float e0 = expf(a0), e1 = expf(a1), e2 = expf(a2), e3 = expf(a3);
  float4* rp = recs1 + (size_t)(rowstart[i] + prepos[e]) * 4;
  rp[0] = make_float4(__int_as_float(j), e0, e1, e2);
  rp[1] = make_float4(e3, __int_as_float(rt), low[0], low[1]);
  rp[2] = make_float4(low[2], low[3], low[4], low[5]);
  rp[3] = make_float4(low[6], low[7], 0.f, 0.f);
}

// ---------------- Layer-1 Q/den: writes normalized Q (bf16) + rden1[Nn][32] ----------------
__global__ __launch_bounds__(256) void qden1(const float4* __restrict__ recs1,
    const int* __restrict__ rowstart, unsigned short* __restrict__ Q1b,
    float* __restrict__ rden1, int Nn) {
  const int wid = threadIdx.x >> 6, lane = threadIdx.x & 63;
  const int i = blockIdx.x * 4 + wid;
  if (i >= Nn) return;
  const int rt_mine = lane >> 3, k = lane & 7;
  const int s0 = rowstart[i], deg = rowstart[i + 1] - s0;
  const float* rf = (const float*)recs1;
  float q0 = 0.f, q1 = 0.f, q2 = 0.f, q3 = 0.f;
  float d0 = 0.f, d1 = 0.f, d2 = 0.f, d3 = 0.f;
  float4 a0 = {}, a1 = {};
  float lw = 0.f;
  if (deg > 0) {
    a0 = recs1[(size_t)s0 * 4]; a1 = recs1[(size_t)s0 * 4 + 1];
    lw = rf[(size_t)s0 * 16 + 6 + k];
  }
  for (int p = 0; p < deg; ++p) {
    float4 b0 = a0, b1 = a1; float lwn = lw;
    if (p + 1 < deg) {
      b0 = recs1[(size_t)(s0 + p + 1) * 4]; b1 = recs1[(size_t)(s0 + p + 1) * 4 + 1];
      lwn = rf[(size_t)(s0 + p + 1) * 16 + 6 + k];
    }
    int rt = __float_as_int(a1.y);
    if (rt == rt_mine) {
      q0 = fmaf(a0.y, lw, q0); q1 = fmaf(a0.z, lw, q1);
      q2 = fmaf(a0.w, lw, q2); q3 = fmaf(a1.x, lw, q3);
      d0 += a0.y; d1 += a0.z; d2 += a0.w; d3 += a1.x;
    }
    a0 = b0; a1 = b1; lw = lwn;
  }
  float r0 = (d0 > 0.f) ? 1.f / d0 : 0.f;
  float r1 = (d1 > 0.f) ? 1.f / d1 : 0.f;
  float r2 = (d2 > 0.f) ? 1.f / d2 : 0.f;
  float r3 = (d3 > 0.f) ? 1.f / d3 : 0.f;
  size_t qb = (size_t)i * 256;
  Q1b[qb + lane]       = f2bf(q0 * r0);
  Q1b[qb + 64 + lane]  = f2bf(q1 * r1);
  Q1b[qb + 128 + lane] = f2bf(q2 * r2);
  Q1b[qb + 192 + lane] = f2bf(q3 * r3);
  if (k == 0) {
    size_t db = (size_t)i * 32;
    rden1[db + rt_mine]      = r0;
    rden1[db + 8 + rt_mine]  = r1;
    rden1[db + 16 + rt_mine] = r2;
    rden1[db + 24 + rt_mine] = r3;
  }
}

// ---------------- Layer-1 gather: wave per node, 8 ch/lane, w = ex * rden[h][rt] ----------------
__global__ __launch_bounds__(256) void node_agg1_lite(const float4* __restrict__ recs1,
    const int* __restrict__ rowstart, const unsigned short* __restrict__ z1b,
    const unsigned short* __restrict__ L1b, const float* __restrict__ rden1,
    unsigned short* __restrict__ h1out, int Nn) {
  const int wid = threadIdx.x >> 6;
  const int lane = threadIdx.x & 63;
  const int i = blockIdx.x * 4 + wid;
  if (i >= Nn) return;
  __shared__ float denS[4][32];
  if (lane < 32) denS[wid][lane] = rden1[(size_t)i * 32 + lane];
  // wave-synchronous LDS (each wave writes+reads its own row), no barrier
  const int s0 = rowstart[i];
  const int deg = rowstart[i + 1] - s0;
  const int c0 = lane * 8;                 // head = lane>>4
  const float* rf = (const float*)recs1;
  const int hb = (lane >> 4) << 3;         // head*8 base into denS
  float acc[8] = {};
  float4 r0 = {}, r1 = {}, r2 = {};
  float2 g0 = {}, g1 = {}, g2 = {};        // (ex3, rt)
  uint4 za = {}, zb = {};
  if (deg > 0) { r0 = recs1[(size_t)s0 * 4]; g0 = *(const float2*)(rf + (size_t)s0 * 16 + 4);
    za = *(const uint4*)(z1b + (size_t)__float_as_int(r0.x) * D2 + c0); }
  if (deg > 1) { r1 = recs1[(size_t)(s0 + 1) * 4]; g1 = *(const float2*)(rf + (size_t)(s0 + 1) * 16 + 4);
    zb = *(const uint4*)(z1b + (size_t)__float_as_int(r1.x) * D2 + c0); }
  if (deg > 2) { r2 = recs1[(size_t)(s0 + 2) * 4]; g2 = *(const float2*)(rf + (size_t)(s0 + 2) * 16 + 4); }
  for (int p = 0; p < deg; ++p) {
    float4 r3 = r2; float2 g3 = g2; uint4 zn = zb;
    if (p + 3 < deg) { r3 = recs1[(size_t)(s0 + p + 3) * 4];
                       g3 = *(const float2*)(rf + (size_t)(s0 + p + 3) * 16 + 4); }
    if (p + 2 < deg) zn = *(const uint4*)(z1b + (size_t)__float_as_int(r2.x) * D2 + c0);
    int rt = __float_as_int(g0.y);
    float wlo = (lane & 16) ? r0.z : r0.y;
    float whi = (lane & 16) ? g0.x : r0.w;
    float wt = ((lane & 32) ? whi : wlo) * denS[wid][hb + rt];
    acc[0] = fmaf(wt, bf2f((unsigned short)(za.x & 0xffff)), acc[0]);
    acc[1] = fmaf(wt, bf2f((unsigned short)(za.x >> 16)), acc[1]);
    acc[2] = fmaf(wt, bf2f((unsigned short)(za.y & 0xffff)), acc[2]);
    acc[3] = fmaf(wt, bf2f((unsigned short)(za.y >> 16)), acc[3]);
    acc[4] = fmaf(wt, bf2f((unsigned short)(za.z & 0xffff)), acc[4]);
    acc[5] = fmaf(wt, bf2f((unsigned short)(za.z >> 16)), acc[5]);
    acc[6] = fmaf(wt, bf2f((unsigned short)(za.w & 0xffff)), acc[6]);
    acc[7] = fmaf(wt, bf2f((unsigned short)(za.w >> 16)), acc[7]);
    r0 = r1; g0 = g1; r1 = r2; g1 = g2; r2 = r3; g2 = g3; za = zb; zb = zn;
  }
  uint4 lv = *(const uint4*)(L1b + (size_t)i * D2 + c0);  // lora + bias1 (pre-folded)
  unsigned lw[4] = {lv.x, lv.y, lv.z, lv.w};
  unsigned ov[4];
#pragma unroll
  for (int q = 0; q < 4; ++q) {
    float e0 = acc[2 * q]     + bf2f((unsigned short)(lw[q] & 0xffff));
    float e1 = acc[2 * q + 1] + bf2f((unsigned short)(lw[q] >> 16));
    e0 = e0 > 0.f ? e0 : expm1f(e0);
    e1 = e1 > 0.f ? e1 : expm1f(e1);
    ov[q] = (unsigned)f2bf(e0) | ((unsigned)f2bf(e1) << 16);
  }
  *(uint4*)(h1out + (size_t)i * D2 + c0) = make_uint4(ov[0], ov[1], ov[2], ov[3]);
}

// ---------------- Layer-2 edge logits -> packed records ----------------
// rec2 (12 floats): [j, rt, ex, low0 | low1..low4 | low5, low6, low7, 0]
__global__ void edge_alpha2(const int* __restrict__ ji, const int* __restrict__ ii,
                            const int* __restrict__ et, const int* __restrict__ rowstart,
                            const int* __restrict__ prepos,
                            const float* __restrict__ P2,
                            const float* __restrict__ al2, const float* __restrict__ ar2,
                            const float* __restrict__ relb2, const float* __restrict__ Matt2,
                            float4* __restrict__ recs2, int E, int Nn) {
  int e = blockIdx.x * blockDim.x + threadIdx.x;
  if (e >= E) return;
  int j = ji[e], i = ii[e], rt = et[e];
  float4 lo0 = *(const float4*)(P2 + (size_t)j * 64 + rt * 8);
  float4 lo1 = *(const float4*)(P2 + (size_t)j * 64 + rt * 8 + 4);
  float low[RANK] = {lo0.x, lo0.y, lo0.z, lo0.w, lo1.x, lo1.y, lo1.z, lo1.w};
  float a = al2[i] + al2[(size_t)Nn + i] + ar2[j] + ar2[(size_t)Nn + j] + relb2[rt];
#pragma unroll
  for (int k = 0; k < RANK; ++k) a = fmaf(low[k], Matt2[rt * RANK + k], a);
  a = (a > 0.f) ? a : NEG_SLOPE * a;
  float ex = expf(a);
  float4* rp = recs2 + (size_t)(rowstart[i] + prepos[e]) * 3;
  rp[0] = make_float4(__int_as_float(j), __int_as_float(rt), ex, low[0]);
  rp[1] = make_float4(low[1], low[2], low[3], low[4]);
  rp[2] = make_float4(low[5], low[6], low[7], 0.f);
}

// ---------------- Layer-2 Q/den: Q -> Acat cols 128..191, rden2[Nn][8] ----------------
__global__ __launch_bounds__(256) void qden2(const float4* __restrict__ recs2,
    const int* __restrict__ rowstart, unsigned short* __restrict__ Acat,
    float* __restrict__ rden2, int Nn) {
  const int wid = threadIdx.x >> 6, lane = threadIdx.x & 63;
  const int i = blockIdx.x * 4 + wid;
  if (i >= Nn) return;
  const int rt_mine = lane >> 3, k = lane & 7;
  const int s0 = rowstart[i], deg = rowstart[i + 1] - s0;
  const float* rf = (const float*)recs2;
  float q = 0.f, d = 0.f;
  float4 a0 = {}; float lw = 0.f;
  if (deg > 0) { a0 = recs2[(size_t)s0 * 3]; lw = rf[(size_t)s0 * 12 + 3 + k]; }
  for (int p = 0; p < deg; ++p) {
    float4 b0 = a0; float lwn = lw;
    if (p + 1 < deg) {
      b0 = recs2[(size_t)(s0 + p + 1) * 3];
      lwn = rf[(size_t)(s0 + p + 1) * 12 + 3 + k];
    }
    int rt = __float_as_int(a0.y);
    if (rt == rt_mine) { q = fmaf(a0.z, lw, q); d += a0.z; }
    a0 = b0; lw = lwn;
  }
  float rd = (d > 0.f) ? 1.f / d : 0.f;
  Acat[(size_t)i * KCAT + 128 + lane] = f2bf(q * rd);
  if (k == 0) rden2[(size_t)i * 8 + rt_mine] = rd;
}

// ---------------- Layer-2 gather + residual/lora/bias (o2) + LN -> out ----------------
__global__ __launch_bounds__(256) void node_agg2_lite(const float4* __restrict__ recs2,
    const int* __restrict__ rowstart, const unsigned short* __restrict__ z2b,
    const float* __restrict__ rden2, const float* __restrict__ o2,
    const float* __restrict__ ln_g, const float* __restrict__ ln_b,
    float* __restrict__ y, int Nn) {
  const int wid = threadIdx.x >> 6;
  const int lane = threadIdx.x & 63;
  const int i = blockIdx.x * 4 + wid;
  if (i >= Nn) return;
  __shared__ float denS[4][NRELS];
  if (lane < NRELS) denS[wid][lane] = rden2[(size_t)i * 8 + lane];
  // wave-synchronous LDS, no barrier
  const int s0 = rowstart[i];
  const int deg = rowstart[i + 1] - s0;
  const int c0 = lane * 4;
  float acc[4] = {};
  float4 r0 = {}, r1 = {}, r2 = {};
  uint2 za = make_uint2(0u, 0u), zb = make_uint2(0u, 0u);
  if (deg > 0) { r0 = recs2[(size_t)s0 * 3];
    za = *(const uint2*)(z2b + (size_t)__float_as_int(r0.x) * OUTD + c0); }
  if (deg > 1) { r1 = recs2[(size_t)(s0 + 1) * 3];
    zb = *(const uint2*)(z2b + (size_t)__float_as_int(r1.x) * OUTD + c0); }
  if (deg > 2) r2 = recs2[(size_t)(s0 + 2) * 3];
  for (int p = 0; p < deg; ++p) {
    float4 r3 = r2;
    uint2 zn = zb;
    if (p + 3 < deg) r3 = recs2[(size_t)(s0 + p + 3) * 3];
    if (p + 2 < deg)
      zn = *(const uint2*)(z2b + (size_t)__float_as_int(r2.x) * OUTD + c0);
    int rt = __float_as_int(r0.y);
    float wt = r0.z * denS[wid][rt];
    acc[0] = fmaf(wt, bf2f((unsigned short)(za.x & 0xffff)), acc[0]);
    acc[1] = fmaf(wt, bf2f((unsigned short)(za.x >> 16)), acc[1]);
    acc[2] = fmaf(wt, bf2f((unsigned short)(za.y & 0xffff)), acc[2]);
    acc[3] = fmaf(wt, bf2f((unsigned short)(za.y >> 16)), acc[3]);
    r0 = r1; r1 = r2; r2 = r3; za = zb; zb = zn;
  }
  float4 rsv = *(const float4*)(o2 + (size_t)i * OUTD + c0);   // residual+lora2+bias2+res_b
  float vv[4];
  vv[0] = acc[0] + rsv.x;
  vv[1] = acc[1] + rsv.y;
  vv[2] = acc[2] + rsv.z;
  vv[3] = acc[3] + rsv.w;
  float s = vv[0] + vv[1] + vv[2] + vv[3];
  for (int o = 32; o > 0; o >>= 1) s += __shfl_xor(s, o, 64);
  float mu = s * (1.f / OUTD);
  float q = 0.f;
#pragma unroll
  for (int k = 0; k < 4; ++k) { float d = vv[k] - mu; q += d * d; }
  for (int o = 32; o > 0; o >>= 1) q += __shfl_xor(q, o, 64);
  float rstd = rsqrtf(q * (1.f / OUTD) + LN_EPS);
  float4 g = *(const float4*)(ln_g + c0);
  float4 bb = *(const float4*)(ln_b + c0);
  float4 ov;
  ov.x = (vv[0] - mu) * rstd * g.x + bb.x;
  ov.y = (vv[1] - mu) * rstd * g.y + bb.y;
  ov.z = (vv[2] - mu) * rstd * g.z + bb.z;
  ov.w = (vv[3] - mu) * rstd * g.w + bb.w;
  *(float4*)(y + (size_t)i * OUTD + c0) = ov;
}

extern "C" void kernel_launch(void* const* d_in, const int* in_sizes, int n_in,
                              void* d_out, int out_size, void* d_ws, size_t ws_size,
                              hipStream_t stream) {
  const float* x0     = (const float*)d_in[0];
  const float* A1     = (const float*)d_in[1];
  const float* B1     = (const float*)d_in[2];
  const float* W1     = (const float*)d_in[3];
  const float* attL1  = (const float*)d_in[4];
  const float* attR1  = (const float*)d_in[5];
  const float* relb1  = (const float*)d_in[6];
  const float* bias1  = (const float*)d_in[7];
  const float* A2     = (const float*)d_in[8];
  const float* B2     = (const float*)d_in[9];
  const float* W2     = (const float*)d_in[10];
  const float* attL2  = (const float*)d_in[11];
  const float* attR2  = (const float*)d_in[12];
  const float* relb2  = (const float*)d_in[13];
  const float* bias2  = (const float*)d_in[14];
  const float* res_W  = (const float*)d_in[15];
  const float* res_b  = (const float*)d_in[16];
  const float* ln_g   = (const float*)d_in[17];
  const float* ln_b   = (const float*)d_in[18];
  const int*   eidx   = (const int*)d_in[19];
  const int*   etype  = (const int*)d_in[20];
  float* out = (float*)d_out;

  const int Nn = in_sizes[0] / EMB;     // 30000
  const int E  = in_sizes[20];          // 150000
  const int* ji = eidx;
  const int* ii = eidx + E;

  // ---- workspace carve-up (float units; all offsets stay 16B-aligned) ----
  float* w = (float*)d_ws;
  size_t off = 0;
  float* o2    = w + off; off += (size_t)Nn * OUTD;   // ALSO aliased as L1b (bf16 [Nn][512])
  float* P1    = w + off; off += (size_t)Nn * 64;     // ALSO aliased (with P2) as Q1b (bf16 [Nn][256])
  float* P2    = w + off; off += (size_t)Nn * 64;
  float* M1    = w + off; off += 64 * D2;
  float* M2    = w + off; off += 64 * OUTD;
  float* Amat1 = w + off; off += 64 * EMB;
  float* Amat2 = w + off; off += 64 * D2;
  float* Matt1 = w + off; off += 64 * 4;
  float* Matt2 = w + off; off += 64;
  float* al1   = w + off; off += (size_t)Nn * 4;
  float* ar1   = w + off; off += (size_t)Nn * 4;
  float* al2   = w + off; off += (size_t)Nn * 2;      // [2][Nn] col-block partials
  float* ar2   = w + off; off += (size_t)Nn * 2;
  float* rden1 = w + off; off += (size_t)Nn * 32;
  float* rden2 = w + off; off += (size_t)Nn * 8;
  float4* recs1 = (float4*)(w + off); off += (size_t)E * 16;
  float4* recs2 = (float4*)(w + off); off += (size_t)E * 12;
  unsigned short* z1b    = (unsigned short*)(w + off); off += (size_t)Nn * D2 / 2;
  unsigned short* z2b    = (unsigned short*)(w + off); off += (size_t)Nn * OUTD / 2;
  unsigned short* x0b    = (unsigned short*)(w + off); off += (size_t)Nn * EMB / 2;
  unsigned short* h1b    = (unsigned short*)(w + off); off += (size_t)Nn * D2 / 2;
  unsigned short* W1b    = (unsigned short*)(w + off); off += (size_t)D2 * EMB / 2;
  unsigned short* W2b    = (unsigned short*)(w + off); off += (size_t)OUTD * D2 / 2;
  unsigned short* Bmat1b = (unsigned short*)(w + off); off += (size_t)64 * EMB / 2;
  unsigned short* Bmat2b = (unsigned short*)(w + off); off += (size_t)64 * D2 / 2;
  unsigned short* Acat   = (unsigned short*)(w + off); off += (size_t)Nn * KCAT / 2;
  unsigned short* RWcat  = (unsigned short*)(w + off); off += (size_t)OUTD * KCAT / 2;
  unsigned short* M1T2   = (unsigned short*)(w + off); off += (size_t)512 * 64 / 2;
  int* ideg     = (int*)(w + off); off += (size_t)Nn;
  int* prepos   = (int*)(w + off); off += (size_t)E;
  int* rowstart = (int*)(w + off); off += (size_t)Nn + 1;
  (void)ws_size; (void)n_in; (void)out_size;

  // Aliases (lifetimes verified):
  //  Q1b over P1+P2: P1 dead after edge_alpha1; P2 written (z2 P-branch) after lora1 consumed Q1b.
  //  L1b over o2:    o2 written in layer 2 (after node_agg1_lite consumed L1b).
  unsigned short* Q1b = (unsigned short*)P1;   // [Nn][256] bf16
  unsigned short* L1b = (unsigned short*)o2;   // [Nn][512] bf16

  const int MT128 = (Nn + 127) / 128;
  const int NB4 = (Nn + 3) / 4;

  // 0) CSR hist fused into prep; conversions + LoRA re-layouts + concat copies
  (void)hipMemsetAsync(ideg, 0, (size_t)Nn * sizeof(int), stream);
  {
    int nx0 = Nn * EMB;
    int total = E + nx0 + D2 * EMB + OUTD * D2 + OUTD * EMB
              + 64 * EMB + 64 * D2 + 64 * EMB + 64 * D2;
    prep_all<<<(total + 255) / 256, 256, 0, stream>>>(x0, W1, W2, res_W, A1, A2, B1, B2,
        x0b, Acat, W1b, W2b, RWcat, Amat1, Amat2, Bmat1b, Bmat2b, ii, ideg, prepos, E, nx0);
  }
  exscan_kernel<<<1, 1024, 0, stream>>>(ideg, rowstart, Nn);

  // 1) M1/M2 (one dispatch) + folds/builds (one dispatch)
  gemm_abt2<<<dim3(D2 / 64 + OUTD / 64, 1), 256, 0, stream>>>(Amat1, W1, M1, Amat2, W2, M2);
  fold_build<<<(512 * 64 + 256 * 64 + 256 + 64 + 255) / 256, 256, 0, stream>>>(
      M1, M2, attR1, attR2, M1T2, RWcat, Matt1, Matt2);

  // 2) Layer-1: z1 GEMM (+fused att-dots, +fused P1 tile)
  gemm_tile<1, 0, 0, 1><<<dim3(MT128, D2 / 128 + 1), 256, 0, stream>>>(x0b, W1b, z1b, nullptr,
      Bmat1b, P1, Nn, D2, EMB, EMB, 0, nullptr, nullptr, attL1, attR1, al1, ar1);

  // 3) Layer-1 edge logits; Q/den; LoRA GEMM (K=64 per-head, +bias1); gather
  edge_alpha1<<<(E + 255) / 256, 256, 0, stream>>>(ji, ii, etype, rowstart, prepos, P1,
                                                   al1, ar1, relb1, Matt1, recs1, E);
  qden1<<<NB4, 256, 0, stream>>>(recs1, rowstart, Q1b, rden1, Nn);
  gemm_tile<0, 1, 0, 0><<<dim3(MT128, D2 / 128), 256, 0, stream>>>(Q1b, M1T2, L1b, nullptr,
      nullptr, nullptr, Nn, D2, 64, 256, 64, bias1, nullptr, nullptr, nullptr, nullptr, nullptr);
  node_agg1_lite<<<NB4, 256, 0, stream>>>(recs1, rowstart, z1b, L1b, rden1, h1b, Nn);

  // 4) Layer-2: z2 GEMM (+fused att-dot partials, +fused P2 tile)
  gemm_tile<2, 0, 0, 1><<<dim3(MT128, OUTD / 128 + 1), 256, 0, stream>>>(h1b, W2b, z2b, nullptr,
      Bmat2b, P2, Nn, OUTD, D2, D2, 0, nullptr, nullptr, attL2, attR2, al2, ar2);

  // 5) Layer-2 edge logits; Q/den (fills Acat); fused residual+lora+bias GEMM; gather + LN
  edge_alpha2<<<(E + 255) / 256, 256, 0, stream>>>(ji, ii, etype, rowstart, prepos, P2,
                                                   al2, ar2, relb2, Matt2, recs2, E, Nn);
  qden2<<<NB4, 256, 0, stream>>>(recs2, rowstart, Acat, rden2, Nn);
  gemm_tile<0, 1, 1, 0><<<dim3(MT128, OUTD / 128), 256, 0, stream>>>(Acat, RWcat, nullptr, o2,
      nullptr, nullptr, Nn, OUTD, KCAT, KCAT, 0, bias2, res_b, nullptr, nullptr, nullptr, nullptr);
  node_agg2_lite<<<NB4, 256, 0, stream>>>(recs2, rowstart, z2b, rden2, o2, ln_g, ln_b, out, Nn);
}

// Round 7
// 341.510 us; speedup vs baseline: 1.1004x; 1.0760x over previous
//
#include <hip/hip_runtime.h>
#include <cstddef>

#define NRELS 8
#define EMB 128
#define HID 128
#define OUTD 256
#define HEADS 4
#define RANK 8
#define D2 512            // HEADS*HID, conv2 input dim
#define KCAT 192          // EMB + 64, concatenated K for residual+lora2 GEMM
#define NEG_SLOPE 0.2f
#define LN_EPS 1e-5f

typedef short bf16x8 __attribute__((ext_vector_type(8)));   // 8 bf16 in 4 VGPRs
typedef float f32x4 __attribute__((ext_vector_type(4)));

__device__ __forceinline__ unsigned short f2bf(float f) {   // RNE
  union { float f; unsigned u; } v; v.f = f;
  unsigned u = v.u;
  return (unsigned short)((u + 0x7fffu + ((u >> 16) & 1u)) >> 16);
}
__device__ __forceinline__ float bf2f(unsigned short u) {
  union { unsigned u; float f; } v; v.u = (unsigned)u << 16; return v.f;
}

// async global->LDS, 16B per lane; LDS dest = wave-uniform base + lane*16
#define GLOAD16(ldsp, gp) \
  __builtin_amdgcn_global_load_lds((const __attribute__((address_space(1))) unsigned int*)(gp), \
      (__attribute__((address_space(3))) unsigned int*)(ldsp), 16, 0, 0)

// ---------------- Unified big-tile bf16 MFMA GEMM (128x128 tile, BK=32, LDS dbuf) ----------------
// Double-buffered global_load_lds staging; one __syncthreads per K-step.
// Chunk-XOR involution (2-way bank aliasing = free):
//   source col chunk = (lane&3)^((lane>>3)&3);  frag read chunk = quad^((r16>>1)&3)
// BIAS: add bias[col] (+ b1p[col] if F32OUT) before store.
// F32OUT: write fp32 to Cf. ELU: apply elu before bf16 store.
// PB: last blockIdx.y slice is a full-width f32 "P" GEMM vs Bp, out Cp stride 128.
// lda: A row stride; aoffc: per-col-block A column offset (block-diag A layouts).
template<int BIAS, int F32OUT, int ELU, int PB>
__global__ __launch_bounds__(256) void gemm_tile(const unsigned short* __restrict__ A,
    const unsigned short* __restrict__ B, unsigned short* __restrict__ C,
    float* __restrict__ Cf, const unsigned short* __restrict__ Bp,
    float* __restrict__ Cp, int M, int N, int K, int lda, int aoffc,
    const float* __restrict__ bias, const float* __restrict__ b1p) {
  __shared__ unsigned short As[2][128 * 32];
  __shared__ unsigned short Bs[2][128 * 32];
  const int tid = threadIdx.x;
  const int wave = tid >> 6;
  const int lane = tid & 63;
  const int wm = wave & 1;
  const int wn = wave >> 1;
  const int r16 = lane & 15;
  const int quad = lane >> 4;
  const int bm = blockIdx.x * 128;
  const int lr = lane >> 2;                                  // 0..15
  const int lc = ((lane & 3) ^ ((lane >> 3) & 3)) * 8;       // swizzled source col chunk
  const int rsw = (quad ^ ((r16 >> 1) & 3)) * 8;             // fragment read swizzle
  const bool isP = PB && (blockIdx.y == (int)gridDim.y - 1);
  const unsigned short* Bu = isP ? Bp : B;
  const int bn = isP ? 0 : blockIdx.y * 128;
  const unsigned short* Abase = A + (size_t)blockIdx.y * (isP ? 0 : aoffc);
  int ar0 = bm + wave * 32 + lr;      if (ar0 >= M) ar0 = M - 1;
  int ar1 = bm + wave * 32 + 16 + lr; if (ar1 >= M) ar1 = M - 1;
  const unsigned short* Ag0 = Abase + (size_t)ar0 * lda + lc;
  const unsigned short* Ag1 = Abase + (size_t)ar1 * lda + lc;
  const unsigned short* Bg0 = Bu + (size_t)(bn + wave * 32 + lr) * K + lc;
  const unsigned short* Bg1 = Bu + (size_t)(bn + wave * 32 + 16 + lr) * K + lc;
  f32x4 acc[4][4] = {};
  GLOAD16(As[0] + wave * 1024, Ag0);
  GLOAD16(As[0] + wave * 1024 + 512, Ag1);
  GLOAD16(Bs[0] + wave * 1024, Bg0);
  GLOAD16(Bs[0] + wave * 1024 + 512, Bg1);
  __syncthreads();
  int cur = 0;
  for (int k0 = 0; k0 < K; k0 += 32) {
    if (k0 + 32 < K) {
      GLOAD16(As[cur ^ 1] + wave * 1024, Ag0 + k0 + 32);
      GLOAD16(As[cur ^ 1] + wave * 1024 + 512, Ag1 + k0 + 32);
      GLOAD16(Bs[cur ^ 1] + wave * 1024, Bg0 + k0 + 32);
      GLOAD16(Bs[cur ^ 1] + wave * 1024 + 512, Bg1 + k0 + 32);
    }
    bf16x8 af[4], bfr[4];
#pragma unroll
    for (int mi = 0; mi < 4; ++mi)
      af[mi] = *(const bf16x8*)(As[cur] + (wm * 64 + mi * 16 + r16) * 32 + rsw);
#pragma unroll
    for (int ni = 0; ni < 4; ++ni)
      bfr[ni] = *(const bf16x8*)(Bs[cur] + (wn * 64 + ni * 16 + r16) * 32 + rsw);
#pragma unroll
    for (int mi = 0; mi < 4; ++mi)
#pragma unroll
      for (int ni = 0; ni < 4; ++ni)
        acc[mi][ni] = __builtin_amdgcn_mfma_f32_16x16x32_bf16(af[mi], bfr[ni], acc[mi][ni], 0, 0, 0);
    __syncthreads();
    cur ^= 1;
  }
  float bcol[4];
  if (BIAS) {
#pragma unroll
    for (int ni = 0; ni < 4; ++ni) {
      int cn = bn + wn * 64 + ni * 16 + r16;
      bcol[ni] = bias[cn];
      if (F32OUT) bcol[ni] += b1p[cn];
    }
  }
#pragma unroll
  for (int mi = 0; mi < 4; ++mi)
#pragma unroll
    for (int ni = 0; ni < 4; ++ni)
#pragma unroll
      for (int r = 0; r < 4; ++r) {
        int row = bm + wm * 64 + mi * 16 + quad * 4 + r;
        if (row < M) {
          int col = wn * 64 + ni * 16 + r16;
          float v = acc[mi][ni][r];
          if (isP) {
            Cp[(size_t)row * 128 + col] = v;
          } else {
            if (BIAS) v += bcol[ni];
            if (ELU) v = v > 0.f ? v : expm1f(v);
            size_t idx = (size_t)row * N + bn + col;
            if (F32OUT) Cf[idx] = v;
            else        C[idx] = f2bf(v);
          }
        }
      }
}

// ---------------- fp32 tiled GEMM, both tiny M1/M2 precomputes in one dispatch ----------------
__global__ __launch_bounds__(256) void gemm_abt2(const float* __restrict__ Amat1,
    const float* __restrict__ W1, float* __restrict__ M1o,
    const float* __restrict__ Amat2, const float* __restrict__ W2, float* __restrict__ M2o) {
  const float* A; const float* B; float* C; int N, K, bn;
  if (blockIdx.x < D2 / 64) { A = Amat1; B = W1; C = M1o; N = D2; K = EMB; bn = blockIdx.x * 64; }
  else { A = Amat2; B = W2; C = M2o; N = OUTD; K = D2; bn = (blockIdx.x - D2 / 64) * 64; }
  __shared__ float As[32][64];
  __shared__ float Bs[32][64];
  const int tid = threadIdx.x;
  const int tx = tid & 15;
  const int ty = tid >> 4;
  const int lr = tid & 63;
  const int lq = tid >> 6;
  float acc[4][4] = {};
  for (int k0 = 0; k0 < K; k0 += 32) {
#pragma unroll
    for (int s = 0; s < 2; ++s) {
      const int q = lq + s * 4;
      float4 va = *(const float4*)(A + (size_t)lr * K + k0 + q * 4);
      As[q * 4 + 0][lr] = va.x; As[q * 4 + 1][lr] = va.y;
      As[q * 4 + 2][lr] = va.z; As[q * 4 + 3][lr] = va.w;
      float4 vb = *(const float4*)(B + (size_t)(bn + lr) * K + k0 + q * 4);
      Bs[q * 4 + 0][lr] = vb.x; Bs[q * 4 + 1][lr] = vb.y;
      Bs[q * 4 + 2][lr] = vb.z; Bs[q * 4 + 3][lr] = vb.w;
    }
    __syncthreads();
#pragma unroll
    for (int kk = 0; kk < 32; ++kk) {
      float a[4], b[4];
#pragma unroll
      for (int i2 = 0; i2 < 4; ++i2) { a[i2] = As[kk][ty * 4 + i2]; b[i2] = Bs[kk][tx * 4 + i2]; }
#pragma unroll
      for (int i2 = 0; i2 < 4; ++i2)
#pragma unroll
        for (int j2 = 0; j2 < 4; ++j2)
          acc[i2][j2] = fmaf(a[i2], b[j2], acc[i2][j2]);
    }
    __syncthreads();
  }
#pragma unroll
  for (int i2 = 0; i2 < 4; ++i2)
#pragma unroll
    for (int j2 = 0; j2 < 4; ++j2)
      C[(size_t)(ty * 4 + i2) * N + bn + tx * 4 + j2] = acc[i2][j2];
}

// ---------------- Fused prep: CSR hist + bf16 conversions + LoRA re-layouts + concat ----------------
__global__ void prep_all(const float* __restrict__ x0, const float* __restrict__ W2,
    const float* __restrict__ res_W,
    const float* __restrict__ A1, const float* __restrict__ A2,
    const float* __restrict__ B1, const float* __restrict__ B2,
    unsigned short* __restrict__ x0b, unsigned short* __restrict__ Acat,
    unsigned short* __restrict__ W2b, unsigned short* __restrict__ RWcat,
    float* __restrict__ Amat1, float* __restrict__ Amat2,
    unsigned short* __restrict__ Bmat1b, unsigned short* __restrict__ Bmat2b,
    const int* __restrict__ ii, int* __restrict__ ideg, int* __restrict__ prepos,
    int E, int nx0) {
  int idx = blockIdx.x * 256 + threadIdx.x;
  if (idx < E) { prepos[idx] = atomicAdd(&ideg[ii[idx]], 1); return; } idx -= E;
  if (idx < nx0) { unsigned short b = f2bf(x0[idx]); x0b[idx] = b;
    Acat[(size_t)(idx >> 7) * KCAT + (idx & 127)] = b; return; } idx -= nx0;
  if (idx < OUTD * D2) { W2b[idx] = f2bf(W2[idx]); return; } idx -= OUTD * D2;
  if (idx < OUTD * EMB) { RWcat[(size_t)(idx >> 7) * KCAT + (idx & 127)] = f2bf(res_W[idx]); return; } idx -= OUTD * EMB;
  if (idx < 64 * EMB) { int d = idx % EMB, rk = idx / EMB, k = rk & 7, r = rk >> 3;
    Amat1[idx] = A1[(size_t)r * EMB * RANK + (size_t)d * RANK + k]; return; } idx -= 64 * EMB;
  if (idx < 64 * D2) { int d = idx % D2, rk = idx / D2, k = rk & 7, r = rk >> 3;
    Amat2[idx] = A2[(size_t)r * D2 * RANK + (size_t)d * RANK + k]; return; } idx -= 64 * D2;
  if (idx < 64 * EMB) { int d = idx % EMB, rk = idx / EMB, k = rk & 7, r = rk >> 3;
    Bmat1b[idx] = f2bf(B1[(size_t)r * EMB * RANK + (size_t)d * RANK + k]); return; } idx -= 64 * EMB;
  if (idx < 64 * D2) { int d = idx % D2, rk = idx / D2, k = rk & 7, r = rk >> 3;
    Bmat2b[idx] = f2bf(B2[(size_t)r * D2 * RANK + (size_t)d * RANK + k]); }
}

// ---------------- Fold/build all small operands ----------------
// Bcat1 [512][192]: row c = [W1[c][0..127] | M1[rk][c], rk<64]   (msg GEMM B)
// RWcat cols 128..191: M2 transpose.
// Bp1ext [128][128]: rows 0-63 Bmat1b; 64-67 aw1L[h]; 68-71 aw1R[h]; rest 0.
// Bp2ext [128][512]: rows 0-63 Bmat2b; 64 aw2L; 65 aw2R; rest 0.
// Matt1 [64][4], Matt2 [64].
__global__ void fold_build(const float* __restrict__ M1, const float* __restrict__ M2,
    const float* __restrict__ W1, const float* __restrict__ W2,
    const float* __restrict__ attL1, const float* __restrict__ attR1,
    const float* __restrict__ attL2, const float* __restrict__ attR2,
    const unsigned short* __restrict__ Bmat1b, const unsigned short* __restrict__ Bmat2b,
    unsigned short* __restrict__ Bcat1, unsigned short* __restrict__ RWcat,
    unsigned short* __restrict__ Bp1ext, unsigned short* __restrict__ Bp2ext,
    float* __restrict__ Matt1, float* __restrict__ Matt2) {
  int idx = blockIdx.x * 256 + threadIdx.x;
  if (idx < 512 * 192) { int c = idx / 192, t = idx % 192;
    float v = (t < 128) ? W1[(size_t)c * EMB + t] : M1[(size_t)(t - 128) * D2 + c];
    Bcat1[idx] = f2bf(v); return; } idx -= 512 * 192;
  if (idx < 256 * 64) { int c = idx >> 6, rk = idx & 63;
    RWcat[(size_t)c * KCAT + 128 + rk] = f2bf(M2[(size_t)rk * OUTD + c]); return; } idx -= 256 * 64;
  if (idx < 128 * 128) { int r = idx >> 7, d = idx & 127;
    unsigned short v;
    if (r < 64) v = Bmat1b[r * 128 + d];
    else if (r < 72) { int h = (r - 64) & 3;
      const float* att = (r < 68) ? attL1 : attR1;
      float s = 0.f;
      for (int c = 0; c < HID; ++c)
        s = fmaf(W1[(size_t)(h * HID + c) * EMB + d], att[h * HID + c], s);
      v = f2bf(s); }
    else v = 0;
    Bp1ext[idx] = v; return; } idx -= 128 * 128;
  if (idx < 128 * 512) { int r = idx >> 9, d = idx & 511;
    unsigned short v;
    if (r < 64) v = Bmat2b[r * 512 + d];
    else if (r < 66) { const float* att = (r == 64) ? attL2 : attR2;
      float s = 0.f;
      for (int c = 0; c < OUTD; ++c)
        s = fmaf(W2[(size_t)c * D2 + d], att[c], s);
      v = f2bf(s); }
    else v = 0;
    Bp2ext[idx] = v; return; } idx -= 128 * 512;
  if (idx < 256) { int h = idx & 3, rk = idx >> 2;
    float s = 0.f;
    for (int c = 0; c < HID; ++c)
      s = fmaf(M1[(size_t)rk * D2 + h * HID + c], attR1[h * HID + c], s);
    Matt1[rk * 4 + h] = s; return; } idx -= 256;
  if (idx < 64) {
    float s = 0.f;
    for (int c = 0; c < OUTD; ++c) s = fmaf(M2[(size_t)idx * OUTD + c], attR2[c], s);
    Matt2[idx] = s; }
}

__global__ __launch_bounds__(1024) void exscan_kernel(const int* __restrict__ deg,
                                                      int* __restrict__ rowstart, int n) {
  __shared__ int wsum[16];
  int t = threadIdx.x;
  int lane = t & 63, wid = t >> 6;
  int carry = 0;
  for (int base = 0; base < n; base += 4096) {
    int i0 = base + t * 4;
    int v0 = 0, v1 = 0, v2 = 0, v3 = 0;
    if (i0 + 3 < n) {
      int4 vv = *(const int4*)(deg + i0);
      v0 = vv.x; v1 = vv.y; v2 = vv.z; v3 = vv.w;
    } else {
      if (i0 < n) v0 = deg[i0];
      if (i0 + 1 < n) v1 = deg[i0 + 1];
      if (i0 + 2 < n) v2 = deg[i0 + 2];
      if (i0 + 3 < n) v3 = deg[i0 + 3];
    }
    int tot = v0 + v1 + v2 + v3;
    int x = tot;
#pragma unroll
    for (int o = 1; o < 64; o <<= 1) {
      int y = __shfl_up(x, o, 64);
      if (lane >= o) x += y;
    }
    if (lane == 63) wsum[wid] = x;
    __syncthreads();
    if (t == 0) {
      int s = carry;
      for (int w2 = 0; w2 < 16; ++w2) { int tmp = wsum[w2]; wsum[w2] = s; s += tmp; }
      carry = s;
    }
    __syncthreads();
    int ex0 = x - tot + wsum[wid];
    if (i0 + 3 < n) {
      int4 ov; ov.x = ex0; ov.y = ex0 + v0; ov.z = ex0 + v0 + v1; ov.w = ex0 + v0 + v1 + v2;
      *(int4*)(rowstart + i0) = ov;
    } else {
      if (i0 < n) rowstart[i0] = ex0;
      if (i0 + 1 < n) rowstart[i0 + 1] = ex0 + v0;
      if (i0 + 2 < n) rowstart[i0 + 2] = ex0 + v0 + v1;
      if (i0 + 3 < n) rowstart[i0 + 3] = ex0 + v0 + v1 + v2;
    }
    __syncthreads();
  }
  if (t == 0) rowstart[n] = carry;
}

// ---------------- Layer-1 edge logits -> packed records at CSR slots ----------------
// Cp1 [Nn][128] f32: cols 0-63 = P1[rt*8+k]; 64-67 = al1[h]; 68-71 = ar1[h].
// rec1 (16 floats): [j, ex0, ex1, ex2 | ex3, rt, low0, low1 | low2..low5 | low6, low7, 0, 0]
__global__ void edge_alpha1(const int* __restrict__ ji, const int* __restrict__ ii,
                            const int* __restrict__ et, const int* __restrict__ rowstart,
                            const int* __restrict__ prepos,
                            const float* __restrict__ Cp1,
                            const float* __restrict__ relb1, const float* __restrict__ Matt1,
                            float4* __restrict__ recs1, int E) {
  int e = blockIdx.x * blockDim.x + threadIdx.x;
  if (e >= E) return;
  int j = ji[e], i = ii[e], rt = et[e];
  float4 lo0 = *(const float4*)(Cp1 + (size_t)j * 128 + rt * 8);
  float4 lo1 = *(const float4*)(Cp1 + (size_t)j * 128 + rt * 8 + 4);
  float low[RANK] = {lo0.x, lo0.y, lo0.z, lo0.w, lo1.x, lo1.y, lo1.z, lo1.w};
  float4 ali = *(const float4*)(Cp1 + (size_t)i * 128 + 64);
  float4 arj = *(const float4*)(Cp1 + (size_t)j * 128 + 68);
  float4 rb  = *(const float4*)(relb1 + rt * 4);
  float a0 = ali.x + arj.x + rb.x;
  float a1 = ali.y + arj.y + rb.y;
  float a2 = ali.z + arj.z + rb.z;
  float a3 = ali.w + arj.w + rb.w;
#pragma unroll
  for (int k = 0; k < RANK; ++k) {
    float4 mk = *(const float4*)(Matt1 + ((rt * 8 + k) << 2));
    a0 = fmaf(low[k], mk.x, a0); a1 = fmaf(low[k], mk.y, a1);
    a2 = fmaf(low[k], mk.z, a2); a3 = fmaf(low[k], mk.w, a3);
  }
  a0 = (a0 > 0.f) ? a0 : NEG_SLOPE * a0;
  a1 = (a1 > 0.f) ? a1 : NEG_SLOPE * a1;
  a2 = (a2 > 0.f) ? a2 : NEG_SLOPE * a2;
  a3 = (a3 > 0.f) ? a3 : NEG_SLOPE * a3;
  float e0 = expf(a0), e1 = expf(a1), e2 = expf(a2), e3 = expf(a3);
  float4* rp = recs1 + (size_t)(rowstart[i] + prepos[e]) * 4;
  rp[0] = make_float4(__int_as_float(j), e0, e1, e2);
  rp[1] = make_float4(e3, __int_as_float(rt), low[0], low[1]);
  rp[2] = make_float4(low[2], low[3], low[4], low[5]);
  rp[3] = make_float4(low[6], low[7], 0.f, 0.f);
}

// ---------------- Layer-1 fused Q/den + x0-gather: fills XQ1 [Nn][4x(128 Xw | 64 Q)] ----------------
__global__ __launch_bounds__(256) void agg1f(const float4* __restrict__ recs1,
    const int* __restrict__ rowstart, const unsigned short* __restrict__ x0b,
    unsigned short* __restrict__ XQ1, int Nn) {
  __shared__ float denS[4][32];          // [wid][h*8+rt]
  const int wid = threadIdx.x >> 6, lane = threadIdx.x & 63;
  const int i = blockIdx.x * 4 + wid;
  if (i >= Nn) return;
  const int rt_mine = lane >> 3, k = lane & 7;
  const int s0 = rowstart[i], deg = rowstart[i + 1] - s0;
  const float* rf = (const float*)recs1;
  const size_t xb = (size_t)i * 768;
  // ---- Phase A: LoRA Q sums + softmax denominators (lane = rt*8+k) ----
  {
    float q0 = 0.f, q1 = 0.f, q2 = 0.f, q3 = 0.f;
    float d0 = 0.f, d1 = 0.f, d2 = 0.f, d3 = 0.f;
    float4 a0 = {}, a1 = {};
    float lw = 0.f;
    if (deg > 0) {
      a0 = recs1[(size_t)s0 * 4]; a1 = recs1[(size_t)s0 * 4 + 1];
      lw = rf[(size_t)s0 * 16 + 6 + k];
    }
    for (int p = 0; p < deg; ++p) {
      float4 b0 = a0, b1 = a1; float lwn = lw;
      if (p + 1 < deg) {
        b0 = recs1[(size_t)(s0 + p + 1) * 4]; b1 = recs1[(size_t)(s0 + p + 1) * 4 + 1];
        lwn = rf[(size_t)(s0 + p + 1) * 16 + 6 + k];
      }
      int rt = __float_as_int(a1.y);
      if (rt == rt_mine) {
        q0 = fmaf(a0.y, lw, q0); q1 = fmaf(a0.z, lw, q1);
        q2 = fmaf(a0.w, lw, q2); q3 = fmaf(a1.x, lw, q3);
        d0 += a0.y; d1 += a0.z; d2 += a0.w; d3 += a1.x;
      }
      a0 = b0; a1 = b1; lw = lwn;
    }
    float r0 = (d0 > 0.f) ? 1.f / d0 : 0.f;
    float r1 = (d1 > 0.f) ? 1.f / d1 : 0.f;
    float r2 = (d2 > 0.f) ? 1.f / d2 : 0.f;
    float r3 = (d3 > 0.f) ? 1.f / d3 : 0.f;
    XQ1[xb + 0 * 192 + 128 + lane] = f2bf(q0 * r0);
    XQ1[xb + 1 * 192 + 128 + lane] = f2bf(q1 * r1);
    XQ1[xb + 2 * 192 + 128 + lane] = f2bf(q2 * r2);
    XQ1[xb + 3 * 192 + 128 + lane] = f2bf(q3 * r3);
    if (k == 0) {
      denS[wid][rt_mine]      = r0;
      denS[wid][8 + rt_mine]  = r1;
      denS[wid][16 + rt_mine] = r2;
      denS[wid][24 + rt_mine] = r3;
    }
  }
  // wave-synchronous LDS: same wave wrote denS[wid], no barrier needed
  // ---- Phase B: weighted x0 gather (lane = 2 cols, records now L1-hot) ----
  const int c0 = lane * 2;
  float acc[8] = {};
  float4 r0 = {}, r1 = {};
  float2 g0 = {}, g1 = {};
  unsigned za = 0u, zn0 = 0u;
  if (deg > 0) { r0 = recs1[(size_t)s0 * 4]; g0 = *(const float2*)(rf + (size_t)s0 * 16 + 4);
    za = *(const unsigned*)(x0b + (size_t)__float_as_int(r0.x) * 128 + c0); }
  if (deg > 1) { r1 = recs1[(size_t)(s0 + 1) * 4]; g1 = *(const float2*)(rf + (size_t)(s0 + 1) * 16 + 4); }
  for (int p = 0; p < deg; ++p) {
    float4 r2 = r1; float2 g2 = g1; unsigned zb = za;
    if (p + 2 < deg) { r2 = recs1[(size_t)(s0 + p + 2) * 4];
                       g2 = *(const float2*)(rf + (size_t)(s0 + p + 2) * 16 + 4); }
    if (p + 1 < deg) zb = *(const unsigned*)(x0b + (size_t)__float_as_int(r1.x) * 128 + c0);
    int rt = __float_as_int(g0.y);
    float w0 = r0.y * denS[wid][rt];
    float w1 = r0.z * denS[wid][8 + rt];
    float w2 = r0.w * denS[wid][16 + rt];
    float w3 = g0.x * denS[wid][24 + rt];
    float v0 = bf2f((unsigned short)(za & 0xffff));
    float v1 = bf2f((unsigned short)(za >> 16));
    acc[0] = fmaf(w0, v0, acc[0]); acc[1] = fmaf(w0, v1, acc[1]);
    acc[2] = fmaf(w1, v0, acc[2]); acc[3] = fmaf(w1, v1, acc[3]);
    acc[4] = fmaf(w2, v0, acc[4]); acc[5] = fmaf(w2, v1, acc[5]);
    acc[6] = fmaf(w3, v0, acc[6]); acc[7] = fmaf(w3, v1, acc[7]);
    r0 = r1; g0 = g1; r1 = r2; g1 = g2; za = zb;
  }
#pragma unroll
  for (int h = 0; h < 4; ++h) {
    unsigned pv = (unsigned)f2bf(acc[2 * h]) | ((unsigned)f2bf(acc[2 * h + 1]) << 16);
    *(unsigned*)(XQ1 + xb + h * 192 + c0) = pv;
  }
}

// ---------------- Layer-2 edge logits -> packed records ----------------
// Cp2 [Nn][128] f32: cols 0-63 = P2; col 64 = al2; col 65 = ar2.
// rec2 (12 floats): [j, rt, ex, low0 | low1..low4 | low5, low6, low7, 0]
__global__ void edge_alpha2(const int* __restrict__ ji, const int* __restrict__ ii,
                            const int* __restrict__ et, const int* __restrict__ rowstart,
                            const int* __restrict__ prepos,
                            const float* __restrict__ Cp2,
                            const float* __restrict__ relb2, const float* __restrict__ Matt2,
                            float4* __restrict__ recs2, int E) {
  int e = blockIdx.x * blockDim.x + threadIdx.x;
  if (e >= E) return;
  int j = ji[e], i = ii[e], rt = et[e];
  float4 lo0 = *(const float4*)(Cp2 + (size_t)j * 128 + rt * 8);
  float4 lo1 = *(const float4*)(Cp2 + (size_t)j * 128 + rt * 8 + 4);
  float low[RANK] = {lo0.x, lo0.y, lo0.z, lo0.w, lo1.x, lo1.y, lo1.z, lo1.w};
  float a = Cp2[(size_t)i * 128 + 64] + Cp2[(size_t)j * 128 + 65] + relb2[rt];
#pragma unroll
  for (int k = 0; k < RANK; ++k) a = fmaf(low[k], Matt2[rt * RANK + k], a);
  a = (a > 0.f) ? a : NEG_SLOPE * a;
  float ex = expf(a);
  float4* rp = recs2 + (size_t)(rowstart[i] + prepos[e]) * 3;
  rp[0] = make_float4(__int_as_float(j), __int_as_float(rt), ex, low[0]);
  rp[1] = make_float4(low[1], low[2], low[3], low[4]);
  rp[2] = make_float4(low[5], low[6], low[7], 0.f);
}

// ---------------- Layer-2 Q/den: Q -> Acat cols 128..191, rden2[Nn][8] ----------------
__global__ __launch_bounds__(256) void qden2(const float4* __restrict__ recs2,
    const int* __restrict__ rowstart, unsigned short* __restrict__ Acat,
    float* __restrict__ rden2, int Nn) {
  const int wid = threadIdx.x >> 6, lane = threadIdx.x & 63;
  const int i = blockIdx.x * 4 + wid;
  if (i >= Nn) return;
  const int rt_mine = lane >> 3, k = lane & 7;
  const int s0 = rowstart[i], deg = rowstart[i + 1] - s0;
  const float* rf = (const float*)recs2;
  float q = 0.f, d = 0.f;
  float4 a0 = {}; float lw = 0.f;
  if (deg > 0) { a0 = recs2[(size_t)s0 * 3]; lw = rf[(size_t)s0 * 12 + 3 + k]; }
  for (int p = 0; p < deg; ++p) {
    float4 b0 = a0; float lwn = lw;
    if (p + 1 < deg) {
      b0 = recs2[(size_t)(s0 + p + 1) * 3];
      lwn = rf[(size_t)(s0 + p + 1) * 12 + 3 + k];
    }
    int rt = __float_as_int(a0.y);
    if (rt == rt_mine) { q = fmaf(a0.z, lw, q); d += a0.z; }
    a0 = b0; lw = lwn;
  }
  float rd = (d > 0.f) ? 1.f / d : 0.f;
  Acat[(size_t)i * KCAT + 128 + lane] = f2bf(q * rd);
  if (k == 0) rden2[(size_t)i * 8 + rt_mine] = rd;
}

// ---------------- Layer-2 gather + residual/lora/bias (o2) + LN -> out ----------------
__global__ __launch_bounds__(256) void node_agg2_lite(const float4* __restrict__ recs2,
    const int* __restrict__ rowstart, const unsigned short* __restrict__ z2b,
    const float* __restrict__ rden2, const float* __restrict__ o2,
    const float* __restrict__ ln_g, const float* __restrict__ ln_b,
    float* __restrict__ y, int Nn) {
  const int wid = threadIdx.x >> 6;
  const int lane = threadIdx.x & 63;
  const int i = blockIdx.x * 4 + wid;
  if (i >= Nn) return;
  __shared__ float denS[4][NRELS];
  if (lane < NRELS) denS[wid][lane] = rden2[(size_t)i * 8 + lane];
  // wave-synchronous LDS, no barrier
  const int s0 = rowstart[i];
  const int deg = rowstart[i + 1] - s0;
  const int c0 = lane * 4;
  float acc[4] = {};
  float4 r0 = {}, r1 = {}, r2 = {};
  uint2 za = make_uint2(0u, 0u), zb = make_uint2(0u, 0u);
  if (deg > 0) { r0 = recs2[(size_t)s0 * 3];
    za = *(const uint2*)(z2b + (size_t)__float_as_int(r0.x) * OUTD + c0); }
  if (deg > 1) { r1 = recs2[(size_t)(s0 + 1) * 3];
    zb = *(const uint2*)(z2b + (size_t)__float_as_int(r1.x) * OUTD + c0); }
  if (deg > 2) r2 = recs2[(size_t)(s0 + 2) * 3];
  for (int p = 0; p < deg; ++p) {
    float4 r3 = r2;
    uint2 zn = zb;
    if (p + 3 < deg) r3 = recs2[(size_t)(s0 + p + 3) * 3];
    if (p + 2 < deg)
      zn = *(const uint2*)(z2b + (size_t)__float_as_int(r2.x) * OUTD + c0);
    int rt = __float_as_int(r0.y);
    float wt = r0.z * denS[wid][rt];
    acc[0] = fmaf(wt, bf2f((unsigned short)(za.x & 0xffff)), acc[0]);
    acc[1] = fmaf(wt, bf2f((unsigned short)(za.x >> 16)), acc[1]);
    acc[2] = fmaf(wt, bf2f((unsigned short)(za.y & 0xffff)), acc[2]);
    acc[3] = fmaf(wt, bf2f((unsigned short)(za.y >> 16)), acc[3]);
    r0 = r1; r1 = r2; r2 = r3; za = zb; zb = zn;
  }
  float4 rsv = *(const float4*)(o2 + (size_t)i * OUTD + c0);   // residual+lora2+bias2+res_b
  float vv[4];
  vv[0] = acc[0] + rsv.x;
  vv[1] = acc[1] + rsv.y;
  vv[2] = acc[2] + rsv.z;
  vv[3] = acc[3] + rsv.w;
  float s = vv[0] + vv[1] + vv[2] + vv[3];
  for (int o = 32; o > 0; o >>= 1) s += __shfl_xor(s, o, 64);
  float mu = s * (1.f / OUTD);
  float q = 0.f;
#pragma unroll
  for (int k = 0; k < 4; ++k) { float d = vv[k] - mu; q += d * d; }
  for (int o = 32; o > 0; o >>= 1) q += __shfl_xor(q, o, 64);
  float rstd = rsqrtf(q * (1.f / OUTD) + LN_EPS);
  float4 g = *(const float4*)(ln_g + c0);
  float4 bb = *(const float4*)(ln_b + c0);
  float4 ov;
  ov.x = (vv[0] - mu) * rstd * g.x + bb.x;
  ov.y = (vv[1] - mu) * rstd * g.y + bb.y;
  ov.z = (vv[2] - mu) * rstd * g.z + bb.z;
  ov.w = (vv[3] - mu) * rstd * g.w + bb.w;
  *(float4*)(y + (size_t)i * OUTD + c0) = ov;
}

extern "C" void kernel_launch(void* const* d_in, const int* in_sizes, int n_in,
                              void* d_out, int out_size, void* d_ws, size_t ws_size,
                              hipStream_t stream) {
  const float* x0     = (const float*)d_in[0];
  const float* A1     = (const float*)d_in[1];
  const float* B1     = (const float*)d_in[2];
  const float* W1     = (const float*)d_in[3];
  const float* attL1  = (const float*)d_in[4];
  const float* attR1  = (const float*)d_in[5];
  const float* relb1  = (const float*)d_in[6];
  const float* bias1  = (const float*)d_in[7];
  const float* A2     = (const float*)d_in[8];
  const float* B2     = (const float*)d_in[9];
  const float* W2     = (const float*)d_in[10];
  const float* attL2  = (const float*)d_in[11];
  const float* attR2  = (const float*)d_in[12];
  const float* relb2  = (const float*)d_in[13];
  const float* bias2  = (const float*)d_in[14];
  const float* res_W  = (const float*)d_in[15];
  const float* res_b  = (const float*)d_in[16];
  const float* ln_g   = (const float*)d_in[17];
  const float* ln_b   = (const float*)d_in[18];
  const int*   eidx   = (const int*)d_in[19];
  const int*   etype  = (const int*)d_in[20];
  float* out = (float*)d_out;

  const int Nn = in_sizes[0] / EMB;     // 30000
  const int E  = in_sizes[20];          // 150000
  const int* ji = eidx;
  const int* ii = eidx + E;

  // ---- workspace carve-up (float units; all offsets stay 16B-aligned) ----
  float* w = (float*)d_ws;
  size_t off = 0;
  float* o2    = w + off; off += (size_t)Nn * OUTD;
  float* Cp1   = w + off; off += (size_t)Nn * 128;    // P1 + al1/ar1
  float* Cp2   = w + off; off += (size_t)Nn * 128;    // P2 + al2/ar2
  float* M1    = w + off; off += 64 * D2;
  float* M2    = w + off; off += 64 * OUTD;
  float* Amat1 = w + off; off += 64 * EMB;
  float* Amat2 = w + off; off += 64 * D2;
  float* Matt1 = w + off; off += 64 * 4;
  float* Matt2 = w + off; off += 64;
  float* rden2 = w + off; off += (size_t)Nn * 8;
  float4* recs1 = (float4*)(w + off); off += (size_t)E * 16;
  float4* recs2 = (float4*)(w + off); off += (size_t)E * 12;
  unsigned short* z2b    = (unsigned short*)(w + off); off += (size_t)Nn * OUTD / 2;
  unsigned short* x0b    = (unsigned short*)(w + off); off += (size_t)Nn * EMB / 2;
  unsigned short* h1b    = (unsigned short*)(w + off); off += (size_t)Nn * D2 / 2;
  unsigned short* XQ1    = (unsigned short*)(w + off); off += (size_t)Nn * 768 / 2;
  unsigned short* W2b    = (unsigned short*)(w + off); off += (size_t)OUTD * D2 / 2;
  unsigned short* Bmat1b = (unsigned short*)(w + off); off += (size_t)64 * EMB / 2;
  unsigned short* Bmat2b = (unsigned short*)(w + off); off += (size_t)64 * D2 / 2;
  unsigned short* Acat   = (unsigned short*)(w + off); off += (size_t)Nn * KCAT / 2;
  unsigned short* RWcat  = (unsigned short*)(w + off); off += (size_t)OUTD * KCAT / 2;
  unsigned short* Bcat1  = (unsigned short*)(w + off); off += (size_t)512 * 192 / 2;
  unsigned short* Bp1ext = (unsigned short*)(w + off); off += (size_t)128 * 128 / 2;
  unsigned short* Bp2ext = (unsigned short*)(w + off); off += (size_t)128 * 512 / 2;
  int* ideg     = (int*)(w + off); off += (size_t)Nn;
  int* prepos   = (int*)(w + off); off += (size_t)E;
  int* rowstart = (int*)(w + off); off += (size_t)Nn + 1;
  (void)ws_size; (void)n_in; (void)out_size;

  const int MT128 = (Nn + 127) / 128;
  const int NB4 = (Nn + 3) / 4;

  // 0) hist fused into prep; conversions + LoRA re-layouts + concat copies
  (void)hipMemsetAsync(ideg, 0, (size_t)Nn * sizeof(int), stream);
  {
    int nx0 = Nn * EMB;
    int total = E + nx0 + OUTD * D2 + OUTD * EMB + 64 * EMB + 64 * D2 + 64 * EMB + 64 * D2;
    prep_all<<<(total + 255) / 256, 256, 0, stream>>>(x0, W2, res_W, A1, A2, B1, B2,
        x0b, Acat, W2b, RWcat, Amat1, Amat2, Bmat1b, Bmat2b, ii, ideg, prepos, E, nx0);
  }
  exscan_kernel<<<1, 1024, 0, stream>>>(ideg, rowstart, Nn);

  // 1) M1/M2 + all small operand builds (Bcat1, RWcat lora, Bp1ext, Bp2ext, Matt)
  gemm_abt2<<<dim3(D2 / 64 + OUTD / 64, 1), 256, 0, stream>>>(Amat1, W1, M1, Amat2, W2, M2);
  {
    int total = 512 * 192 + 256 * 64 + 128 * 128 + 128 * 512 + 256 + 64;
    fold_build<<<(total + 255) / 256, 256, 0, stream>>>(M1, M2, W1, W2, attL1, attR1,
        attL2, attR2, Bmat1b, Bmat2b, Bcat1, RWcat, Bp1ext, Bp2ext, Matt1, Matt2);
  }

  // 2) Layer-1 P/att GEMM: Cp1 = x0b @ Bp1ext^T (f32, N=128)
  gemm_tile<0, 1, 0, 0><<<dim3(MT128, 1), 256, 0, stream>>>(x0b, Bp1ext, nullptr, Cp1,
      nullptr, nullptr, Nn, 128, EMB, EMB, 0, nullptr, nullptr);

  // 3) Layer-1 edge logits; fused Q/den + x0-gather; msg GEMM -> h1 (elu fused)
  edge_alpha1<<<(E + 255) / 256, 256, 0, stream>>>(ji, ii, etype, rowstart, prepos, Cp1,
                                                   relb1, Matt1, recs1, E);
  agg1f<<<NB4, 256, 0, stream>>>(recs1, rowstart, x0b, XQ1, Nn);
  gemm_tile<1, 0, 1, 0><<<dim3(MT128, 4), 256, 0, stream>>>(XQ1, Bcat1, h1b, nullptr,
      nullptr, nullptr, Nn, D2, 192, 768, 192, bias1, nullptr);

  // 4) Layer-2: z2 GEMM + P2/att slice (PB)
  gemm_tile<0, 0, 0, 1><<<dim3(MT128, 3), 256, 0, stream>>>(h1b, W2b, z2b, nullptr,
      Bp2ext, Cp2, Nn, OUTD, D2, D2, 0, nullptr, nullptr);

  // 5) Layer-2 edge logits; Q/den (fills Acat); fused residual+lora+bias GEMM; gather + LN
  edge_alpha2<<<(E + 255) / 256, 256, 0, stream>>>(ji, ii, etype, rowstart, prepos, Cp2,
                                                   relb2, Matt2, recs2, E);
  qden2<<<NB4, 256, 0, stream>>>(recs2, rowstart, Acat, rden2, Nn);
  gemm_tile<1, 1, 0, 0><<<dim3(MT128, 2), 256, 0, stream>>>(Acat, RWcat, nullptr, o2,
      nullptr, nullptr, Nn, OUTD, KCAT, KCAT, 0, bias2, res_b);
  node_agg2_lite<<<NB4, 256, 0, stream>>>(recs2, rowstart, z2b, rden2, o2, ln_g, ln_b, out, Nn);
}

// Round 8
// 341.094 us; speedup vs baseline: 1.1017x; 1.0012x over previous
//
#include <hip/hip_runtime.h>
#include <cstddef>

#define NRELS 8
#define EMB 128
#define HID 128
#define OUTD 256
#define HEADS 4
#define RANK 8
#define D2 512            // HEADS*HID, conv2 input dim
#define KCAT 192          // EMB + 64, concatenated K
#define NEG_SLOPE 0.2f
#define LN_EPS 1e-5f
#define JMASK 0x07FFFFFFu

typedef short bf16x8 __attribute__((ext_vector_type(8)));   // 8 bf16 in 4 VGPRs
typedef float f32x4 __attribute__((ext_vector_type(4)));

__device__ __forceinline__ unsigned short f2bf(float f) {   // RNE
  union { float f; unsigned u; } v; v.f = f;
  unsigned u = v.u;
  return (unsigned short)((u + 0x7fffu + ((u >> 16) & 1u)) >> 16);
}
__device__ __forceinline__ float bf2f(unsigned short u) {
  union { unsigned u; float f; } v; v.u = (unsigned)u << 16; return v.f;
}
__device__ __forceinline__ unsigned pk2(float a, float b) {
  return (unsigned)f2bf(a) | ((unsigned)f2bf(b) << 16);
}
__device__ __forceinline__ unsigned asu(float f) { return __float_as_uint(f); }

// async global->LDS, 16B per lane; LDS dest = wave-uniform base + lane*16
#define GLOAD16(ldsp, gp) \
  __builtin_amdgcn_global_load_lds((const __attribute__((address_space(1))) unsigned int*)(gp), \
      (__attribute__((address_space(3))) unsigned int*)(ldsp), 16, 0, 0)

// ---------------- Unified big-tile bf16 MFMA GEMM body (128x128 tile, BK=32, LDS dbuf) ----------------
// Double-buffered global_load_lds staging; one __syncthreads per K-step.
// Chunk-XOR involution (2-way bank aliasing = free).
// PB: last by slice runs the same GEMM against Bp, f32 out to Cp stride 128.
template<int BIAS, int F32OUT, int ELU, int PB>
__device__ __forceinline__ void gemm_tile_body(unsigned short* AsB, unsigned short* BsB,
    int bx, int by, int ny,
    const unsigned short* __restrict__ A, const unsigned short* __restrict__ B,
    unsigned short* __restrict__ C, float* __restrict__ Cf,
    const unsigned short* __restrict__ Bp, float* __restrict__ Cp,
    int M, int N, int K, int lda, int aoffc,
    const float* __restrict__ bias, const float* __restrict__ b1p) {
  const int tid = threadIdx.x;
  const int wave = tid >> 6;
  const int lane = tid & 63;
  const int wm = wave & 1;
  const int wn = wave >> 1;
  const int r16 = lane & 15;
  const int quad = lane >> 4;
  const int bm = bx * 128;
  const int lr = lane >> 2;                                  // 0..15
  const int lc = ((lane & 3) ^ ((lane >> 3) & 3)) * 8;       // swizzled source col chunk
  const int rsw = (quad ^ ((r16 >> 1) & 3)) * 8;             // fragment read swizzle
  const bool isP = PB && (by == ny - 1);
  const unsigned short* Bu = isP ? Bp : B;
  const int bn = isP ? 0 : by * 128;
  const unsigned short* Abase = A + (size_t)by * (isP ? 0 : aoffc);
  int ar0 = bm + wave * 32 + lr;      if (ar0 >= M) ar0 = M - 1;
  int ar1 = bm + wave * 32 + 16 + lr; if (ar1 >= M) ar1 = M - 1;
  const unsigned short* Ag0 = Abase + (size_t)ar0 * lda + lc;
  const unsigned short* Ag1 = Abase + (size_t)ar1 * lda + lc;
  const unsigned short* Bg0 = Bu + (size_t)(bn + wave * 32 + lr) * K + lc;
  const unsigned short* Bg1 = Bu + (size_t)(bn + wave * 32 + 16 + lr) * K + lc;
  f32x4 acc[4][4] = {};
  GLOAD16(AsB + wave * 1024, Ag0);
  GLOAD16(AsB + wave * 1024 + 512, Ag1);
  GLOAD16(BsB + wave * 1024, Bg0);
  GLOAD16(BsB + wave * 1024 + 512, Bg1);
  __syncthreads();
  int cur = 0;
  for (int k0 = 0; k0 < K; k0 += 32) {
    if (k0 + 32 < K) {
      GLOAD16(AsB + (cur ^ 1) * 4096 + wave * 1024, Ag0 + k0 + 32);
      GLOAD16(AsB + (cur ^ 1) * 4096 + wave * 1024 + 512, Ag1 + k0 + 32);
      GLOAD16(BsB + (cur ^ 1) * 4096 + wave * 1024, Bg0 + k0 + 32);
      GLOAD16(BsB + (cur ^ 1) * 4096 + wave * 1024 + 512, Bg1 + k0 + 32);
    }
    bf16x8 af[4], bfr[4];
#pragma unroll
    for (int mi = 0; mi < 4; ++mi)
      af[mi] = *(const bf16x8*)(AsB + cur * 4096 + (wm * 64 + mi * 16 + r16) * 32 + rsw);
#pragma unroll
    for (int ni = 0; ni < 4; ++ni)
      bfr[ni] = *(const bf16x8*)(BsB + cur * 4096 + (wn * 64 + ni * 16 + r16) * 32 + rsw);
#pragma unroll
    for (int mi = 0; mi < 4; ++mi)
#pragma unroll
      for (int ni = 0; ni < 4; ++ni)
        acc[mi][ni] = __builtin_amdgcn_mfma_f32_16x16x32_bf16(af[mi], bfr[ni], acc[mi][ni], 0, 0, 0);
    __syncthreads();
    cur ^= 1;
  }
  float bcol[4];
  if (BIAS) {
#pragma unroll
    for (int ni = 0; ni < 4; ++ni) {
      int cn = bn + wn * 64 + ni * 16 + r16;
      bcol[ni] = bias[cn];
      if (F32OUT) bcol[ni] += b1p[cn];
    }
  }
#pragma unroll
  for (int mi = 0; mi < 4; ++mi)
#pragma unroll
    for (int ni = 0; ni < 4; ++ni)
#pragma unroll
      for (int r = 0; r < 4; ++r) {
        int row = bm + wm * 64 + mi * 16 + quad * 4 + r;
        if (row < M) {
          int col = wn * 64 + ni * 16 + r16;
          float v = acc[mi][ni][r];
          if (isP) {
            Cp[(size_t)row * 128 + col] = v;
          } else {
            if (BIAS) v += bcol[ni];
            if (ELU) v = v > 0.f ? v : expm1f(v);
            size_t idx = (size_t)row * N + bn + col;
            if (F32OUT) Cf[idx] = v;
            else        C[idx] = f2bf(v);
          }
        }
      }
}

template<int BIAS, int F32OUT, int ELU, int PB>
__global__ __launch_bounds__(256) void gemm_tile(const unsigned short* __restrict__ A,
    const unsigned short* __restrict__ B, unsigned short* __restrict__ C,
    float* __restrict__ Cf, const unsigned short* __restrict__ Bp,
    float* __restrict__ Cp, int M, int N, int K, int lda, int aoffc,
    const float* __restrict__ bias, const float* __restrict__ b1p) {
  __shared__ unsigned short As[2 * 4096];
  __shared__ unsigned short Bs[2 * 4096];
  gemm_tile_body<BIAS, F32OUT, ELU, PB>(As, Bs, blockIdx.x, blockIdx.y, gridDim.y,
      A, B, C, Cf, Bp, Cp, M, N, K, lda, aoffc, bias, b1p);
}

// ---------------- Combined: tiny fp32 GEMMs (M1,M2) + P1 GEMM in one dispatch ----------------
__global__ __launch_bounds__(256) void combo_abt_p1(const float* __restrict__ Amat1,
    const float* __restrict__ W1, float* __restrict__ M1o,
    const float* __restrict__ Amat2, const float* __restrict__ W2, float* __restrict__ M2o,
    const unsigned short* __restrict__ x0b, const unsigned short* __restrict__ Bp1ext,
    float* __restrict__ Cp1, int Nn) {
  __shared__ unsigned short GA[2 * 4096];
  __shared__ unsigned short GB[2 * 4096];
  const int bx = blockIdx.x;
  if (bx < 12) {
    float* As_ = (float*)GA;   // [32][64] = 8KB (fits in 16KB)
    float* Bs_ = (float*)GB;
    const float* A; const float* B; float* C; int N, K, bn;
    if (bx < 8) { A = Amat1; B = W1; C = M1o; N = D2; K = EMB; bn = bx * 64; }
    else { A = Amat2; B = W2; C = M2o; N = OUTD; K = D2; bn = (bx - 8) * 64; }
    const int tid = threadIdx.x;
    const int tx = tid & 15;
    const int ty = tid >> 4;
    const int lr2 = tid & 63;
    const int lq = tid >> 6;
    float acc[4][4] = {};
    for (int k0 = 0; k0 < K; k0 += 32) {
#pragma unroll
      for (int s = 0; s < 2; ++s) {
        const int q = lq + s * 4;
        float4 va = *(const float4*)(A + (size_t)lr2 * K + k0 + q * 4);
        As_[(q * 4 + 0) * 64 + lr2] = va.x; As_[(q * 4 + 1) * 64 + lr2] = va.y;
        As_[(q * 4 + 2) * 64 + lr2] = va.z; As_[(q * 4 + 3) * 64 + lr2] = va.w;
        float4 vb = *(const float4*)(B + (size_t)(bn + lr2) * K + k0 + q * 4);
        Bs_[(q * 4 + 0) * 64 + lr2] = vb.x; Bs_[(q * 4 + 1) * 64 + lr2] = vb.y;
        Bs_[(q * 4 + 2) * 64 + lr2] = vb.z; Bs_[(q * 4 + 3) * 64 + lr2] = vb.w;
      }
      __syncthreads();
#pragma unroll
      for (int kk = 0; kk < 32; ++kk) {
        float a[4], b[4];
#pragma unroll
        for (int i2 = 0; i2 < 4; ++i2) { a[i2] = As_[kk * 64 + ty * 4 + i2]; b[i2] = Bs_[kk * 64 + tx * 4 + i2]; }
#pragma unroll
        for (int i2 = 0; i2 < 4; ++i2)
#pragma unroll
          for (int j2 = 0; j2 < 4; ++j2)
            acc[i2][j2] = fmaf(a[i2], b[j2], acc[i2][j2]);
      }
      __syncthreads();
    }
#pragma unroll
    for (int i2 = 0; i2 < 4; ++i2)
#pragma unroll
      for (int j2 = 0; j2 < 4; ++j2)
        C[(size_t)(ty * 4 + i2) * N + bn + tx * 4 + j2] = acc[i2][j2];
  } else {
    gemm_tile_body<0, 1, 0, 0>(GA, GB, bx - 12, 0, 1, x0b, Bp1ext, nullptr, Cp1,
                               nullptr, nullptr, Nn, 128, EMB, EMB, 0, nullptr, nullptr);
  }
}

// ---------------- Fused prep: hist + conversions + LoRA re-layouts + B-operand builds ----------------
__global__ void prep_all(const float* __restrict__ x0, const float* __restrict__ W1,
    const float* __restrict__ W2, const float* __restrict__ res_W,
    const float* __restrict__ A1, const float* __restrict__ A2,
    const float* __restrict__ B1, const float* __restrict__ B2,
    const float* __restrict__ attL1, const float* __restrict__ attR1,
    const float* __restrict__ attL2, const float* __restrict__ attR2,
    unsigned short* __restrict__ x0b, unsigned short* __restrict__ Acat,
    unsigned short* __restrict__ W2b, unsigned short* __restrict__ RWcat,
    float* __restrict__ Amat1, float* __restrict__ Amat2,
    unsigned short* __restrict__ Bp1ext, unsigned short* __restrict__ Bp2ext,
    unsigned short* __restrict__ Bcat1,
    float* __restrict__ awR1f, float* __restrict__ awR2f,
    const int* __restrict__ ii, int* __restrict__ ideg, int* __restrict__ prepos,
    int E, int nx0) {
  int idx = blockIdx.x * 256 + threadIdx.x;
  if (idx < E) { prepos[idx] = atomicAdd(&ideg[ii[idx]], 1); return; } idx -= E;
  if (idx < nx0) { unsigned short b = f2bf(x0[idx]); x0b[idx] = b;
    Acat[(size_t)(idx >> 7) * KCAT + (idx & 127)] = b; return; } idx -= nx0;
  if (idx < OUTD * D2) { W2b[idx] = f2bf(W2[idx]); return; } idx -= OUTD * D2;
  if (idx < OUTD * EMB) { RWcat[(size_t)(idx >> 7) * KCAT + (idx & 127)] = f2bf(res_W[idx]); return; } idx -= OUTD * EMB;
  if (idx < 64 * EMB) { int d = idx % EMB, rk = idx / EMB, k = rk & 7, r = rk >> 3;
    Amat1[idx] = A1[(size_t)r * EMB * RANK + (size_t)d * RANK + k]; return; } idx -= 64 * EMB;
  if (idx < 64 * D2) { int d = idx % D2, rk = idx / D2, k = rk & 7, r = rk >> 3;
    Amat2[idx] = A2[(size_t)r * D2 * RANK + (size_t)d * RANK + k]; return; } idx -= 64 * D2;
  if (idx < 64 * EMB) { int d = idx % EMB, rk = idx / EMB, k = rk & 7, r = rk >> 3;
    Bp1ext[idx] = f2bf(B1[(size_t)r * EMB * RANK + (size_t)d * RANK + k]); return; } idx -= 64 * EMB;
  if (idx < 64 * D2) { int d = idx % D2, rk = idx / D2, k = rk & 7, r = rk >> 3;
    Bp2ext[idx] = f2bf(B2[(size_t)r * D2 * RANK + (size_t)d * RANK + k]); return; } idx -= 64 * D2;
  if (idx < 1024) {            // Bp1ext att rows 64-71 (+awR1f)
    int rr = idx >> 7, d = idx & 127;
    int h = rr & 3; bool isL = rr < 4;
    const float* att = isL ? attL1 : attR1;
    float s = 0.f;
    for (int c = 0; c < HID; ++c)
      s = fmaf(W1[(size_t)(h * HID + c) * EMB + d], att[h * HID + c], s);
    Bp1ext[(64 + rr) * 128 + d] = f2bf(s);
    if (!isL) awR1f[h * 128 + d] = s;
    return; } idx -= 1024;
  if (idx < 1024) {            // Bp2ext att rows 64-65 (+awR2f)
    int rr = idx >> 9, d = idx & 511;
    const float* att = (rr == 0) ? attL2 : attR2;
    float s = 0.f;
    for (int c = 0; c < OUTD; ++c)
      s = fmaf(W2[(size_t)c * D2 + d], att[c], s);
    Bp2ext[(size_t)(64 + rr) * 512 + d] = f2bf(s);
    if (rr == 1) awR2f[d] = s;
    return; } idx -= 1024;
  if (idx < 56 * 128) { Bp1ext[72 * 128 + idx] = 0; return; } idx -= 56 * 128;
  if (idx < 62 * 512) { Bp2ext[66 * 512 + idx] = 0; return; } idx -= 62 * 512;
  if (idx < 512 * 128) { int c = idx >> 7, t = idx & 127;
    Bcat1[(size_t)c * KCAT + t] = f2bf(W1[(size_t)c * EMB + t]); }
}

// ---------------- exscan (8/thread) + Matt folds in spare blocks ----------------
__global__ __launch_bounds__(1024) void exscan_matt(const int* __restrict__ deg,
    int* __restrict__ rowstart, int n,
    const float* __restrict__ Amat1, const float* __restrict__ awR1f, float* __restrict__ Matt1,
    const float* __restrict__ Amat2, const float* __restrict__ awR2f, float* __restrict__ Matt2) {
  if (blockIdx.x == 1) {
    int t = threadIdx.x;
    if (t < 256) {
      int rk = t >> 2, h = t & 3;
      float s = 0.f;
      for (int d = 0; d < 128; ++d)
        s = fmaf(Amat1[rk * 128 + d], awR1f[h * 128 + d], s);
      Matt1[t] = s;
    }
    return;
  }
  if (blockIdx.x == 2) {
    int t = threadIdx.x;
    if (t < 64) {
      float s = 0.f;
      for (int d = 0; d < 512; ++d) s = fmaf(Amat2[t * 512 + d], awR2f[d], s);
      Matt2[t] = s;
    }
    return;
  }
  __shared__ int wsum[16];
  int t = threadIdx.x;
  int lane = t & 63, wid = t >> 6;
  int carry = 0;
  for (int base = 0; base < n; base += 8192) {
    int i0 = base + t * 8;
    int v[8];
    if (i0 + 7 < n) {
      int4 a = *(const int4*)(deg + i0);
      int4 b = *(const int4*)(deg + i0 + 4);
      v[0] = a.x; v[1] = a.y; v[2] = a.z; v[3] = a.w;
      v[4] = b.x; v[5] = b.y; v[6] = b.z; v[7] = b.w;
    } else {
#pragma unroll
      for (int q = 0; q < 8; ++q) v[q] = (i0 + q < n) ? deg[i0 + q] : 0;
    }
    int tot = 0;
#pragma unroll
    for (int q = 0; q < 8; ++q) tot += v[q];
    int x = tot;
#pragma unroll
    for (int o = 1; o < 64; o <<= 1) {
      int y = __shfl_up(x, o, 64);
      if (lane >= o) x += y;
    }
    if (lane == 63) wsum[wid] = x;
    __syncthreads();
    if (t == 0) {
      int s = carry;
      for (int w2 = 0; w2 < 16; ++w2) { int tmp = wsum[w2]; wsum[w2] = s; s += tmp; }
      carry = s;
    }
    __syncthreads();
    int ex0 = x - tot + wsum[wid];
#pragma unroll
    for (int q = 0; q < 8; ++q) {
      if (i0 + q < n) rowstart[i0 + q] = ex0;
      ex0 += v[q];
    }
    __syncthreads();
  }
  if (t == 0) rowstart[n] = carry;
}

// ---------------- Combined: Bcat1/RWcat M-halves + layer-1 edge logits ----------------
// rec1 (3 float4 = 48B): [pack(rt<<27|j), ex0, ex1, ex2][ex3, low01, low23, low45][low67,0,0,0]
#define FB_BLOCKS 192
__global__ void combo_fold_ea1(const float* __restrict__ M1, const float* __restrict__ M2,
    unsigned short* __restrict__ Bcat1, unsigned short* __restrict__ RWcat,
    const int* __restrict__ ji, const int* __restrict__ ii,
    const int* __restrict__ et, const int* __restrict__ rowstart,
    const int* __restrict__ prepos, const float* __restrict__ Cp1,
    const float* __restrict__ relb1, const float* __restrict__ Matt1,
    float4* __restrict__ recs1, int E) {
  const int bx = blockIdx.x;
  if (bx < FB_BLOCKS) {
    int idx = bx * 256 + threadIdx.x;
    if (idx < 512 * 64) { int c = idx >> 6, rk = idx & 63;
      Bcat1[(size_t)c * KCAT + 128 + rk] = f2bf(M1[(size_t)rk * D2 + c]); return; }
    idx -= 512 * 64;
    if (idx < 256 * 64) { int c = idx >> 6, rk = idx & 63;
      RWcat[(size_t)c * KCAT + 128 + rk] = f2bf(M2[(size_t)rk * OUTD + c]); }
    return;
  }
  int e = (bx - FB_BLOCKS) * 256 + threadIdx.x;
  if (e >= E) return;
  int j = ji[e], i = ii[e], rt = et[e];
  float4 lo0 = *(const float4*)(Cp1 + (size_t)j * 128 + rt * 8);
  float4 lo1 = *(const float4*)(Cp1 + (size_t)j * 128 + rt * 8 + 4);
  float low[RANK] = {lo0.x, lo0.y, lo0.z, lo0.w, lo1.x, lo1.y, lo1.z, lo1.w};
  float4 ali = *(const float4*)(Cp1 + (size_t)i * 128 + 64);
  float4 arj = *(const float4*)(Cp1 + (size_t)j * 128 + 68);
  float4 rb  = *(const float4*)(relb1 + rt * 4);
  float a0 = ali.x + arj.x + rb.x;
  float a1 = ali.y + arj.y + rb.y;
  float a2 = ali.z + arj.z + rb.z;
  float a3 = ali.w + arj.w + rb.w;
#pragma unroll
  for (int k = 0; k < RANK; ++k) {
    float4 mk = *(const float4*)(Matt1 + ((rt * 8 + k) << 2));
    a0 = fmaf(low[k], mk.x, a0); a1 = fmaf(low[k], mk.y, a1);
    a2 = fmaf(low[k], mk.z, a2); a3 = fmaf(low[k], mk.w, a3);
  }
  a0 = (a0 > 0.f) ? a0 : NEG_SLOPE * a0;
  a1 = (a1 > 0.f) ? a1 : NEG_SLOPE * a1;
  a2 = (a2 > 0.f) ? a2 : NEG_SLOPE * a2;
  a3 = (a3 > 0.f) ? a3 : NEG_SLOPE * a3;
  float e0 = expf(a0), e1 = expf(a1), e2 = expf(a2), e3 = expf(a3);
  unsigned pack = ((unsigned)rt << 27) | (unsigned)j;
  float4* rp = recs1 + (size_t)(rowstart[i] + prepos[e]) * 3;
  rp[0] = make_float4(__uint_as_float(pack), e0, e1, e2);
  rp[1] = make_float4(e3, __uint_as_float(pk2(low[0], low[1])),
                      __uint_as_float(pk2(low[2], low[3])),
                      __uint_as_float(pk2(low[4], low[5])));
  rp[2] = make_float4(__uint_as_float(pk2(low[6], low[7])), 0.f, 0.f, 0.f);
}

// ---------------- Layer-1 fused Q/den + x0-gather: fills XQ1 [Nn][4x(128 Xw | 64 Q)] ----------------
__global__ __launch_bounds__(256) void agg1f(const float4* __restrict__ recs1,
    const int* __restrict__ rowstart, const unsigned short* __restrict__ x0b,
    unsigned short* __restrict__ XQ1, int Nn) {
  __shared__ float denS[4][32];          // [wid][h*8+rt]
  const int wid = threadIdx.x >> 6, lane = threadIdx.x & 63;
  const int i = blockIdx.x * 4 + wid;
  if (i >= Nn) return;
  const int rt_mine = lane >> 3, k = lane & 7;
  const int s0 = rowstart[i], deg = rowstart[i + 1] - s0;
  const float* rf = (const float*)recs1;
  const size_t xb = (size_t)i * 768;
  // ---- Phase A: LoRA Q sums + softmax denominators (lane = rt*8+k) ----
  {
    float q0 = 0.f, q1 = 0.f, q2 = 0.f, q3 = 0.f;
    float d0 = 0.f, d1 = 0.f, d2 = 0.f, d3 = 0.f;
    float4 a0 = {}, a1 = {};
    float a2x = 0.f;
    if (deg > 0) {
      a0 = recs1[(size_t)s0 * 3]; a1 = recs1[(size_t)s0 * 3 + 1];
      a2x = rf[(size_t)s0 * 12 + 8];
    }
    const int sel = k >> 1;
    for (int p = 0; p < deg; ++p) {
      float4 b0 = a0, b1 = a1; float b2x = a2x;
      if (p + 1 < deg) {
        b0 = recs1[(size_t)(s0 + p + 1) * 3]; b1 = recs1[(size_t)(s0 + p + 1) * 3 + 1];
        b2x = rf[(size_t)(s0 + p + 1) * 12 + 8];
      }
      int rt = (int)(asu(a0.x) >> 27);
      if (rt == rt_mine) {
        float pw = (sel == 0) ? a1.y : (sel == 1) ? a1.z : (sel == 2) ? a1.w : a2x;
        unsigned pu = asu(pw);
        float lw = bf2f((unsigned short)((k & 1) ? (pu >> 16) : (pu & 0xffff)));
        q0 = fmaf(a0.y, lw, q0); q1 = fmaf(a0.z, lw, q1);
        q2 = fmaf(a0.w, lw, q2); q3 = fmaf(a1.x, lw, q3);
        d0 += a0.y; d1 += a0.z; d2 += a0.w; d3 += a1.x;
      }
      a0 = b0; a1 = b1; a2x = b2x;
    }
    float r0 = (d0 > 0.f) ? 1.f / d0 : 0.f;
    float r1 = (d1 > 0.f) ? 1.f / d1 : 0.f;
    float r2 = (d2 > 0.f) ? 1.f / d2 : 0.f;
    float r3 = (d3 > 0.f) ? 1.f / d3 : 0.f;
    XQ1[xb + 0 * 192 + 128 + lane] = f2bf(q0 * r0);
    XQ1[xb + 1 * 192 + 128 + lane] = f2bf(q1 * r1);
    XQ1[xb + 2 * 192 + 128 + lane] = f2bf(q2 * r2);
    XQ1[xb + 3 * 192 + 128 + lane] = f2bf(q3 * r3);
    if (k == 0) {
      denS[wid][rt_mine]      = r0;
      denS[wid][8 + rt_mine]  = r1;
      denS[wid][16 + rt_mine] = r2;
      denS[wid][24 + rt_mine] = r3;
    }
  }
  // wave-synchronous LDS: same wave wrote denS[wid], no barrier needed
  // ---- Phase B: weighted x0 gather (lane = 2 cols, records now cache-hot) ----
  const int c0 = lane * 2;
  float acc[8] = {};
  float4 r0 = {}, r1 = {};
  float e30 = 0.f, e31 = 0.f;
  unsigned za = 0u;
  if (deg > 0) { r0 = recs1[(size_t)s0 * 3]; e30 = rf[(size_t)s0 * 12 + 4];
    za = *(const unsigned*)(x0b + (size_t)(asu(r0.x) & JMASK) * 128 + c0); }
  if (deg > 1) { r1 = recs1[(size_t)(s0 + 1) * 3]; e31 = rf[(size_t)(s0 + 1) * 12 + 4]; }
  for (int p = 0; p < deg; ++p) {
    float4 r2 = r1; float e32 = e31; unsigned zb = za;
    if (p + 2 < deg) { r2 = recs1[(size_t)(s0 + p + 2) * 3];
                       e32 = rf[(size_t)(s0 + p + 2) * 12 + 4]; }
    if (p + 1 < deg) zb = *(const unsigned*)(x0b + (size_t)(asu(r1.x) & JMASK) * 128 + c0);
    int rt = (int)(asu(r0.x) >> 27);
    float w0 = r0.y * denS[wid][rt];
    float w1 = r0.z * denS[wid][8 + rt];
    float w2 = r0.w * denS[wid][16 + rt];
    float w3 = e30 * denS[wid][24 + rt];
    float v0 = bf2f((unsigned short)(za & 0xffff));
    float v1 = bf2f((unsigned short)(za >> 16));
    acc[0] = fmaf(w0, v0, acc[0]); acc[1] = fmaf(w0, v1, acc[1]);
    acc[2] = fmaf(w1, v0, acc[2]); acc[3] = fmaf(w1, v1, acc[3]);
    acc[4] = fmaf(w2, v0, acc[4]); acc[5] = fmaf(w2, v1, acc[5]);
    acc[6] = fmaf(w3, v0, acc[6]); acc[7] = fmaf(w3, v1, acc[7]);
    r0 = r1; e30 = e31; r1 = r2; e31 = e32; za = zb;
  }
#pragma unroll
  for (int h = 0; h < 4; ++h) {
    unsigned pv = pk2(acc[2 * h], acc[2 * h + 1]);
    *(unsigned*)(XQ1 + xb + h * 192 + c0) = pv;
  }
}

// ---------------- Layer-2 edge logits -> packed records ----------------
// rec2 (2 float4 = 32B): [pack, ex, low01, low23][low45, low67, 0, 0]
__global__ void edge_alpha2(const int* __restrict__ ji, const int* __restrict__ ii,
                            const int* __restrict__ et, const int* __restrict__ rowstart,
                            const int* __restrict__ prepos,
                            const float* __restrict__ Cp2,
                            const float* __restrict__ relb2, const float* __restrict__ Matt2,
                            float4* __restrict__ recs2, int E) {
  int e = blockIdx.x * blockDim.x + threadIdx.x;
  if (e >= E) return;
  int j = ji[e], i = ii[e], rt = et[e];
  float4 lo0 = *(const float4*)(Cp2 + (size_t)j * 128 + rt * 8);
  float4 lo1 = *(const float4*)(Cp2 + (size_t)j * 128 + rt * 8 + 4);
  float low[RANK] = {lo0.x, lo0.y, lo0.z, lo0.w, lo1.x, lo1.y, lo1.z, lo1.w};
  float a = Cp2[(size_t)i * 128 + 64] + Cp2[(size_t)j * 128 + 65] + relb2[rt];
#pragma unroll
  for (int k = 0; k < RANK; ++k) a = fmaf(low[k], Matt2[rt * RANK + k], a);
  a = (a > 0.f) ? a : NEG_SLOPE * a;
  float ex = expf(a);
  unsigned pack = ((unsigned)rt << 27) | (unsigned)j;
  float4* rp = recs2 + (size_t)(rowstart[i] + prepos[e]) * 2;
  rp[0] = make_float4(__uint_as_float(pack), ex,
                      __uint_as_float(pk2(low[0], low[1])),
                      __uint_as_float(pk2(low[2], low[3])));
  rp[1] = make_float4(__uint_as_float(pk2(low[4], low[5])),
                      __uint_as_float(pk2(low[6], low[7])), 0.f, 0.f);
}

// ---------------- Layer-2 Q/den: Q -> Acat cols 128..191, rden2[Nn][8] ----------------
__global__ __launch_bounds__(256) void qden2(const float4* __restrict__ recs2,
    const int* __restrict__ rowstart, unsigned short* __restrict__ Acat,
    float* __restrict__ rden2, int Nn) {
  const int wid = threadIdx.x >> 6, lane = threadIdx.x & 63;
  const int i = blockIdx.x * 4 + wid;
  if (i >= Nn) return;
  const int rt_mine = lane >> 3, k = lane & 7;
  const int s0 = rowstart[i], deg = rowstart[i + 1] - s0;
  const float* rf = (const float*)recs2;
  float q = 0.f, d = 0.f;
  float4 a0 = {}; float2 a1 = {};
  if (deg > 0) { a0 = recs2[(size_t)s0 * 2]; a1 = *(const float2*)(rf + (size_t)s0 * 8 + 4); }
  const int sel = k >> 1;
  for (int p = 0; p < deg; ++p) {
    float4 b0 = a0; float2 b1 = a1;
    if (p + 1 < deg) {
      b0 = recs2[(size_t)(s0 + p + 1) * 2];
      b1 = *(const float2*)(rf + (size_t)(s0 + p + 1) * 8 + 4);
    }
    int rt = (int)(asu(a0.x) >> 27);
    if (rt == rt_mine) {
      float pw = (sel == 0) ? a0.z : (sel == 1) ? a0.w : (sel == 2) ? a1.x : a1.y;
      unsigned pu = asu(pw);
      float lw = bf2f((unsigned short)((k & 1) ? (pu >> 16) : (pu & 0xffff)));
      q = fmaf(a0.y, lw, q); d += a0.y;
    }
    a0 = b0; a1 = b1;
  }
  float rd = (d > 0.f) ? 1.f / d : 0.f;
  Acat[(size_t)i * KCAT + 128 + lane] = f2bf(q * rd);
  if (k == 0) rden2[(size_t)i * 8 + rt_mine] = rd;
}

// ---------------- Layer-2 gather + residual/lora/bias (o2) + LN -> out ----------------
__global__ __launch_bounds__(256) void node_agg2_lite(const float4* __restrict__ recs2,
    const int* __restrict__ rowstart, const unsigned short* __restrict__ z2b,
    const float* __restrict__ rden2, const float* __restrict__ o2,
    const float* __restrict__ ln_g, const float* __restrict__ ln_b,
    float* __restrict__ y, int Nn) {
  const int wid = threadIdx.x >> 6;
  const int lane = threadIdx.x & 63;
  const int i = blockIdx.x * 4 + wid;
  if (i >= Nn) return;
  __shared__ float denS[4][NRELS];
  if (lane < NRELS) denS[wid][lane] = rden2[(size_t)i * 8 + lane];
  // wave-synchronous LDS, no barrier
  const int s0 = rowstart[i];
  const int deg = rowstart[i + 1] - s0;
  const int c0 = lane * 4;
  float acc[4] = {};
  float4 r0 = {}, r1 = {}, r2 = {};
  uint2 za = make_uint2(0u, 0u), zb = make_uint2(0u, 0u);
  if (deg > 0) { r0 = recs2[(size_t)s0 * 2];
    za = *(const uint2*)(z2b + (size_t)(asu(r0.x) & JMASK) * OUTD + c0); }
  if (deg > 1) { r1 = recs2[(size_t)(s0 + 1) * 2];
    zb = *(const uint2*)(z2b + (size_t)(asu(r1.x) & JMASK) * OUTD + c0); }
  if (deg > 2) r2 = recs2[(size_t)(s0 + 2) * 2];
  for (int p = 0; p < deg; ++p) {
    float4 r3 = r2;
    uint2 zn = zb;
    if (p + 3 < deg) r3 = recs2[(size_t)(s0 + p + 3) * 2];
    if (p + 2 < deg)
      zn = *(const uint2*)(z2b + (size_t)(asu(r2.x) & JMASK) * OUTD + c0);
    int rt = (int)(asu(r0.x) >> 27);
    float wt = r0.y * denS[wid][rt];
    acc[0] = fmaf(wt, bf2f((unsigned short)(za.x & 0xffff)), acc[0]);
    acc[1] = fmaf(wt, bf2f((unsigned short)(za.x >> 16)), acc[1]);
    acc[2] = fmaf(wt, bf2f((unsigned short)(za.y & 0xffff)), acc[2]);
    acc[3] = fmaf(wt, bf2f((unsigned short)(za.y >> 16)), acc[3]);
    r0 = r1; r1 = r2; r2 = r3; za = zb; zb = zn;
  }
  float4 rsv = *(const float4*)(o2 + (size_t)i * OUTD + c0);   // residual+lora2+bias2+res_b
  float vv[4];
  vv[0] = acc[0] + rsv.x;
  vv[1] = acc[1] + rsv.y;
  vv[2] = acc[2] + rsv.z;
  vv[3] = acc[3] + rsv.w;
  float s = vv[0] + vv[1] + vv[2] + vv[3];
  for (int o = 32; o > 0; o >>= 1) s += __shfl_xor(s, o, 64);
  float mu = s * (1.f / OUTD);
  float q = 0.f;
#pragma unroll
  for (int k = 0; k < 4; ++k) { float d = vv[k] - mu; q += d * d; }
  for (int o = 32; o > 0; o >>= 1) q += __shfl_xor(q, o, 64);
  float rstd = rsqrtf(q * (1.f / OUTD) + LN_EPS);
  float4 g = *(const float4*)(ln_g + c0);
  float4 bb = *(const float4*)(ln_b + c0);
  float4 ov;
  ov.x = (vv[0] - mu) * rstd * g.x + bb.x;
  ov.y = (vv[1] - mu) * rstd * g.y + bb.y;
  ov.z = (vv[2] - mu) * rstd * g.z + bb.z;
  ov.w = (vv[3] - mu) * rstd * g.w + bb.w;
  *(float4*)(y + (size_t)i * OUTD + c0) = ov;
}

extern "C" void kernel_launch(void* const* d_in, const int* in_sizes, int n_in,
                              void* d_out, int out_size, void* d_ws, size_t ws_size,
                              hipStream_t stream) {
  const float* x0     = (const float*)d_in[0];
  const float* A1     = (const float*)d_in[1];
  const float* B1     = (const float*)d_in[2];
  const float* W1     = (const float*)d_in[3];
  const float* attL1  = (const float*)d_in[4];
  const float* attR1  = (const float*)d_in[5];
  const float* relb1  = (const float*)d_in[6];
  const float* bias1  = (const float*)d_in[7];
  const float* A2     = (const float*)d_in[8];
  const float* B2     = (const float*)d_in[9];
  const float* W2     = (const float*)d_in[10];
  const float* attL2  = (const float*)d_in[11];
  const float* attR2  = (const float*)d_in[12];
  const float* relb2  = (const float*)d_in[13];
  const float* bias2  = (const float*)d_in[14];
  const float* res_W  = (const float*)d_in[15];
  const float* res_b  = (const float*)d_in[16];
  const float* ln_g   = (const float*)d_in[17];
  const float* ln_b   = (const float*)d_in[18];
  const int*   eidx   = (const int*)d_in[19];
  const int*   etype  = (const int*)d_in[20];
  float* out = (float*)d_out;

  const int Nn = in_sizes[0] / EMB;     // 30000
  const int E  = in_sizes[20];          // 150000
  const int* ji = eidx;
  const int* ii = eidx + E;

  // ---- workspace carve-up (float units; all offsets stay 16B-aligned) ----
  float* w = (float*)d_ws;
  size_t off = 0;
  float* o2    = w + off; off += (size_t)Nn * OUTD;
  float* Cp1   = w + off; off += (size_t)Nn * 128;    // P1 + al1/ar1
  float* Cp2   = w + off; off += (size_t)Nn * 128;    // P2 + al2/ar2
  float* M1    = w + off; off += 64 * D2;
  float* M2    = w + off; off += 64 * OUTD;
  float* Amat1 = w + off; off += 64 * EMB;
  float* Amat2 = w + off; off += 64 * D2;
  float* Matt1 = w + off; off += 64 * 4;
  float* Matt2 = w + off; off += 64;
  float* awR1f = w + off; off += 512;
  float* awR2f = w + off; off += 512;
  float* rden2 = w + off; off += (size_t)Nn * 8;
  float4* recs1 = (float4*)(w + off); off += (size_t)E * 12;   // 48B records
  float4* recs2 = (float4*)(w + off); off += (size_t)E * 8;    // 32B records
  unsigned short* z2b    = (unsigned short*)(w + off); off += (size_t)Nn * OUTD / 2;
  unsigned short* x0b    = (unsigned short*)(w + off); off += (size_t)Nn * EMB / 2;
  unsigned short* h1b    = (unsigned short*)(w + off); off += (size_t)Nn * D2 / 2;
  unsigned short* XQ1    = (unsigned short*)(w + off); off += (size_t)Nn * 768 / 2;
  unsigned short* W2b    = (unsigned short*)(w + off); off += (size_t)OUTD * D2 / 2;
  unsigned short* Acat   = (unsigned short*)(w + off); off += (size_t)Nn * KCAT / 2;
  unsigned short* RWcat  = (unsigned short*)(w + off); off += (size_t)OUTD * KCAT / 2;
  unsigned short* Bcat1  = (unsigned short*)(w + off); off += (size_t)512 * KCAT / 2;
  unsigned short* Bp1ext = (unsigned short*)(w + off); off += (size_t)128 * 128 / 2;
  unsigned short* Bp2ext = (unsigned short*)(w + off); off += (size_t)128 * 512 / 2;
  int* ideg     = (int*)(w + off); off += (size_t)Nn;
  int* prepos   = (int*)(w + off); off += (size_t)E;
  int* rowstart = (int*)(w + off); off += (size_t)Nn + 1;
  (void)ws_size; (void)n_in; (void)out_size;

  const int MT128 = (Nn + 127) / 128;
  const int NB4 = (Nn + 3) / 4;

  // 0) fused prep: hist + conversions + all M-independent B-operand builds
  (void)hipMemsetAsync(ideg, 0, (size_t)Nn * sizeof(int), stream);
  {
    int nx0 = Nn * EMB;
    int total = E + nx0 + OUTD * D2 + OUTD * EMB + 64 * EMB + 64 * D2
              + 64 * EMB + 64 * D2 + 1024 + 1024 + 56 * 128 + 62 * 512 + 512 * 128;
    prep_all<<<(total + 255) / 256, 256, 0, stream>>>(x0, W1, W2, res_W, A1, A2, B1, B2,
        attL1, attR1, attL2, attR2, x0b, Acat, W2b, RWcat, Amat1, Amat2,
        Bp1ext, Bp2ext, Bcat1, awR1f, awR2f, ii, ideg, prepos, E, nx0);
  }

  // 1) exscan + Matt folds (spare blocks)
  exscan_matt<<<3, 1024, 0, stream>>>(ideg, rowstart, Nn, Amat1, awR1f, Matt1,
                                      Amat2, awR2f, Matt2);

  // 2) M1/M2 fp32 GEMMs + P1/att GEMM (one dispatch)
  combo_abt_p1<<<12 + MT128, 256, 0, stream>>>(Amat1, W1, M1, Amat2, W2, M2,
                                               x0b, Bp1ext, Cp1, Nn);

  // 3) Bcat1/RWcat M-halves + layer-1 edge logits (one dispatch)
  combo_fold_ea1<<<FB_BLOCKS + (E + 255) / 256, 256, 0, stream>>>(M1, M2, Bcat1, RWcat,
      ji, ii, etype, rowstart, prepos, Cp1, relb1, Matt1, recs1, E);

  // 4) fused Q/den + x0-gather; msg GEMM -> h1 (elu+bias fused)
  agg1f<<<NB4, 256, 0, stream>>>(recs1, rowstart, x0b, XQ1, Nn);
  gemm_tile<1, 0, 1, 0><<<dim3(MT128, 4), 256, 0, stream>>>(XQ1, Bcat1, h1b, nullptr,
      nullptr, nullptr, Nn, D2, KCAT, 768, KCAT, bias1, nullptr);

  // 5) Layer-2: z2 GEMM + P2/att slice (PB)
  gemm_tile<0, 0, 0, 1><<<dim3(MT128, 3), 256, 0, stream>>>(h1b, W2b, z2b, nullptr,
      Bp2ext, Cp2, Nn, OUTD, D2, D2, 0, nullptr, nullptr);

  // 6) Layer-2 edge logits; Q/den (fills Acat); fused residual+lora+bias GEMM; gather + LN
  edge_alpha2<<<(E + 255) / 256, 256, 0, stream>>>(ji, ii, etype, rowstart, prepos, Cp2,
                                                   relb2, Matt2, recs2, E);
  qden2<<<NB4, 256, 0, stream>>>(recs2, rowstart, Acat, rden2, Nn);
  gemm_tile<1, 1, 0, 0><<<dim3(MT128, 2), 256, 0, stream>>>(Acat, RWcat, nullptr, o2,
      nullptr, nullptr, Nn, OUTD, KCAT, KCAT, 0, bias2, res_b);
  node_agg2_lite<<<NB4, 256, 0, stream>>>(recs2, rowstart, z2b, rden2, o2, ln_g, ln_b, out, Nn);
}

// Round 9
// 337.371 us; speedup vs baseline: 1.1139x; 1.0110x over previous
//
#include <hip/hip_runtime.h>
#include <cstddef>

#define NRELS 8
#define EMB 128
#define HID 128
#define OUTD 256
#define HEADS 4
#define RANK 8
#define D2 512            // HEADS*HID, conv2 input dim
#define KCAT 192          // EMB + 64, concatenated K
#define NEG_SLOPE 0.2f
#define LN_EPS 1e-5f
#define JMASK 0x07FFFFFFu

typedef short bf16x8 __attribute__((ext_vector_type(8)));   // 8 bf16 in 4 VGPRs
typedef float f32x4 __attribute__((ext_vector_type(4)));

__device__ __forceinline__ unsigned short f2bf(float f) {   // RNE
  union { float f; unsigned u; } v; v.f = f;
  unsigned u = v.u;
  return (unsigned short)((u + 0x7fffu + ((u >> 16) & 1u)) >> 16);
}
__device__ __forceinline__ float bf2f(unsigned short u) {
  union { unsigned u; float f; } v; v.u = (unsigned)u << 16; return v.f;
}
__device__ __forceinline__ unsigned pk2(float a, float b) {
  return (unsigned)f2bf(a) | ((unsigned)f2bf(b) << 16);
}
__device__ __forceinline__ unsigned asu(float f) { return __float_as_uint(f); }

// async global->LDS, 16B per lane; LDS dest = wave-uniform base + lane*16
#define GLOAD16(ldsp, gp) \
  __builtin_amdgcn_global_load_lds((const __attribute__((address_space(1))) unsigned int*)(gp), \
      (__attribute__((address_space(3))) unsigned int*)(ldsp), 16, 0, 0)

// ---------------- Unified big-tile bf16 MFMA GEMM body (128x128 tile, BK=32, LDS dbuf) ----------------
// Double-buffered global_load_lds staging; one __syncthreads per K-step.
// Chunk-XOR involution (2-way bank aliasing = free).
// PB: last by slice runs the same GEMM against Bp, f32 out to Cp stride 128.
// SPLITA: A columns k<128 from A (lda), k>=128 from A2 (lda2=64).
template<int BIAS, int F32OUT, int ELU, int PB, int SPLITA>
__device__ __forceinline__ void gemm_tile_body(unsigned short* AsB, unsigned short* BsB,
    int bx, int by, int ny,
    const unsigned short* __restrict__ A, const unsigned short* __restrict__ B,
    unsigned short* __restrict__ C, float* __restrict__ Cf,
    const unsigned short* __restrict__ Bp, float* __restrict__ Cp,
    const unsigned short* __restrict__ A2, int lda2,
    int M, int N, int K, int lda, int aoffc,
    const float* __restrict__ bias, const float* __restrict__ b1p) {
  const int tid = threadIdx.x;
  const int wave = tid >> 6;
  const int lane = tid & 63;
  const int wm = wave & 1;
  const int wn = wave >> 1;
  const int r16 = lane & 15;
  const int quad = lane >> 4;
  const int bm = bx * 128;
  const int lr = lane >> 2;                                  // 0..15
  const int lc = ((lane & 3) ^ ((lane >> 3) & 3)) * 8;       // swizzled source col chunk
  const int rsw = (quad ^ ((r16 >> 1) & 3)) * 8;             // fragment read swizzle
  const bool isP = PB && (by == ny - 1);
  const unsigned short* Bu = isP ? Bp : B;
  const int bn = isP ? 0 : by * 128;
  const unsigned short* Abase = A + (size_t)by * (isP ? 0 : aoffc);
  int ar0 = bm + wave * 32 + lr;      if (ar0 >= M) ar0 = M - 1;
  int ar1 = bm + wave * 32 + 16 + lr; if (ar1 >= M) ar1 = M - 1;
  const unsigned short* Ag0 = Abase + (size_t)ar0 * lda + lc;
  const unsigned short* Ag1 = Abase + (size_t)ar1 * lda + lc;
  const unsigned short* Ag0b = SPLITA ? (A2 + (size_t)ar0 * lda2 + lc) : nullptr;
  const unsigned short* Ag1b = SPLITA ? (A2 + (size_t)ar1 * lda2 + lc) : nullptr;
  const unsigned short* Bg0 = Bu + (size_t)(bn + wave * 32 + lr) * K + lc;
  const unsigned short* Bg1 = Bu + (size_t)(bn + wave * 32 + 16 + lr) * K + lc;
  auto srcA0 = [&](int kk) {
    return (SPLITA && kk >= 128) ? Ag0b + (kk - 128) : Ag0 + kk;
  };
  auto srcA1 = [&](int kk) {
    return (SPLITA && kk >= 128) ? Ag1b + (kk - 128) : Ag1 + kk;
  };
  f32x4 acc[4][4] = {};
  GLOAD16(AsB + wave * 1024, srcA0(0));
  GLOAD16(AsB + wave * 1024 + 512, srcA1(0));
  GLOAD16(BsB + wave * 1024, Bg0);
  GLOAD16(BsB + wave * 1024 + 512, Bg1);
  __syncthreads();
  int cur = 0;
  for (int k0 = 0; k0 < K; k0 += 32) {
    if (k0 + 32 < K) {
      GLOAD16(AsB + (cur ^ 1) * 4096 + wave * 1024, srcA0(k0 + 32));
      GLOAD16(AsB + (cur ^ 1) * 4096 + wave * 1024 + 512, srcA1(k0 + 32));
      GLOAD16(BsB + (cur ^ 1) * 4096 + wave * 1024, Bg0 + k0 + 32);
      GLOAD16(BsB + (cur ^ 1) * 4096 + wave * 1024 + 512, Bg1 + k0 + 32);
    }
    bf16x8 af[4], bfr[4];
#pragma unroll
    for (int mi = 0; mi < 4; ++mi)
      af[mi] = *(const bf16x8*)(AsB + cur * 4096 + (wm * 64 + mi * 16 + r16) * 32 + rsw);
#pragma unroll
    for (int ni = 0; ni < 4; ++ni)
      bfr[ni] = *(const bf16x8*)(BsB + cur * 4096 + (wn * 64 + ni * 16 + r16) * 32 + rsw);
#pragma unroll
    for (int mi = 0; mi < 4; ++mi)
#pragma unroll
      for (int ni = 0; ni < 4; ++ni)
        acc[mi][ni] = __builtin_amdgcn_mfma_f32_16x16x32_bf16(af[mi], bfr[ni], acc[mi][ni], 0, 0, 0);
    __syncthreads();
    cur ^= 1;
  }
  float bcol[4];
  if (BIAS) {
#pragma unroll
    for (int ni = 0; ni < 4; ++ni) {
      int cn = bn + wn * 64 + ni * 16 + r16;
      bcol[ni] = bias[cn];
      if (F32OUT) bcol[ni] += b1p[cn];
    }
  }
#pragma unroll
  for (int mi = 0; mi < 4; ++mi)
#pragma unroll
    for (int ni = 0; ni < 4; ++ni)
#pragma unroll
      for (int r = 0; r < 4; ++r) {
        int row = bm + wm * 64 + mi * 16 + quad * 4 + r;
        if (row < M) {
          int col = wn * 64 + ni * 16 + r16;
          float v = acc[mi][ni][r];
          if (isP) {
            Cp[(size_t)row * 128 + col] = v;
          } else {
            if (BIAS) v += bcol[ni];
            if (ELU) v = v > 0.f ? v : expm1f(v);
            size_t idx = (size_t)row * N + bn + col;
            if (F32OUT) Cf[idx] = v;
            else        C[idx] = f2bf(v);
          }
        }
      }
}

template<int BIAS, int F32OUT, int ELU, int PB, int SPLITA>
__global__ __launch_bounds__(256) void gemm_tile(const unsigned short* __restrict__ A,
    const unsigned short* __restrict__ B, unsigned short* __restrict__ C,
    float* __restrict__ Cf, const unsigned short* __restrict__ Bp,
    float* __restrict__ Cp, const unsigned short* __restrict__ A2, int lda2,
    int M, int N, int K, int lda, int aoffc,
    const float* __restrict__ bias, const float* __restrict__ b1p) {
  __shared__ unsigned short As[2 * 4096];
  __shared__ unsigned short Bs[2 * 4096];
  gemm_tile_body<BIAS, F32OUT, ELU, PB, SPLITA>(As, Bs, blockIdx.x, blockIdx.y, gridDim.y,
      A, B, C, Cf, Bp, Cp, A2, lda2, M, N, K, lda, aoffc, bias, b1p);
}

// ---------------- z2 GEMM with XCD-trio swizzle: 3 col-blocks of same row-panel co-XCD ----------------
// slot = g*24 + by*8 + (bx&7), bx = g*8 + (slot&7): trio {s, s+8, s+16} -> same XCD (8 XCDs, rr).
__global__ __launch_bounds__(256) void gemm_tile_z2(const unsigned short* __restrict__ A,
    const unsigned short* __restrict__ B, unsigned short* __restrict__ C,
    const unsigned short* __restrict__ Bp, float* __restrict__ Cp,
    int M, int N, int K, int nbx) {
  __shared__ unsigned short As[2 * 4096];
  __shared__ unsigned short Bs[2 * 4096];
  int id = blockIdx.x;
  int g = id / 24, r = id % 24;
  int by = r >> 3;
  int bx = g * 8 + (r & 7);
  if (bx >= nbx) return;
  gemm_tile_body<0, 0, 0, 1, 0>(As, Bs, bx, by, 3,
      A, B, C, nullptr, Bp, Cp, nullptr, 0, M, N, K, K, 0, nullptr, nullptr);
}

// ---------------- Combined: tiny fp32 GEMMs (M1,M2) + P1 GEMM in one dispatch ----------------
__global__ __launch_bounds__(256) void combo_abt_p1(const float* __restrict__ Amat1,
    const float* __restrict__ W1, float* __restrict__ M1o,
    const float* __restrict__ Amat2, const float* __restrict__ W2, float* __restrict__ M2o,
    const unsigned short* __restrict__ x0b, const unsigned short* __restrict__ Bp1ext,
    float* __restrict__ Cp1, int Nn) {
  __shared__ unsigned short GA[2 * 4096];
  __shared__ unsigned short GB[2 * 4096];
  const int bx = blockIdx.x;
  if (bx < 12) {
    float* As_ = (float*)GA;   // [32][64] = 8KB (fits in 16KB)
    float* Bs_ = (float*)GB;
    const float* A; const float* B; float* C; int N, K, bn;
    if (bx < 8) { A = Amat1; B = W1; C = M1o; N = D2; K = EMB; bn = bx * 64; }
    else { A = Amat2; B = W2; C = M2o; N = OUTD; K = D2; bn = (bx - 8) * 64; }
    const int tid = threadIdx.x;
    const int tx = tid & 15;
    const int ty = tid >> 4;
    const int lr2 = tid & 63;
    const int lq = tid >> 6;
    float acc[4][4] = {};
    for (int k0 = 0; k0 < K; k0 += 32) {
#pragma unroll
      for (int s = 0; s < 2; ++s) {
        const int q = lq + s * 4;
        float4 va = *(const float4*)(A + (size_t)lr2 * K + k0 + q * 4);
        As_[(q * 4 + 0) * 64 + lr2] = va.x; As_[(q * 4 + 1) * 64 + lr2] = va.y;
        As_[(q * 4 + 2) * 64 + lr2] = va.z; As_[(q * 4 + 3) * 64 + lr2] = va.w;
        float4 vb = *(const float4*)(B + (size_t)(bn + lr2) * K + k0 + q * 4);
        Bs_[(q * 4 + 0) * 64 + lr2] = vb.x; Bs_[(q * 4 + 1) * 64 + lr2] = vb.y;
        Bs_[(q * 4 + 2) * 64 + lr2] = vb.z; Bs_[(q * 4 + 3) * 64 + lr2] = vb.w;
      }
      __syncthreads();
#pragma unroll
      for (int kk = 0; kk < 32; ++kk) {
        float a[4], b[4];
#pragma unroll
        for (int i2 = 0; i2 < 4; ++i2) { a[i2] = As_[kk * 64 + ty * 4 + i2]; b[i2] = Bs_[kk * 64 + tx * 4 + i2]; }
#pragma unroll
        for (int i2 = 0; i2 < 4; ++i2)
#pragma unroll
          for (int j2 = 0; j2 < 4; ++j2)
            acc[i2][j2] = fmaf(a[i2], b[j2], acc[i2][j2]);
      }
      __syncthreads();
    }
#pragma unroll
    for (int i2 = 0; i2 < 4; ++i2)
#pragma unroll
      for (int j2 = 0; j2 < 4; ++j2)
        C[(size_t)(ty * 4 + i2) * N + bn + tx * 4 + j2] = acc[i2][j2];
  } else {
    gemm_tile_body<0, 1, 0, 0, 0>(GA, GB, bx - 12, 0, 1, x0b, Bp1ext, nullptr, Cp1,
        nullptr, nullptr, nullptr, 0, Nn, 128, EMB, EMB, 0, nullptr, nullptr);
  }
}

// ---------------- Fused prep: hist + conversions + LoRA re-layouts + B-operand builds ----------------
__global__ void prep_all(const float* __restrict__ x0, const float* __restrict__ W1,
    const float* __restrict__ W2, const float* __restrict__ res_W,
    const float* __restrict__ A1, const float* __restrict__ A2,
    const float* __restrict__ B1, const float* __restrict__ B2,
    const float* __restrict__ attL1, const float* __restrict__ attR1,
    const float* __restrict__ attL2, const float* __restrict__ attR2,
    unsigned short* __restrict__ x0b,
    unsigned short* __restrict__ W2b, unsigned short* __restrict__ RWcat,
    float* __restrict__ Amat1, float* __restrict__ Amat2,
    unsigned short* __restrict__ Bp1ext, unsigned short* __restrict__ Bp2ext,
    unsigned short* __restrict__ Bcat1,
    float* __restrict__ awR1f, float* __restrict__ awR2f,
    const int* __restrict__ ii, int* __restrict__ ideg, int* __restrict__ prepos,
    int E, int nx0) {
  int idx = blockIdx.x * 256 + threadIdx.x;
  if (idx < E) { prepos[idx] = atomicAdd(&ideg[ii[idx]], 1); return; } idx -= E;
  if (idx < nx0) { x0b[idx] = f2bf(x0[idx]); return; } idx -= nx0;
  if (idx < OUTD * D2) { W2b[idx] = f2bf(W2[idx]); return; } idx -= OUTD * D2;
  if (idx < OUTD * EMB) { RWcat[(size_t)(idx >> 7) * KCAT + (idx & 127)] = f2bf(res_W[idx]); return; } idx -= OUTD * EMB;
  if (idx < 64 * EMB) { int d = idx % EMB, rk = idx / EMB, k = rk & 7, r = rk >> 3;
    Amat1[idx] = A1[(size_t)r * EMB * RANK + (size_t)d * RANK + k]; return; } idx -= 64 * EMB;
  if (idx < 64 * D2) { int d = idx % D2, rk = idx / D2, k = rk & 7, r = rk >> 3;
    Amat2[idx] = A2[(size_t)r * D2 * RANK + (size_t)d * RANK + k]; return; } idx -= 64 * D2;
  if (idx < 64 * EMB) { int d = idx % EMB, rk = idx / EMB, k = rk & 7, r = rk >> 3;
    Bp1ext[idx] = f2bf(B1[(size_t)r * EMB * RANK + (size_t)d * RANK + k]); return; } idx -= 64 * EMB;
  if (idx < 64 * D2) { int d = idx % D2, rk = idx / D2, k = rk & 7, r = rk >> 3;
    Bp2ext[idx] = f2bf(B2[(size_t)r * D2 * RANK + (size_t)d * RANK + k]); return; } idx -= 64 * D2;
  if (idx < 1024) {            // Bp1ext att rows 64-71 (+awR1f)
    int rr = idx >> 7, d = idx & 127;
    int h = rr & 3; bool isL = rr < 4;
    const float* att = isL ? attL1 : attR1;
    float s = 0.f;
    for (int c = 0; c < HID; ++c)
      s = fmaf(W1[(size_t)(h * HID + c) * EMB + d], att[h * HID + c], s);
    Bp1ext[(64 + rr) * 128 + d] = f2bf(s);
    if (!isL) awR1f[h * 128 + d] = s;
    return; } idx -= 1024;
  if (idx < 1024) {            // Bp2ext att rows 64-65 (+awR2f)
    int rr = idx >> 9, d = idx & 511;
    const float* att = (rr == 0) ? attL2 : attR2;
    float s = 0.f;
    for (int c = 0; c < OUTD; ++c)
      s = fmaf(W2[(size_t)c * D2 + d], att[c], s);
    Bp2ext[(size_t)(64 + rr) * 512 + d] = f2bf(s);
    if (rr == 1) awR2f[d] = s;
    return; } idx -= 1024;
  if (idx < 56 * 128) { Bp1ext[72 * 128 + idx] = 0; return; } idx -= 56 * 128;
  if (idx < 62 * 512) { Bp2ext[66 * 512 + idx] = 0; return; } idx -= 62 * 512;
  if (idx < 512 * 128) { int c = idx >> 7, t = idx & 127;
    Bcat1[(size_t)c * KCAT + t] = f2bf(W1[(size_t)c * EMB + t]); }
}

// ---------------- exscan (8/thread) + Matt folds in spare blocks ----------------
__global__ __launch_bounds__(1024) void exscan_matt(const int* __restrict__ deg,
    int* __restrict__ rowstart, int n,
    const float* __restrict__ Amat1, const float* __restrict__ awR1f, float* __restrict__ Matt1,
    const float* __restrict__ Amat2, const float* __restrict__ awR2f, float* __restrict__ Matt2) {
  if (blockIdx.x == 1) {
    int t = threadIdx.x;
    if (t < 256) {
      int rk = t >> 2, h = t & 3;
      float s = 0.f;
      for (int d = 0; d < 128; ++d)
        s = fmaf(Amat1[rk * 128 + d], awR1f[h * 128 + d], s);
      Matt1[t] = s;
    }
    return;
  }
  if (blockIdx.x == 2) {
    int t = threadIdx.x;
    if (t < 64) {
      float s = 0.f;
      for (int d = 0; d < 512; ++d) s = fmaf(Amat2[t * 512 + d], awR2f[d], s);
      Matt2[t] = s;
    }
    return;
  }
  __shared__ int wsum[16];
  int t = threadIdx.x;
  int lane = t & 63, wid = t >> 6;
  int carry = 0;
  for (int base = 0; base < n; base += 8192) {
    int i0 = base + t * 8;
    int v[8];
    if (i0 + 7 < n) {
      int4 a = *(const int4*)(deg + i0);
      int4 b = *(const int4*)(deg + i0 + 4);
      v[0] = a.x; v[1] = a.y; v[2] = a.z; v[3] = a.w;
      v[4] = b.x; v[5] = b.y; v[6] = b.z; v[7] = b.w;
    } else {
#pragma unroll
      for (int q = 0; q < 8; ++q) v[q] = (i0 + q < n) ? deg[i0 + q] : 0;
    }
    int tot = 0;
#pragma unroll
    for (int q = 0; q < 8; ++q) tot += v[q];
    int x = tot;
#pragma unroll
    for (int o = 1; o < 64; o <<= 1) {
      int y = __shfl_up(x, o, 64);
      if (lane >= o) x += y;
    }
    if (lane == 63) wsum[wid] = x;
    __syncthreads();
    if (t == 0) {
      int s = carry;
      for (int w2 = 0; w2 < 16; ++w2) { int tmp = wsum[w2]; wsum[w2] = s; s += tmp; }
      carry = s;
    }
    __syncthreads();
    int ex0 = x - tot + wsum[wid];
#pragma unroll
    for (int q = 0; q < 8; ++q) {
      if (i0 + q < n) rowstart[i0 + q] = ex0;
      ex0 += v[q];
    }
    __syncthreads();
  }
  if (t == 0) rowstart[n] = carry;
}

// ---------------- Combined: Bcat1/RWcat M-halves + layer-1 edge logits ----------------
// rec1 (3 float4 = 48B): [pack(rt<<27|j), ex0, ex1, ex2][ex3, low01, low23, low45][low67,0,0,0]
#define FB_BLOCKS 192
__global__ void combo_fold_ea1(const float* __restrict__ M1, const float* __restrict__ M2,
    unsigned short* __restrict__ Bcat1, unsigned short* __restrict__ RWcat,
    const int* __restrict__ ji, const int* __restrict__ ii,
    const int* __restrict__ et, const int* __restrict__ rowstart,
    const int* __restrict__ prepos, const float* __restrict__ Cp1,
    const float* __restrict__ relb1, const float* __restrict__ Matt1,
    float4* __restrict__ recs1, int E) {
  const int bx = blockIdx.x;
  if (bx < FB_BLOCKS) {
    int idx = bx * 256 + threadIdx.x;
    if (idx < 512 * 64) { int c = idx >> 6, rk = idx & 63;
      Bcat1[(size_t)c * KCAT + 128 + rk] = f2bf(M1[(size_t)rk * D2 + c]); return; }
    idx -= 512 * 64;
    if (idx < 256 * 64) { int c = idx >> 6, rk = idx & 63;
      RWcat[(size_t)c * KCAT + 128 + rk] = f2bf(M2[(size_t)rk * OUTD + c]); }
    return;
  }
  int e = (bx - FB_BLOCKS) * 256 + threadIdx.x;
  if (e >= E) return;
  int j = ji[e], i = ii[e], rt = et[e];
  float4 lo0 = *(const float4*)(Cp1 + (size_t)j * 128 + rt * 8);
  float4 lo1 = *(const float4*)(Cp1 + (size_t)j * 128 + rt * 8 + 4);
  float low[RANK] = {lo0.x, lo0.y, lo0.z, lo0.w, lo1.x, lo1.y, lo1.z, lo1.w};
  float4 ali = *(const float4*)(Cp1 + (size_t)i * 128 + 64);
  float4 arj = *(const float4*)(Cp1 + (size_t)j * 128 + 68);
  float4 rb  = *(const float4*)(relb1 + rt * 4);
  float a0 = ali.x + arj.x + rb.x;
  float a1 = ali.y + arj.y + rb.y;
  float a2 = ali.z + arj.z + rb.z;
  float a3 = ali.w + arj.w + rb.w;
#pragma unroll
  for (int k = 0; k < RANK; ++k) {
    float4 mk = *(const float4*)(Matt1 + ((rt * 8 + k) << 2));
    a0 = fmaf(low[k], mk.x, a0); a1 = fmaf(low[k], mk.y, a1);
    a2 = fmaf(low[k], mk.z, a2); a3 = fmaf(low[k], mk.w, a3);
  }
  a0 = (a0 > 0.f) ? a0 : NEG_SLOPE * a0;
  a1 = (a1 > 0.f) ? a1 : NEG_SLOPE * a1;
  a2 = (a2 > 0.f) ? a2 : NEG_SLOPE * a2;
  a3 = (a3 > 0.f) ? a3 : NEG_SLOPE * a3;
  float e0 = expf(a0), e1 = expf(a1), e2 = expf(a2), e3 = expf(a3);
  unsigned pack = ((unsigned)rt << 27) | (unsigned)j;
  float4* rp = recs1 + (size_t)(rowstart[i] + prepos[e]) * 3;
  rp[0] = make_float4(__uint_as_float(pack), e0, e1, e2);
  rp[1] = make_float4(e3, __uint_as_float(pk2(low[0], low[1])),
                      __uint_as_float(pk2(low[2], low[3])),
                      __uint_as_float(pk2(low[4], low[5])));
  rp[2] = make_float4(__uint_as_float(pk2(low[6], low[7])), 0.f, 0.f, 0.f);
}

// ---------------- Layer-1 fused Q/den + x0-gather: fills XQ1 [Nn][4x(128 Xw | 64 Q)] ----------------
__global__ __launch_bounds__(256) void agg1f(const float4* __restrict__ recs1,
    const int* __restrict__ rowstart, const unsigned short* __restrict__ x0b,
    unsigned short* __restrict__ XQ1, int Nn) {
  __shared__ float denS[4][32];          // [wid][h*8+rt]
  const int wid = threadIdx.x >> 6, lane = threadIdx.x & 63;
  const int i = blockIdx.x * 4 + wid;
  if (i >= Nn) return;
  const int rt_mine = lane >> 3, k = lane & 7;
  const int s0 = rowstart[i], deg = rowstart[i + 1] - s0;
  const float* rf = (const float*)recs1;
  const size_t xb = (size_t)i * 768;
  // ---- Phase A: LoRA Q sums + softmax denominators (lane = rt*8+k) ----
  {
    float q0 = 0.f, q1 = 0.f, q2 = 0.f, q3 = 0.f;
    float d0 = 0.f, d1 = 0.f, d2 = 0.f, d3 = 0.f;
    float4 a0 = {}, a1 = {};
    float a2x = 0.f;
    if (deg > 0) {
      a0 = recs1[(size_t)s0 * 3]; a1 = recs1[(size_t)s0 * 3 + 1];
      a2x = rf[(size_t)s0 * 12 + 8];
    }
    const int sel = k >> 1;
    for (int p = 0; p < deg; ++p) {
      float4 b0 = a0, b1 = a1; float b2x = a2x;
      if (p + 1 < deg) {
        b0 = recs1[(size_t)(s0 + p + 1) * 3]; b1 = recs1[(size_t)(s0 + p + 1) * 3 + 1];
        b2x = rf[(size_t)(s0 + p + 1) * 12 + 8];
      }
      int rt = (int)(asu(a0.x) >> 27);
      if (rt == rt_mine) {
        float pw = (sel == 0) ? a1.y : (sel == 1) ? a1.z : (sel == 2) ? a1.w : a2x;
        unsigned pu = asu(pw);
        float lw = bf2f((unsigned short)((k & 1) ? (pu >> 16) : (pu & 0xffff)));
        q0 = fmaf(a0.y, lw, q0); q1 = fmaf(a0.z, lw, q1);
        q2 = fmaf(a0.w, lw, q2); q3 = fmaf(a1.x, lw, q3);
        d0 += a0.y; d1 += a0.z; d2 += a0.w; d3 += a1.x;
      }
      a0 = b0; a1 = b1; a2x = b2x;
    }
    float r0 = (d0 > 0.f) ? 1.f / d0 : 0.f;
    float r1 = (d1 > 0.f) ? 1.f / d1 : 0.f;
    float r2 = (d2 > 0.f) ? 1.f / d2 : 0.f;
    float r3 = (d3 > 0.f) ? 1.f / d3 : 0.f;
    XQ1[xb + 0 * 192 + 128 + lane] = f2bf(q0 * r0);
    XQ1[xb + 1 * 192 + 128 + lane] = f2bf(q1 * r1);
    XQ1[xb + 2 * 192 + 128 + lane] = f2bf(q2 * r2);
    XQ1[xb + 3 * 192 + 128 + lane] = f2bf(q3 * r3);
    if (k == 0) {
      denS[wid][rt_mine]      = r0;
      denS[wid][8 + rt_mine]  = r1;
      denS[wid][16 + rt_mine] = r2;
      denS[wid][24 + rt_mine] = r3;
    }
  }
  // wave-synchronous LDS: same wave wrote denS[wid], no barrier needed
  // ---- Phase B: weighted x0 gather (lane = 2 cols, records now cache-hot) ----
  const int c0 = lane * 2;
  float acc[8] = {};
  float4 r0 = {}, r1 = {};
  float e30 = 0.f, e31 = 0.f;
  unsigned za = 0u;
  if (deg > 0) { r0 = recs1[(size_t)s0 * 3]; e30 = rf[(size_t)s0 * 12 + 4];
    za = *(const unsigned*)(x0b + (size_t)(asu(r0.x) & JMASK) * 128 + c0); }
  if (deg > 1) { r1 = recs1[(size_t)(s0 + 1) * 3]; e31 = rf[(size_t)(s0 + 1) * 12 + 4]; }
  for (int p = 0; p < deg; ++p) {
    float4 r2 = r1; float e32 = e31; unsigned zb = za;
    if (p + 2 < deg) { r2 = recs1[(size_t)(s0 + p + 2) * 3];
                       e32 = rf[(size_t)(s0 + p + 2) * 12 + 4]; }
    if (p + 1 < deg) zb = *(const unsigned*)(x0b + (size_t)(asu(r1.x) & JMASK) * 128 + c0);
    int rt = (int)(asu(r0.x) >> 27);
    float w0 = r0.y * denS[wid][rt];
    float w1 = r0.z * denS[wid][8 + rt];
    float w2 = r0.w * denS[wid][16 + rt];
    float w3 = e30 * denS[wid][24 + rt];
    float v0 = bf2f((unsigned short)(za & 0xffff));
    float v1 = bf2f((unsigned short)(za >> 16));
    acc[0] = fmaf(w0, v0, acc[0]); acc[1] = fmaf(w0, v1, acc[1]);
    acc[2] = fmaf(w1, v0, acc[2]); acc[3] = fmaf(w1, v1, acc[3]);
    acc[4] = fmaf(w2, v0, acc[4]); acc[5] = fmaf(w2, v1, acc[5]);
    acc[6] = fmaf(w3, v0, acc[6]); acc[7] = fmaf(w3, v1, acc[7]);
    r0 = r1; e30 = e31; r1 = r2; e31 = e32; za = zb;
  }
#pragma unroll
  for (int h = 0; h < 4; ++h) {
    unsigned pv = pk2(acc[2 * h], acc[2 * h + 1]);
    *(unsigned*)(XQ1 + xb + h * 192 + c0) = pv;
  }
}

// ---------------- Layer-2 edge logits -> packed records ----------------
// rec2 (2 float4 = 32B): [pack, ex, low01, low23][low45, low67, 0, 0]
__global__ void edge_alpha2(const int* __restrict__ ji, const int* __restrict__ ii,
                            const int* __restrict__ et, const int* __restrict__ rowstart,
                            const int* __restrict__ prepos,
                            const float* __restrict__ Cp2,
                            const float* __restrict__ relb2, const float* __restrict__ Matt2,
                            float4* __restrict__ recs2, int E) {
  int e = blockIdx.x * blockDim.x + threadIdx.x;
  if (e >= E) return;
  int j = ji[e], i = ii[e], rt = et[e];
  float4 lo0 = *(const float4*)(Cp2 + (size_t)j * 128 + rt * 8);
  float4 lo1 = *(const float4*)(Cp2 + (size_t)j * 128 + rt * 8 + 4);
  float low[RANK] = {lo0.x, lo0.y, lo0.z, lo0.w, lo1.x, lo1.y, lo1.z, lo1.w};
  float a = Cp2[(size_t)i * 128 + 64] + Cp2[(size_t)j * 128 + 65] + relb2[rt];
#pragma unroll
  for (int k = 0; k < RANK; ++k) a = fmaf(low[k], Matt2[rt * RANK + k], a);
  a = (a > 0.f) ? a : NEG_SLOPE * a;
  float ex = expf(a);
  unsigned pack = ((unsigned)rt << 27) | (unsigned)j;
  float4* rp = recs2 + (size_t)(rowstart[i] + prepos[e]) * 2;
  rp[0] = make_float4(__uint_as_float(pack), ex,
                      __uint_as_float(pk2(low[0], low[1])),
                      __uint_as_float(pk2(low[2], low[3])));
  rp[1] = make_float4(__uint_as_float(pk2(low[4], low[5])),
                      __uint_as_float(pk2(low[6], low[7])), 0.f, 0.f);
}

// ---------------- Layer-2 Q/den: Q2b [Nn][64] bf16, rden2[Nn][8] ----------------
__global__ __launch_bounds__(256) void qden2(const float4* __restrict__ recs2,
    const int* __restrict__ rowstart, unsigned short* __restrict__ Q2b,
    float* __restrict__ rden2, int Nn) {
  const int wid = threadIdx.x >> 6, lane = threadIdx.x & 63;
  const int i = blockIdx.x * 4 + wid;
  if (i >= Nn) return;
  const int rt_mine = lane >> 3, k = lane & 7;
  const int s0 = rowstart[i], deg = rowstart[i + 1] - s0;
  const float* rf = (const float*)recs2;
  float q = 0.f, d = 0.f;
  float4 a0 = {}; float2 a1 = {};
  if (deg > 0) { a0 = recs2[(size_t)s0 * 2]; a1 = *(const float2*)(rf + (size_t)s0 * 8 + 4); }
  const int sel = k >> 1;
  for (int p = 0; p < deg; ++p) {
    float4 b0 = a0; float2 b1 = a1;
    if (p + 1 < deg) {
      b0 = recs2[(size_t)(s0 + p + 1) * 2];
      b1 = *(const float2*)(rf + (size_t)(s0 + p + 1) * 8 + 4);
    }
    int rt = (int)(asu(a0.x) >> 27);
    if (rt == rt_mine) {
      float pw = (sel == 0) ? a0.z : (sel == 1) ? a0.w : (sel == 2) ? a1.x : a1.y;
      unsigned pu = asu(pw);
      float lw = bf2f((unsigned short)((k & 1) ? (pu >> 16) : (pu & 0xffff)));
      q = fmaf(a0.y, lw, q); d += a0.y;
    }
    a0 = b0; a1 = b1;
  }
  float rd = (d > 0.f) ? 1.f / d : 0.f;
  Q2b[(size_t)i * 64 + lane] = f2bf(q * rd);
  if (k == 0) rden2[(size_t)i * 8 + rt_mine] = rd;
}

// ---------------- Layer-2 gather + residual/lora/bias (o2) + LN -> out ----------------
__global__ __launch_bounds__(256) void node_agg2_lite(const float4* __restrict__ recs2,
    const int* __restrict__ rowstart, const unsigned short* __restrict__ z2b,
    const float* __restrict__ rden2, const float* __restrict__ o2,
    const float* __restrict__ ln_g, const float* __restrict__ ln_b,
    float* __restrict__ y, int Nn) {
  const int wid = threadIdx.x >> 6;
  const int lane = threadIdx.x & 63;
  const int i = blockIdx.x * 4 + wid;
  if (i >= Nn) return;
  __shared__ float denS[4][NRELS];
  if (lane < NRELS) denS[wid][lane] = rden2[(size_t)i * 8 + lane];
  // wave-synchronous LDS, no barrier
  const int s0 = rowstart[i];
  const int deg = rowstart[i + 1] - s0;
  const int c0 = lane * 4;
  // hoist independent loads: residual row + LN params issue under the gather chase
  float4 rsv = *(const float4*)(o2 + (size_t)i * OUTD + c0);   // residual+lora2+bias2+res_b
  float4 g = *(const float4*)(ln_g + c0);
  float4 bb = *(const float4*)(ln_b + c0);
  float acc[4] = {};
  float4 r0 = {}, r1 = {}, r2 = {};
  uint2 za = make_uint2(0u, 0u), zb = make_uint2(0u, 0u);
  if (deg > 0) { r0 = recs2[(size_t)s0 * 2];
    za = *(const uint2*)(z2b + (size_t)(asu(r0.x) & JMASK) * OUTD + c0); }
  if (deg > 1) { r1 = recs2[(size_t)(s0 + 1) * 2];
    zb = *(const uint2*)(z2b + (size_t)(asu(r1.x) & JMASK) * OUTD + c0); }
  if (deg > 2) r2 = recs2[(size_t)(s0 + 2) * 2];
  for (int p = 0; p < deg; ++p) {
    float4 r3 = r2;
    uint2 zn = zb;
    if (p + 3 < deg) r3 = recs2[(size_t)(s0 + p + 3) * 2];
    if (p + 2 < deg)
      zn = *(const uint2*)(z2b + (size_t)(asu(r2.x) & JMASK) * OUTD + c0);
    int rt = (int)(asu(r0.x) >> 27);
    float wt = r0.y * denS[wid][rt];
    acc[0] = fmaf(wt, bf2f((unsigned short)(za.x & 0xffff)), acc[0]);
    acc[1] = fmaf(wt, bf2f((unsigned short)(za.x >> 16)), acc[1]);
    acc[2] = fmaf(wt, bf2f((unsigned short)(za.y & 0xffff)), acc[2]);
    acc[3] = fmaf(wt, bf2f((unsigned short)(za.y >> 16)), acc[3]);
    r0 = r1; r1 = r2; r2 = r3; za = zb; zb = zn;
  }
  float vv[4];
  vv[0] = acc[0] + rsv.x;
  vv[1] = acc[1] + rsv.y;
  vv[2] = acc[2] + rsv.z;
  vv[3] = acc[3] + rsv.w;
  float s = vv[0] + vv[1] + vv[2] + vv[3];
  for (int o = 32; o > 0; o >>= 1) s += __shfl_xor(s, o, 64);
  float mu = s * (1.f / OUTD);
  float q = 0.f;
#pragma unroll
  for (int k = 0; k < 4; ++k) { float d = vv[k] - mu; q += d * d; }
  for (int o = 32; o > 0; o >>= 1) q += __shfl_xor(q, o, 64);
  float rstd = rsqrtf(q * (1.f / OUTD) + LN_EPS);
  float4 ov;
  ov.x = (vv[0] - mu) * rstd * g.x + bb.x;
  ov.y = (vv[1] - mu) * rstd * g.y + bb.y;
  ov.z = (vv[2] - mu) * rstd * g.z + bb.z;
  ov.w = (vv[3] - mu) * rstd * g.w + bb.w;
  *(float4*)(y + (size_t)i * OUTD + c0) = ov;
}

extern "C" void kernel_launch(void* const* d_in, const int* in_sizes, int n_in,
                              void* d_out, int out_size, void* d_ws, size_t ws_size,
                              hipStream_t stream) {
  const float* x0     = (const float*)d_in[0];
  const float* A1     = (const float*)d_in[1];
  const float* B1     = (const float*)d_in[2];
  const float* W1     = (const float*)d_in[3];
  const float* attL1  = (const float*)d_in[4];
  const float* attR1  = (const float*)d_in[5];
  const float* relb1  = (const float*)d_in[6];
  const float* bias1  = (const float*)d_in[7];
  const float* A2     = (const float*)d_in[8];
  const float* B2     = (const float*)d_in[9];
  const float* W2     = (const float*)d_in[10];
  const float* attL2  = (const float*)d_in[11];
  const float* attR2  = (const float*)d_in[12];
  const float* relb2  = (const float*)d_in[13];
  const float* bias2  = (const float*)d_in[14];
  const float* res_W  = (const float*)d_in[15];
  const float* res_b  = (const float*)d_in[16];
  const float* ln_g   = (const float*)d_in[17];
  const float* ln_b   = (const float*)d_in[18];
  const int*   eidx   = (const int*)d_in[19];
  const int*   etype  = (const int*)d_in[20];
  float* out = (float*)d_out;

  const int Nn = in_sizes[0] / EMB;     // 30000
  const int E  = in_sizes[20];          // 150000
  const int* ji = eidx;
  const int* ii = eidx + E;

  // ---- workspace carve-up (float units; all offsets stay 16B-aligned) ----
  float* w = (float*)d_ws;
  size_t off = 0;
  float* o2    = w + off; off += (size_t)Nn * OUTD;
  float* Cp1   = w + off; off += (size_t)Nn * 128;    // P1 + al1/ar1
  float* Cp2   = w + off; off += (size_t)Nn * 128;    // P2 + al2/ar2
  float* M1    = w + off; off += 64 * D2;
  float* M2    = w + off; off += 64 * OUTD;
  float* Amat1 = w + off; off += 64 * EMB;
  float* Amat2 = w + off; off += 64 * D2;
  float* Matt1 = w + off; off += 64 * 4;
  float* Matt2 = w + off; off += 64;
  float* awR1f = w + off; off += 512;
  float* awR2f = w + off; off += 512;
  float* rden2 = w + off; off += (size_t)Nn * 8;
  float4* recs1 = (float4*)(w + off); off += (size_t)E * 12;   // 48B records
  float4* recs2 = (float4*)(w + off); off += (size_t)E * 8;    // 32B records
  unsigned short* z2b    = (unsigned short*)(w + off); off += (size_t)Nn * OUTD / 2;
  unsigned short* x0b    = (unsigned short*)(w + off); off += (size_t)Nn * EMB / 2;
  unsigned short* h1b    = (unsigned short*)(w + off); off += (size_t)Nn * D2 / 2;
  unsigned short* XQ1    = (unsigned short*)(w + off); off += (size_t)Nn * 768 / 2;
  unsigned short* Q2b    = (unsigned short*)(w + off); off += (size_t)Nn * 64 / 2;
  unsigned short* W2b    = (unsigned short*)(w + off); off += (size_t)OUTD * D2 / 2;
  unsigned short* RWcat  = (unsigned short*)(w + off); off += (size_t)OUTD * KCAT / 2;
  unsigned short* Bcat1  = (unsigned short*)(w + off); off += (size_t)512 * KCAT / 2;
  unsigned short* Bp1ext = (unsigned short*)(w + off); off += (size_t)128 * 128 / 2;
  unsigned short* Bp2ext = (unsigned short*)(w + off); off += (size_t)128 * 512 / 2;
  int* ideg     = (int*)(w + off); off += (size_t)Nn;
  int* prepos   = (int*)(w + off); off += (size_t)E;
  int* rowstart = (int*)(w + off); off += (size_t)Nn + 1;
  (void)ws_size; (void)n_in; (void)out_size;

  const int MT128 = (Nn + 127) / 128;
  const int NB4 = (Nn + 3) / 4;

  // 0) fused prep: hist + conversions + all M-independent B-operand builds
  (void)hipMemsetAsync(ideg, 0, (size_t)Nn * sizeof(int), stream);
  {
    int nx0 = Nn * EMB;
    int total = E + nx0 + OUTD * D2 + OUTD * EMB + 64 * EMB + 64 * D2
              + 64 * EMB + 64 * D2 + 1024 + 1024 + 56 * 128 + 62 * 512 + 512 * 128;
    prep_all<<<(total + 255) / 256, 256, 0, stream>>>(x0, W1, W2, res_W, A1, A2, B1, B2,
        attL1, attR1, attL2, attR2, x0b, W2b, RWcat, Amat1, Amat2,
        Bp1ext, Bp2ext, Bcat1, awR1f, awR2f, ii, ideg, prepos, E, nx0);
  }

  // 1) exscan + Matt folds (spare blocks)
  exscan_matt<<<3, 1024, 0, stream>>>(ideg, rowstart, Nn, Amat1, awR1f, Matt1,
                                      Amat2, awR2f, Matt2);

  // 2) M1/M2 fp32 GEMMs + P1/att GEMM (one dispatch)
  combo_abt_p1<<<12 + MT128, 256, 0, stream>>>(Amat1, W1, M1, Amat2, W2, M2,
                                               x0b, Bp1ext, Cp1, Nn);

  // 3) Bcat1/RWcat M-halves + layer-1 edge logits (one dispatch)
  combo_fold_ea1<<<FB_BLOCKS + (E + 255) / 256, 256, 0, stream>>>(M1, M2, Bcat1, RWcat,
      ji, ii, etype, rowstart, prepos, Cp1, relb1, Matt1, recs1, E);

  // 4) fused Q/den + x0-gather; msg GEMM -> h1 (elu+bias fused)
  agg1f<<<NB4, 256, 0, stream>>>(recs1, rowstart, x0b, XQ1, Nn);
  gemm_tile<1, 0, 1, 0, 0><<<dim3(MT128, 4), 256, 0, stream>>>(XQ1, Bcat1, h1b, nullptr,
      nullptr, nullptr, nullptr, 0, Nn, D2, KCAT, 768, KCAT, bias1, nullptr);

  // 5) Layer-2: z2 GEMM + P2/att slice, XCD-trio swizzled (same-row-panel tiles co-XCD)
  {
    int ngrp = (MT128 + 7) / 8;
    gemm_tile_z2<<<ngrp * 24, 256, 0, stream>>>(h1b, W2b, z2b, Bp2ext, Cp2,
                                                Nn, OUTD, D2, MT128);
  }

  // 6) Layer-2 edge logits; Q/den (compact Q2b); two-source residual+lora GEMM; gather + LN
  edge_alpha2<<<(E + 255) / 256, 256, 0, stream>>>(ji, ii, etype, rowstart, prepos, Cp2,
                                                   relb2, Matt2, recs2, E);
  qden2<<<NB4, 256, 0, stream>>>(recs2, rowstart, Q2b, rden2, Nn);
  gemm_tile<1, 1, 0, 0, 1><<<dim3(MT128, 2), 256, 0, stream>>>(x0b, RWcat, nullptr, o2,
      nullptr, nullptr, Q2b, 64, Nn, OUTD, KCAT, EMB, 0, bias2, res_b);
  node_agg2_lite<<<NB4, 256, 0, stream>>>(recs2, rowstart, z2b, rden2, o2, ln_g, ln_b, out, Nn);
}

// Round 10
// 336.596 us; speedup vs baseline: 1.1164x; 1.0023x over previous
//
#include <hip/hip_runtime.h>
#include <cstddef>

#define NRELS 8
#define EMB 128
#define HID 128
#define OUTD 256
#define HEADS 4
#define RANK 8
#define D2 512            // HEADS*HID, conv2 input dim
#define KCAT 192          // EMB + 64, concatenated K
#define NEG_SLOPE 0.2f
#define LN_EPS 1e-5f
#define JMASK 0x07FFFFFFu

typedef short bf16x8 __attribute__((ext_vector_type(8)));   // 8 bf16 in 4 VGPRs
typedef float f32x4 __attribute__((ext_vector_type(4)));

__device__ __forceinline__ unsigned short f2bf(float f) {   // RNE
  union { float f; unsigned u; } v; v.f = f;
  unsigned u = v.u;
  return (unsigned short)((u + 0x7fffu + ((u >> 16) & 1u)) >> 16);
}
__device__ __forceinline__ float bf2f(unsigned short u) {
  union { unsigned u; float f; } v; v.u = (unsigned)u << 16; return v.f;
}
__device__ __forceinline__ unsigned pk2(float a, float b) {
  return (unsigned)f2bf(a) | ((unsigned)f2bf(b) << 16);
}
__device__ __forceinline__ unsigned asu(float f) { return __float_as_uint(f); }

// async global->LDS, 16B per lane; LDS dest = wave-uniform base + lane*16
#define GLOAD16(ldsp, gp) \
  __builtin_amdgcn_global_load_lds((const __attribute__((address_space(1))) unsigned int*)(gp), \
      (__attribute__((address_space(3))) unsigned int*)(ldsp), 16, 0, 0)

// ---------------- Unified big-tile bf16 MFMA GEMM body (128x128 tile, BK=32, LDS dbuf) ----------------
// Double-buffered global_load_lds staging; one __syncthreads per K-step.
// Chunk-XOR involution (2-way bank aliasing = free).
// PB: last by slice runs the same GEMM against Bp, f32 out to Cp stride 128.
template<int BIAS, int F32OUT, int ELU, int PB>
__device__ __forceinline__ void gemm_tile_body(unsigned short* AsB, unsigned short* BsB,
    int bx, int by, int ny,
    const unsigned short* __restrict__ A, const unsigned short* __restrict__ B,
    unsigned short* __restrict__ C, float* __restrict__ Cf,
    const unsigned short* __restrict__ Bp, float* __restrict__ Cp,
    int M, int N, int K, int lda, int aoffc,
    const float* __restrict__ bias, const float* __restrict__ b1p) {
  const int tid = threadIdx.x;
  const int wave = tid >> 6;
  const int lane = tid & 63;
  const int wm = wave & 1;
  const int wn = wave >> 1;
  const int r16 = lane & 15;
  const int quad = lane >> 4;
  const int bm = bx * 128;
  const int lr = lane >> 2;                                  // 0..15
  const int lc = ((lane & 3) ^ ((lane >> 3) & 3)) * 8;       // swizzled source col chunk
  const int rsw = (quad ^ ((r16 >> 1) & 3)) * 8;             // fragment read swizzle
  const bool isP = PB && (by == ny - 1);
  const unsigned short* Bu = isP ? Bp : B;
  const int bn = isP ? 0 : by * 128;
  const unsigned short* Abase = A + (size_t)by * (isP ? 0 : aoffc);
  int ar0 = bm + wave * 32 + lr;      if (ar0 >= M) ar0 = M - 1;
  int ar1 = bm + wave * 32 + 16 + lr; if (ar1 >= M) ar1 = M - 1;
  const unsigned short* Ag0 = Abase + (size_t)ar0 * lda + lc;
  const unsigned short* Ag1 = Abase + (size_t)ar1 * lda + lc;
  const unsigned short* Bg0 = Bu + (size_t)(bn + wave * 32 + lr) * K + lc;
  const unsigned short* Bg1 = Bu + (size_t)(bn + wave * 32 + 16 + lr) * K + lc;
  f32x4 acc[4][4] = {};
  GLOAD16(AsB + wave * 1024, Ag0);
  GLOAD16(AsB + wave * 1024 + 512, Ag1);
  GLOAD16(BsB + wave * 1024, Bg0);
  GLOAD16(BsB + wave * 1024 + 512, Bg1);
  __syncthreads();
  int cur = 0;
  for (int k0 = 0; k0 < K; k0 += 32) {
    if (k0 + 32 < K) {
      GLOAD16(AsB + (cur ^ 1) * 4096 + wave * 1024, Ag0 + k0 + 32);
      GLOAD16(AsB + (cur ^ 1) * 4096 + wave * 1024 + 512, Ag1 + k0 + 32);
      GLOAD16(BsB + (cur ^ 1) * 4096 + wave * 1024, Bg0 + k0 + 32);
      GLOAD16(BsB + (cur ^ 1) * 4096 + wave * 1024 + 512, Bg1 + k0 + 32);
    }
    bf16x8 af[4], bfr[4];
#pragma unroll
    for (int mi = 0; mi < 4; ++mi)
      af[mi] = *(const bf16x8*)(AsB + cur * 4096 + (wm * 64 + mi * 16 + r16) * 32 + rsw);
#pragma unroll
    for (int ni = 0; ni < 4; ++ni)
      bfr[ni] = *(const bf16x8*)(BsB + cur * 4096 + (wn * 64 + ni * 16 + r16) * 32 + rsw);
#pragma unroll
    for (int mi = 0; mi < 4; ++mi)
#pragma unroll
      for (int ni = 0; ni < 4; ++ni)
        acc[mi][ni] = __builtin_amdgcn_mfma_f32_16x16x32_bf16(af[mi], bfr[ni], acc[mi][ni], 0, 0, 0);
    __syncthreads();
    cur ^= 1;
  }
  float bcol[4];
  if (BIAS) {
#pragma unroll
    for (int ni = 0; ni < 4; ++ni) {
      int cn = bn + wn * 64 + ni * 16 + r16;
      bcol[ni] = bias[cn];
      if (F32OUT) bcol[ni] += b1p[cn];
    }
  }
#pragma unroll
  for (int mi = 0; mi < 4; ++mi)
#pragma unroll
    for (int ni = 0; ni < 4; ++ni)
#pragma unroll
      for (int r = 0; r < 4; ++r) {
        int row = bm + wm * 64 + mi * 16 + quad * 4 + r;
        if (row < M) {
          int col = wn * 64 + ni * 16 + r16;
          float v = acc[mi][ni][r];
          if (isP) {
            Cp[(size_t)row * 128 + col] = v;
          } else {
            if (BIAS) v += bcol[ni];
            if (ELU) v = v > 0.f ? v : expm1f(v);
            size_t idx = (size_t)row * N + bn + col;
            if (F32OUT) Cf[idx] = v;
            else        C[idx] = f2bf(v);
          }
        }
      }
}

template<int BIAS, int F32OUT, int ELU, int PB>
__global__ __launch_bounds__(256) void gemm_tile(const unsigned short* __restrict__ A,
    const unsigned short* __restrict__ B, unsigned short* __restrict__ C,
    float* __restrict__ Cf, const unsigned short* __restrict__ Bp,
    float* __restrict__ Cp, int M, int N, int K, int lda, int aoffc,
    const float* __restrict__ bias, const float* __restrict__ b1p) {
  __shared__ unsigned short As[2 * 4096];
  __shared__ unsigned short Bs[2 * 4096];
  gemm_tile_body<BIAS, F32OUT, ELU, PB>(As, Bs, blockIdx.x, blockIdx.y, gridDim.y,
      A, B, C, Cf, Bp, Cp, M, N, K, lda, aoffc, bias, b1p);
}

// ---------------- XCD-group swizzled launcher: NY col-slices of same row-panel co-XCD ----------------
// id -> g = id/(8*NY), r = id%(8*NY), by = r>>3, bx = g*8 + (r&7): group {s, s+8, ...} same XCD.
template<int BIAS, int F32OUT, int ELU, int PB, int NY>
__global__ __launch_bounds__(256) void gemm_tile_swz(const unsigned short* __restrict__ A,
    const unsigned short* __restrict__ B, unsigned short* __restrict__ C,
    float* __restrict__ Cf, const unsigned short* __restrict__ Bp,
    float* __restrict__ Cp, int M, int N, int K, int lda, int aoffc,
    const float* __restrict__ bias, const float* __restrict__ b1p, int nbx) {
  __shared__ unsigned short As[2 * 4096];
  __shared__ unsigned short Bs[2 * 4096];
  int id = blockIdx.x;
  int g = id / (8 * NY), r = id % (8 * NY);
  int by = r >> 3;
  int bx = g * 8 + (r & 7);
  if (bx >= nbx) return;
  gemm_tile_body<BIAS, F32OUT, ELU, PB>(As, Bs, bx, by, NY,
      A, B, C, Cf, Bp, Cp, M, N, K, lda, aoffc, bias, b1p);
}

// ---------------- Combined: tiny fp32 GEMMs (M1,M2) + P1 GEMM in one dispatch ----------------
__global__ __launch_bounds__(256) void combo_abt_p1(const float* __restrict__ Amat1,
    const float* __restrict__ W1, float* __restrict__ M1o,
    const float* __restrict__ Amat2, const float* __restrict__ W2, float* __restrict__ M2o,
    const unsigned short* __restrict__ x0b, const unsigned short* __restrict__ Bp1ext,
    float* __restrict__ Cp1, int Nn) {
  __shared__ unsigned short GA[2 * 4096];
  __shared__ unsigned short GB[2 * 4096];
  const int bx = blockIdx.x;
  if (bx < 12) {
    float* As_ = (float*)GA;   // [32][64] = 8KB (fits in 16KB)
    float* Bs_ = (float*)GB;
    const float* A; const float* B; float* C; int N, K, bn;
    if (bx < 8) { A = Amat1; B = W1; C = M1o; N = D2; K = EMB; bn = bx * 64; }
    else { A = Amat2; B = W2; C = M2o; N = OUTD; K = D2; bn = (bx - 8) * 64; }
    const int tid = threadIdx.x;
    const int tx = tid & 15;
    const int ty = tid >> 4;
    const int lr2 = tid & 63;
    const int lq = tid >> 6;
    float acc[4][4] = {};
    for (int k0 = 0; k0 < K; k0 += 32) {
#pragma unroll
      for (int s = 0; s < 2; ++s) {
        const int q = lq + s * 4;
        float4 va = *(const float4*)(A + (size_t)lr2 * K + k0 + q * 4);
        As_[(q * 4 + 0) * 64 + lr2] = va.x; As_[(q * 4 + 1) * 64 + lr2] = va.y;
        As_[(q * 4 + 2) * 64 + lr2] = va.z; As_[(q * 4 + 3) * 64 + lr2] = va.w;
        float4 vb = *(const float4*)(B + (size_t)(bn + lr2) * K + k0 + q * 4);
        Bs_[(q * 4 + 0) * 64 + lr2] = vb.x; Bs_[(q * 4 + 1) * 64 + lr2] = vb.y;
        Bs_[(q * 4 + 2) * 64 + lr2] = vb.z; Bs_[(q * 4 + 3) * 64 + lr2] = vb.w;
      }
      __syncthreads();
#pragma unroll
      for (int kk = 0; kk < 32; ++kk) {
        float a[4], b[4];
#pragma unroll
        for (int i2 = 0; i2 < 4; ++i2) { a[i2] = As_[kk * 64 + ty * 4 + i2]; b[i2] = Bs_[kk * 64 + tx * 4 + i2]; }
#pragma unroll
        for (int i2 = 0; i2 < 4; ++i2)
#pragma unroll
          for (int j2 = 0; j2 < 4; ++j2)
            acc[i2][j2] = fmaf(a[i2], b[j2], acc[i2][j2]);
      }
      __syncthreads();
    }
#pragma unroll
    for (int i2 = 0; i2 < 4; ++i2)
#pragma unroll
      for (int j2 = 0; j2 < 4; ++j2)
        C[(size_t)(ty * 4 + i2) * N + bn + tx * 4 + j2] = acc[i2][j2];
  } else {
    gemm_tile_body<0, 1, 0, 0>(GA, GB, bx - 12, 0, 1, x0b, Bp1ext, nullptr, Cp1,
        nullptr, nullptr, Nn, 128, EMB, EMB, 0, nullptr, nullptr);
  }
}

// ---------------- Fused prep: hist + conversions + LoRA re-layouts + B-operand builds ----------------
__global__ void prep_all(const float* __restrict__ x0, const float* __restrict__ W1,
    const float* __restrict__ W2, const float* __restrict__ res_W,
    const float* __restrict__ A1, const float* __restrict__ A2,
    const float* __restrict__ B1, const float* __restrict__ B2,
    const float* __restrict__ attL1, const float* __restrict__ attR1,
    const float* __restrict__ attL2, const float* __restrict__ attR2,
    unsigned short* __restrict__ x0b, unsigned short* __restrict__ Acat,
    unsigned short* __restrict__ W2b, unsigned short* __restrict__ RWcat,
    float* __restrict__ Amat1, float* __restrict__ Amat2,
    unsigned short* __restrict__ Bp1ext, unsigned short* __restrict__ Bp2ext,
    unsigned short* __restrict__ Bcat1,
    float* __restrict__ awR1f, float* __restrict__ awR2f,
    const int* __restrict__ ii, int* __restrict__ ideg, int* __restrict__ prepos,
    int E, int nx0) {
  int idx = blockIdx.x * 256 + threadIdx.x;
  if (idx < E) { prepos[idx] = atomicAdd(&ideg[ii[idx]], 1); return; } idx -= E;
  if (idx < nx0) { unsigned short b = f2bf(x0[idx]); x0b[idx] = b;
    Acat[(size_t)(idx >> 7) * KCAT + (idx & 127)] = b; return; } idx -= nx0;
  if (idx < OUTD * D2) { W2b[idx] = f2bf(W2[idx]); return; } idx -= OUTD * D2;
  if (idx < OUTD * EMB) { RWcat[(size_t)(idx >> 7) * KCAT + (idx & 127)] = f2bf(res_W[idx]); return; } idx -= OUTD * EMB;
  if (idx < 64 * EMB) { int d = idx % EMB, rk = idx / EMB, k = rk & 7, r = rk >> 3;
    Amat1[idx] = A1[(size_t)r * EMB * RANK + (size_t)d * RANK + k]; return; } idx -= 64 * EMB;
  if (idx < 64 * D2) { int d = idx % D2, rk = idx / D2, k = rk & 7, r = rk >> 3;
    Amat2[idx] = A2[(size_t)r * D2 * RANK + (size_t)d * RANK + k]; return; } idx -= 64 * D2;
  if (idx < 64 * EMB) { int d = idx % EMB, rk = idx / EMB, k = rk & 7, r = rk >> 3;
    Bp1ext[idx] = f2bf(B1[(size_t)r * EMB * RANK + (size_t)d * RANK + k]); return; } idx -= 64 * EMB;
  if (idx < 64 * D2) { int d = idx % D2, rk = idx / D2, k = rk & 7, r = rk >> 3;
    Bp2ext[idx] = f2bf(B2[(size_t)r * D2 * RANK + (size_t)d * RANK + k]); return; } idx -= 64 * D2;
  if (idx < 1024) {            // Bp1ext att rows 64-71 (+awR1f)
    int rr = idx >> 7, d = idx & 127;
    int h = rr & 3; bool isL = rr < 4;
    const float* att = isL ? attL1 : attR1;
    float s = 0.f;
    for (int c = 0; c < HID; ++c)
      s = fmaf(W1[(size_t)(h * HID + c) * EMB + d], att[h * HID + c], s);
    Bp1ext[(64 + rr) * 128 + d] = f2bf(s);
    if (!isL) awR1f[h * 128 + d] = s;
    return; } idx -= 1024;
  if (idx < 1024) {            // Bp2ext att rows 64-65 (+awR2f)
    int rr = idx >> 9, d = idx & 511;
    const float* att = (rr == 0) ? attL2 : attR2;
    float s = 0.f;
    for (int c = 0; c < OUTD; ++c)
      s = fmaf(W2[(size_t)c * D2 + d], att[c], s);
    Bp2ext[(size_t)(64 + rr) * 512 + d] = f2bf(s);
    if (rr == 1) awR2f[d] = s;
    return; } idx -= 1024;
  if (idx < 56 * 128) { Bp1ext[72 * 128 + idx] = 0; return; } idx -= 56 * 128;
  if (idx < 62 * 512) { Bp2ext[66 * 512 + idx] = 0; return; } idx -= 62 * 512;
  if (idx < 512 * 128) { int c = idx >> 7, t = idx & 127;
    Bcat1[(size_t)c * KCAT + t] = f2bf(W1[(size_t)c * EMB + t]); }
}

// ---------------- exscan (8/thread) + Matt folds in spare blocks ----------------
__global__ __launch_bounds__(1024) void exscan_matt(const int* __restrict__ deg,
    int* __restrict__ rowstart, int n,
    const float* __restrict__ Amat1, const float* __restrict__ awR1f, float* __restrict__ Matt1,
    const float* __restrict__ Amat2, const float* __restrict__ awR2f, float* __restrict__ Matt2) {
  if (blockIdx.x == 1) {
    int t = threadIdx.x;
    if (t < 256) {
      int rk = t >> 2, h = t & 3;
      float s = 0.f;
      for (int d = 0; d < 128; ++d)
        s = fmaf(Amat1[rk * 128 + d], awR1f[h * 128 + d], s);
      Matt1[t] = s;
    }
    return;
  }
  if (blockIdx.x == 2) {
    int t = threadIdx.x;
    if (t < 64) {
      float s = 0.f;
      for (int d = 0; d < 512; ++d) s = fmaf(Amat2[t * 512 + d], awR2f[d], s);
      Matt2[t] = s;
    }
    return;
  }
  __shared__ int wsum[16];
  int t = threadIdx.x;
  int lane = t & 63, wid = t >> 6;
  int carry = 0;
  for (int base = 0; base < n; base += 8192) {
    int i0 = base + t * 8;
    int v[8];
    if (i0 + 7 < n) {
      int4 a = *(const int4*)(deg + i0);
      int4 b = *(const int4*)(deg + i0 + 4);
      v[0] = a.x; v[1] = a.y; v[2] = a.z; v[3] = a.w;
      v[4] = b.x; v[5] = b.y; v[6] = b.z; v[7] = b.w;
    } else {
#pragma unroll
      for (int q = 0; q < 8; ++q) v[q] = (i0 + q < n) ? deg[i0 + q] : 0;
    }
    int tot = 0;
#pragma unroll
    for (int q = 0; q < 8; ++q) tot += v[q];
    int x = tot;
#pragma unroll
    for (int o = 1; o < 64; o <<= 1) {
      int y = __shfl_up(x, o, 64);
      if (lane >= o) x += y;
    }
    if (lane == 63) wsum[wid] = x;
    __syncthreads();
    if (t == 0) {
      int s = carry;
      for (int w2 = 0; w2 < 16; ++w2) { int tmp = wsum[w2]; wsum[w2] = s; s += tmp; }
      carry = s;
    }
    __syncthreads();
    int ex0 = x - tot + wsum[wid];
#pragma unroll
    for (int q = 0; q < 8; ++q) {
      if (i0 + q < n) rowstart[i0 + q] = ex0;
      ex0 += v[q];
    }
    __syncthreads();
  }
  if (t == 0) rowstart[n] = carry;
}

// ---------------- Combined: Bcat1/RWcat M-halves + layer-1 edge logits ----------------
// rec1 (3 float4 = 48B): [pack(rt<<27|j), ex0, ex1, ex2][ex3, low01, low23, low45][low67,0,0,0]
#define FB_BLOCKS 192
__global__ void combo_fold_ea1(const float* __restrict__ M1, const float* __restrict__ M2,
    unsigned short* __restrict__ Bcat1, unsigned short* __restrict__ RWcat,
    const int* __restrict__ ji, const int* __restrict__ ii,
    const int* __restrict__ et, const int* __restrict__ rowstart,
    const int* __restrict__ prepos, const float* __restrict__ Cp1,
    const float* __restrict__ relb1, const float* __restrict__ Matt1,
    float4* __restrict__ recs1, int E) {
  const int bx = blockIdx.x;
  if (bx < FB_BLOCKS) {
    int idx = bx * 256 + threadIdx.x;
    if (idx < 512 * 64) { int c = idx >> 6, rk = idx & 63;
      Bcat1[(size_t)c * KCAT + 128 + rk] = f2bf(M1[(size_t)rk * D2 + c]); return; }
    idx -= 512 * 64;
    if (idx < 256 * 64) { int c = idx >> 6, rk = idx & 63;
      RWcat[(size_t)c * KCAT + 128 + rk] = f2bf(M2[(size_t)rk * OUTD + c]); }
    return;
  }
  int e = (bx - FB_BLOCKS) * 256 + threadIdx.x;
  if (e >= E) return;
  int j = ji[e], i = ii[e], rt = et[e];
  float4 lo0 = *(const float4*)(Cp1 + (size_t)j * 128 + rt * 8);
  float4 lo1 = *(const float4*)(Cp1 + (size_t)j * 128 + rt * 8 + 4);
  float low[RANK] = {lo0.x, lo0.y, lo0.z, lo0.w, lo1.x, lo1.y, lo1.z, lo1.w};
  float4 ali = *(const float4*)(Cp1 + (size_t)i * 128 + 64);
  float4 arj = *(const float4*)(Cp1 + (size_t)j * 128 + 68);
  float4 rb  = *(const float4*)(relb1 + rt * 4);
  float a0 = ali.x + arj.x + rb.x;
  float a1 = ali.y + arj.y + rb.y;
  float a2 = ali.z + arj.z + rb.z;
  float a3 = ali.w + arj.w + rb.w;
#pragma unroll
  for (int k = 0; k < RANK; ++k) {
    float4 mk = *(const float4*)(Matt1 + ((rt * 8 + k) << 2));
    a0 = fmaf(low[k], mk.x, a0); a1 = fmaf(low[k], mk.y, a1);
    a2 = fmaf(low[k], mk.z, a2); a3 = fmaf(low[k], mk.w, a3);
  }
  a0 = (a0 > 0.f) ? a0 : NEG_SLOPE * a0;
  a1 = (a1 > 0.f) ? a1 : NEG_SLOPE * a1;
  a2 = (a2 > 0.f) ? a2 : NEG_SLOPE * a2;
  a3 = (a3 > 0.f) ? a3 : NEG_SLOPE * a3;
  float e0 = expf(a0), e1 = expf(a1), e2 = expf(a2), e3 = expf(a3);
  unsigned pack = ((unsigned)rt << 27) | (unsigned)j;
  float4* rp = recs1 + (size_t)(rowstart[i] + prepos[e]) * 3;
  rp[0] = make_float4(__uint_as_float(pack), e0, e1, e2);
  rp[1] = make_float4(e3, __uint_as_float(pk2(low[0], low[1])),
                      __uint_as_float(pk2(low[2], low[3])),
                      __uint_as_float(pk2(low[4], low[5])));
  rp[2] = make_float4(__uint_as_float(pk2(low[6], low[7])), 0.f, 0.f, 0.f);
}

// ---------------- Layer-1 fused Q/den + x0-gather: fills XQ1 [Nn][4x(128 Xw | 64 Q)] ----------------
__global__ __launch_bounds__(256) void agg1f(const float4* __restrict__ recs1,
    const int* __restrict__ rowstart, const unsigned short* __restrict__ x0b,
    unsigned short* __restrict__ XQ1, int Nn) {
  __shared__ float denS[4][32];          // [wid][h*8+rt]
  const int wid = threadIdx.x >> 6, lane = threadIdx.x & 63;
  const int i = blockIdx.x * 4 + wid;
  if (i >= Nn) return;
  const int rt_mine = lane >> 3, k = lane & 7;
  const int s0 = rowstart[i], deg = rowstart[i + 1] - s0;
  const float* rf = (const float*)recs1;
  const size_t xb = (size_t)i * 768;
  // ---- Phase A: LoRA Q sums + softmax denominators (lane = rt*8+k) ----
  {
    float q0 = 0.f, q1 = 0.f, q2 = 0.f, q3 = 0.f;
    float d0 = 0.f, d1 = 0.f, d2 = 0.f, d3 = 0.f;
    float4 a0 = {}, a1 = {};
    float a2x = 0.f;
    if (deg > 0) {
      a0 = recs1[(size_t)s0 * 3]; a1 = recs1[(size_t)s0 * 3 + 1];
      a2x = rf[(size_t)s0 * 12 + 8];
    }
    const int sel = k >> 1;
    for (int p = 0; p < deg; ++p) {
      float4 b0 = a0, b1 = a1; float b2x = a2x;
      if (p + 1 < deg) {
        b0 = recs1[(size_t)(s0 + p + 1) * 3]; b1 = recs1[(size_t)(s0 + p + 1) * 3 + 1];
        b2x = rf[(size_t)(s0 + p + 1) * 12 + 8];
      }
      int rt = (int)(asu(a0.x) >> 27);
      if (rt == rt_mine) {
        float pw = (sel == 0) ? a1.y : (sel == 1) ? a1.z : (sel == 2) ? a1.w : a2x;
        unsigned pu = asu(pw);
        float lw = bf2f((unsigned short)((k & 1) ? (pu >> 16) : (pu & 0xffff)));
        q0 = fmaf(a0.y, lw, q0); q1 = fmaf(a0.z, lw, q1);
        q2 = fmaf(a0.w, lw, q2); q3 = fmaf(a1.x, lw, q3);
        d0 += a0.y; d1 += a0.z; d2 += a0.w; d3 += a1.x;
      }
      a0 = b0; a1 = b1; a2x = b2x;
    }
    float r0 = (d0 > 0.f) ? 1.f / d0 : 0.f;
    float r1 = (d1 > 0.f) ? 1.f / d1 : 0.f;
    float r2 = (d2 > 0.f) ? 1.f / d2 : 0.f;
    float r3 = (d3 > 0.f) ? 1.f / d3 : 0.f;
    XQ1[xb + 0 * 192 + 128 + lane] = f2bf(q0 * r0);
    XQ1[xb + 1 * 192 + 128 + lane] = f2bf(q1 * r1);
    XQ1[xb + 2 * 192 + 128 + lane] = f2bf(q2 * r2);
    XQ1[xb + 3 * 192 + 128 + lane] = f2bf(q3 * r3);
    if (k == 0) {
      denS[wid][rt_mine]      = r0;
      denS[wid][8 + rt_mine]  = r1;
      denS[wid][16 + rt_mine] = r2;
      denS[wid][24 + rt_mine] = r3;
    }
  }
  // wave-synchronous LDS: same wave wrote denS[wid], no barrier needed
  // ---- Phase B: weighted x0 gather (lane = 2 cols, records now cache-hot) ----
  const int c0 = lane * 2;
  float acc[8] = {};
  float4 r0 = {}, r1 = {};
  float e30 = 0.f, e31 = 0.f;
  unsigned za = 0u;
  if (deg > 0) { r0 = recs1[(size_t)s0 * 3]; e30 = rf[(size_t)s0 * 12 + 4];
    za = *(const unsigned*)(x0b + (size_t)(asu(r0.x) & JMASK) * 128 + c0); }
  if (deg > 1) { r1 = recs1[(size_t)(s0 + 1) * 3]; e31 = rf[(size_t)(s0 + 1) * 12 + 4]; }
  for (int p = 0; p < deg; ++p) {
    float4 r2 = r1; float e32 = e31; unsigned zb = za;
    if (p + 2 < deg) { r2 = recs1[(size_t)(s0 + p + 2) * 3];
                       e32 = rf[(size_t)(s0 + p + 2) * 12 + 4]; }
    if (p + 1 < deg) zb = *(const unsigned*)(x0b + (size_t)(asu(r1.x) & JMASK) * 128 + c0);
    int rt = (int)(asu(r0.x) >> 27);
    float w0 = r0.y * denS[wid][rt];
    float w1 = r0.z * denS[wid][8 + rt];
    float w2 = r0.w * denS[wid][16 + rt];
    float w3 = e30 * denS[wid][24 + rt];
    float v0 = bf2f((unsigned short)(za & 0xffff));
    float v1 = bf2f((unsigned short)(za >> 16));
    acc[0] = fmaf(w0, v0, acc[0]); acc[1] = fmaf(w0, v1, acc[1]);
    acc[2] = fmaf(w1, v0, acc[2]); acc[3] = fmaf(w1, v1, acc[3]);
    acc[4] = fmaf(w2, v0, acc[4]); acc[5] = fmaf(w2, v1, acc[5]);
    acc[6] = fmaf(w3, v0, acc[6]); acc[7] = fmaf(w3, v1, acc[7]);
    r0 = r1; e30 = e31; r1 = r2; e31 = e32; za = zb;
  }
#pragma unroll
  for (int h = 0; h < 4; ++h) {
    unsigned pv = pk2(acc[2 * h], acc[2 * h + 1]);
    *(unsigned*)(XQ1 + xb + h * 192 + c0) = pv;
  }
}

// ---------------- Layer-2 edge logits -> packed records ----------------
// rec2 (2 float4 = 32B): [pack, ex, low01, low23][low45, low67, 0, 0]
__global__ void edge_alpha2(const int* __restrict__ ji, const int* __restrict__ ii,
                            const int* __restrict__ et, const int* __restrict__ rowstart,
                            const int* __restrict__ prepos,
                            const float* __restrict__ Cp2,
                            const float* __restrict__ relb2, const float* __restrict__ Matt2,
                            float4* __restrict__ recs2, int E) {
  int e = blockIdx.x * blockDim.x + threadIdx.x;
  if (e >= E) return;
  int j = ji[e], i = ii[e], rt = et[e];
  float4 lo0 = *(const float4*)(Cp2 + (size_t)j * 128 + rt * 8);
  float4 lo1 = *(const float4*)(Cp2 + (size_t)j * 128 + rt * 8 + 4);
  float low[RANK] = {lo0.x, lo0.y, lo0.z, lo0.w, lo1.x, lo1.y, lo1.z, lo1.w};
  float a = Cp2[(size_t)i * 128 + 64] + Cp2[(size_t)j * 128 + 65] + relb2[rt];
#pragma unroll
  for (int k = 0; k < RANK; ++k) a = fmaf(low[k], Matt2[rt * RANK + k], a);
  a = (a > 0.f) ? a : NEG_SLOPE * a;
  float ex = expf(a);
  unsigned pack = ((unsigned)rt << 27) | (unsigned)j;
  float4* rp = recs2 + (size_t)(rowstart[i] + prepos[e]) * 2;
  rp[0] = make_float4(__uint_as_float(pack), ex,
                      __uint_as_float(pk2(low[0], low[1])),
                      __uint_as_float(pk2(low[2], low[3])));
  rp[1] = make_float4(__uint_as_float(pk2(low[4], low[5])),
                      __uint_as_float(pk2(low[6], low[7])), 0.f, 0.f);
}

// ---------------- Layer-2 Q/den: Q -> Acat cols 128..191, rden2[Nn][8] ----------------
__global__ __launch_bounds__(256) void qden2(const float4* __restrict__ recs2,
    const int* __restrict__ rowstart, unsigned short* __restrict__ Acat,
    float* __restrict__ rden2, int Nn) {
  const int wid = threadIdx.x >> 6, lane = threadIdx.x & 63;
  const int i = blockIdx.x * 4 + wid;
  if (i >= Nn) return;
  const int rt_mine = lane >> 3, k = lane & 7;
  const int s0 = rowstart[i], deg = rowstart[i + 1] - s0;
  const float* rf = (const float*)recs2;
  float q = 0.f, d = 0.f;
  float4 a0 = {}; float2 a1 = {};
  if (deg > 0) { a0 = recs2[(size_t)s0 * 2]; a1 = *(const float2*)(rf + (size_t)s0 * 8 + 4); }
  const int sel = k >> 1;
  for (int p = 0; p < deg; ++p) {
    float4 b0 = a0; float2 b1 = a1;
    if (p + 1 < deg) {
      b0 = recs2[(size_t)(s0 + p + 1) * 2];
      b1 = *(const float2*)(rf + (size_t)(s0 + p + 1) * 8 + 4);
    }
    int rt = (int)(asu(a0.x) >> 27);
    if (rt == rt_mine) {
      float pw = (sel == 0) ? a0.z : (sel == 1) ? a0.w : (sel == 2) ? a1.x : a1.y;
      unsigned pu = asu(pw);
      float lw = bf2f((unsigned short)((k & 1) ? (pu >> 16) : (pu & 0xffff)));
      q = fmaf(a0.y, lw, q); d += a0.y;
    }
    a0 = b0; a1 = b1;
  }
  float rd = (d > 0.f) ? 1.f / d : 0.f;
  Acat[(size_t)i * KCAT + 128 + lane] = f2bf(q * rd);
  if (k == 0) rden2[(size_t)i * 8 + rt_mine] = rd;
}

// ---------------- Layer-2 gather + residual/lora/bias (o2) + LN -> out ----------------
__global__ __launch_bounds__(256) void node_agg2_lite(const float4* __restrict__ recs2,
    const int* __restrict__ rowstart, const unsigned short* __restrict__ z2b,
    const float* __restrict__ rden2, const float* __restrict__ o2,
    const float* __restrict__ ln_g, const float* __restrict__ ln_b,
    float* __restrict__ y, int Nn) {
  const int wid = threadIdx.x >> 6;
  const int lane = threadIdx.x & 63;
  const int i = blockIdx.x * 4 + wid;
  if (i >= Nn) return;
  __shared__ float denS[4][NRELS];
  if (lane < NRELS) denS[wid][lane] = rden2[(size_t)i * 8 + lane];
  // wave-synchronous LDS, no barrier
  const int s0 = rowstart[i];
  const int deg = rowstart[i + 1] - s0;
  const int c0 = lane * 4;
  // hoist independent loads: residual row + LN params issue under the gather chase
  float4 rsv = *(const float4*)(o2 + (size_t)i * OUTD + c0);   // residual+lora2+bias2+res_b
  float4 g = *(const float4*)(ln_g + c0);
  float4 bb = *(const float4*)(ln_b + c0);
  float acc[4] = {};
  float4 r0 = {}, r1 = {}, r2 = {};
  uint2 za = make_uint2(0u, 0u), zb = make_uint2(0u, 0u);
  if (deg > 0) { r0 = recs2[(size_t)s0 * 2];
    za = *(const uint2*)(z2b + (size_t)(asu(r0.x) & JMASK) * OUTD + c0); }
  if (deg > 1) { r1 = recs2[(size_t)(s0 + 1) * 2];
    zb = *(const uint2*)(z2b + (size_t)(asu(r1.x) & JMASK) * OUTD + c0); }
  if (deg > 2) r2 = recs2[(size_t)(s0 + 2) * 2];
  for (int p = 0; p < deg; ++p) {
    float4 r3 = r2;
    uint2 zn = zb;
    if (p + 3 < deg) r3 = recs2[(size_t)(s0 + p + 3) * 2];
    if (p + 2 < deg)
      zn = *(const uint2*)(z2b + (size_t)(asu(r2.x) & JMASK) * OUTD + c0);
    int rt = (int)(asu(r0.x) >> 27);
    float wt = r0.y * denS[wid][rt];
    acc[0] = fmaf(wt, bf2f((unsigned short)(za.x & 0xffff)), acc[0]);
    acc[1] = fmaf(wt, bf2f((unsigned short)(za.x >> 16)), acc[1]);
    acc[2] = fmaf(wt, bf2f((unsigned short)(za.y & 0xffff)), acc[2]);
    acc[3] = fmaf(wt, bf2f((unsigned short)(za.y >> 16)), acc[3]);
    r0 = r1; r1 = r2; r2 = r3; za = zb; zb = zn;
  }
  float vv[4];
  vv[0] = acc[0] + rsv.x;
  vv[1] = acc[1] + rsv.y;
  vv[2] = acc[2] + rsv.z;
  vv[3] = acc[3] + rsv.w;
  float s = vv[0] + vv[1] + vv[2] + vv[3];
  for (int o = 32; o > 0; o >>= 1) s += __shfl_xor(s, o, 64);
  float mu = s * (1.f / OUTD);
  float q = 0.f;
#pragma unroll
  for (int k = 0; k < 4; ++k) { float d = vv[k] - mu; q += d * d; }
  for (int o = 32; o > 0; o >>= 1) q += __shfl_xor(q, o, 64);
  float rstd = rsqrtf(q * (1.f / OUTD) + LN_EPS);
  float4 ov;
  ov.x = (vv[0] - mu) * rstd * g.x + bb.x;
  ov.y = (vv[1] - mu) * rstd * g.y + bb.y;
  ov.z = (vv[2] - mu) * rstd * g.z + bb.z;
  ov.w = (vv[3] - mu) * rstd * g.w + bb.w;
  *(float4*)(y + (size_t)i * OUTD + c0) = ov;
}

extern "C" void kernel_launch(void* const* d_in, const int* in_sizes, int n_in,
                              void* d_out, int out_size, void* d_ws, size_t ws_size,
                              hipStream_t stream) {
  const float* x0     = (const float*)d_in[0];
  const float* A1     = (const float*)d_in[1];
  const float* B1     = (const float*)d_in[2];
  const float* W1     = (const float*)d_in[3];
  const float* attL1  = (const float*)d_in[4];
  const float* attR1  = (const float*)d_in[5];
  const float* relb1  = (const float*)d_in[6];
  const float* bias1  = (const float*)d_in[7];
  const float* A2     = (const float*)d_in[8];
  const float* B2     = (const float*)d_in[9];
  const float* W2     = (const float*)d_in[10];
  const float* attL2  = (const float*)d_in[11];
  const float* attR2  = (const float*)d_in[12];
  const float* relb2  = (const float*)d_in[13];
  const float* bias2  = (const float*)d_in[14];
  const float* res_W  = (const float*)d_in[15];
  const float* res_b  = (const float*)d_in[16];
  const float* ln_g   = (const float*)d_in[17];
  const float* ln_b   = (const float*)d_in[18];
  const int*   eidx   = (const int*)d_in[19];
  const int*   etype  = (const int*)d_in[20];
  float* out = (float*)d_out;

  const int Nn = in_sizes[0] / EMB;     // 30000
  const int E  = in_sizes[20];          // 150000
  const int* ji = eidx;
  const int* ii = eidx + E;

  // ---- workspace carve-up (float units; all offsets stay 16B-aligned) ----
  float* w = (float*)d_ws;
  size_t off = 0;
  float* o2    = w + off; off += (size_t)Nn * OUTD;
  float* Cp1   = w + off; off += (size_t)Nn * 128;    // P1 + al1/ar1
  float* Cp2   = w + off; off += (size_t)Nn * 128;    // P2 + al2/ar2
  float* M1    = w + off; off += 64 * D2;
  float* M2    = w + off; off += 64 * OUTD;
  float* Amat1 = w + off; off += 64 * EMB;
  float* Amat2 = w + off; off += 64 * D2;
  float* Matt1 = w + off; off += 64 * 4;
  float* Matt2 = w + off; off += 64;
  float* awR1f = w + off; off += 512;
  float* awR2f = w + off; off += 512;
  float* rden2 = w + off; off += (size_t)Nn * 8;
  float4* recs1 = (float4*)(w + off); off += (size_t)E * 12;   // 48B records
  float4* recs2 = (float4*)(w + off); off += (size_t)E * 8;    // 32B records
  unsigned short* z2b    = (unsigned short*)(w + off); off += (size_t)Nn * OUTD / 2;
  unsigned short* x0b    = (unsigned short*)(w + off); off += (size_t)Nn * EMB / 2;
  unsigned short* h1b    = (unsigned short*)(w + off); off += (size_t)Nn * D2 / 2;
  unsigned short* XQ1    = (unsigned short*)(w + off); off += (size_t)Nn * 768 / 2;
  unsigned short* Acat   = (unsigned short*)(w + off); off += (size_t)Nn * KCAT / 2;
  unsigned short* W2b    = (unsigned short*)(w + off); off += (size_t)OUTD * D2 / 2;
  unsigned short* RWcat  = (unsigned short*)(w + off); off += (size_t)OUTD * KCAT / 2;
  unsigned short* Bcat1  = (unsigned short*)(w + off); off += (size_t)512 * KCAT / 2;
  unsigned short* Bp1ext = (unsigned short*)(w + off); off += (size_t)128 * 128 / 2;
  unsigned short* Bp2ext = (unsigned short*)(w + off); off += (size_t)128 * 512 / 2;
  int* ideg     = (int*)(w + off); off += (size_t)Nn;
  int* prepos   = (int*)(w + off); off += (size_t)E;
  int* rowstart = (int*)(w + off); off += (size_t)Nn + 1;
  (void)ws_size; (void)n_in; (void)out_size;

  const int MT128 = (Nn + 127) / 128;
  const int NB4 = (Nn + 3) / 4;
  const int NGRP = (MT128 + 7) / 8;

  // 0) fused prep: hist + conversions + all M-independent B-operand builds
  (void)hipMemsetAsync(ideg, 0, (size_t)Nn * sizeof(int), stream);
  {
    int nx0 = Nn * EMB;
    int total = E + nx0 + OUTD * D2 + OUTD * EMB + 64 * EMB + 64 * D2
              + 64 * EMB + 64 * D2 + 1024 + 1024 + 56 * 128 + 62 * 512 + 512 * 128;
    prep_all<<<(total + 255) / 256, 256, 0, stream>>>(x0, W1, W2, res_W, A1, A2, B1, B2,
        attL1, attR1, attL2, attR2, x0b, Acat, W2b, RWcat, Amat1, Amat2,
        Bp1ext, Bp2ext, Bcat1, awR1f, awR2f, ii, ideg, prepos, E, nx0);
  }

  // 1) exscan + Matt folds (spare blocks)
  exscan_matt<<<3, 1024, 0, stream>>>(ideg, rowstart, Nn, Amat1, awR1f, Matt1,
                                      Amat2, awR2f, Matt2);

  // 2) M1/M2 fp32 GEMMs + P1/att GEMM (one dispatch)
  combo_abt_p1<<<12 + MT128, 256, 0, stream>>>(Amat1, W1, M1, Amat2, W2, M2,
                                               x0b, Bp1ext, Cp1, Nn);

  // 3) Bcat1/RWcat M-halves + layer-1 edge logits (one dispatch)
  combo_fold_ea1<<<FB_BLOCKS + (E + 255) / 256, 256, 0, stream>>>(M1, M2, Bcat1, RWcat,
      ji, ii, etype, rowstart, prepos, Cp1, relb1, Matt1, recs1, E);

  // 4) fused Q/den + x0-gather; msg GEMM -> h1 (elu+bias fused)
  agg1f<<<NB4, 256, 0, stream>>>(recs1, rowstart, x0b, XQ1, Nn);
  gemm_tile<1, 0, 1, 0><<<dim3(MT128, 4), 256, 0, stream>>>(XQ1, Bcat1, h1b, nullptr,
      nullptr, nullptr, Nn, D2, KCAT, 768, KCAT, bias1, nullptr);

  // 5) Layer-2: z2 GEMM + P2/att slice, XCD-trio swizzled (same-row-panel tiles co-XCD)
  gemm_tile_swz<0, 0, 0, 1, 3><<<NGRP * 24, 256, 0, stream>>>(h1b, W2b, z2b, nullptr,
      Bp2ext, Cp2, Nn, OUTD, D2, D2, 0, nullptr, nullptr, MT128);

  // 6) Layer-2 edge logits; Q/den (fills Acat); residual+lora+bias GEMM (pair-swizzled); gather+LN
  edge_alpha2<<<(E + 255) / 256, 256, 0, stream>>>(ji, ii, etype, rowstart, prepos, Cp2,
                                                   relb2, Matt2, recs2, E);
  qden2<<<NB4, 256, 0, stream>>>(recs2, rowstart, Acat, rden2, Nn);
  gemm_tile_swz<1, 1, 0, 0, 2><<<NGRP * 16, 256, 0, stream>>>(Acat, RWcat, nullptr, o2,
      nullptr, nullptr, Nn, OUTD, KCAT, KCAT, 0, bias2, res_b, MT128);
  node_agg2_lite<<<NB4, 256, 0, stream>>>(recs2, rowstart, z2b, rden2, o2, ln_g, ln_b, out, Nn);
}